// Round 2
// baseline (2399.086 us; speedup 1.0000x reference)
//
#include <hip/hip_runtime.h>
#include <math.h>

#define HD 128
#define FD 128
#define RD 64
#define TE 128          // edges per tile
#define RC_CUT 5.0f
#define WIN 16          // dst nodes per bucket window
#define WIN_SHIFT 4

typedef _Float16 half8_t __attribute__((ext_vector_type(8)));
typedef float floatx4 __attribute__((ext_vector_type(4)));

__device__ __forceinline__ float fast_tanh(float x) {
    float ex = __expf(2.0f * x);
    return 1.0f - 2.0f / (ex + 1.0f);
}

// ---------------- lin1: h = x @ lin1_w.T ----------------
__global__ __launch_bounds__(256) void lin1_kernel(const float* __restrict__ x,
                                                   const float* __restrict__ w,
                                                   float* __restrict__ h, int n)
{
    __shared__ float sx[16][HD];
    int base = blockIdx.x * 16;
    for (int i = threadIdx.x; i < 16 * HD; i += 256) {
        int r = i >> 7, c = i & 127;
        int row = base + r;
        sx[r][c] = (row < n) ? x[(size_t)row * HD + c] : 0.0f;
    }
    __syncthreads();
    int f = threadIdx.x & 127;
    int half = threadIdx.x >> 7;
    float acc[8];
#pragma unroll
    for (int r = 0; r < 8; ++r) acc[r] = 0.0f;
    const float* wrow = w + (size_t)f * HD;
    for (int k = 0; k < HD; ++k) {
        float wv = wrow[k];
#pragma unroll
        for (int r = 0; r < 8; ++r) acc[r] += sx[half * 8 + r][k] * wv;
    }
#pragma unroll
    for (int r = 0; r < 8; ++r) {
        int row = base + half * 8 + r;
        if (row < n) h[(size_t)row * FD + f] = acc[r];
    }
}

// ---------------- bucketing: count / scan / scatter ----------------
__global__ __launch_bounds__(256) void count_kernel(const int* __restrict__ dstp,
                                                    int* cnt, int E)
{
    for (int e = blockIdx.x * blockDim.x + threadIdx.x; e < E;
         e += gridDim.x * blockDim.x)
        atomicAdd(&cnt[dstp[e] >> WIN_SHIFT], 1);
}

// single-wave exclusive scan; cnt becomes the cursor copy
__global__ void scan_kernel(int* cnt, int* offs, int nbk)
{
    int lane = threadIdx.x;
    int carry = 0;
    for (int base = 0; base < nbk; base += 64) {
        int i = base + lane;
        int v = (i < nbk) ? cnt[i] : 0;
        int orig = v;
#pragma unroll
        for (int d = 1; d < 64; d <<= 1) {
            int t = __shfl_up(v, d);
            if (lane >= d) v += t;
        }
        if (i < nbk) {
            int excl = carry + v - orig;
            offs[i] = excl;
            cnt[i]  = excl;      // cursor for scatter
        }
        carry += __shfl(v, 63);
    }
    if (lane == 0) offs[nbk] = carry;
}

__global__ __launch_bounds__(256) void scatter_kernel(const int* __restrict__ dstp,
                                                      int* cursor, int* perm, int E)
{
    for (int e = blockIdx.x * blockDim.x + threadIdx.x; e < E;
         e += gridDim.x * blockDim.x) {
        int p = atomicAdd(&cursor[dstp[e] >> WIN_SHIFT], 1);
        perm[p] = e;
    }
}

// ---------------- fused edge kernel (MFMA f16, bucketed LDS agg) -------------
// LDS layout (dynamic, 88 KB -> 1 block/CU, 16 waves):
//   sT   @ 0      : 32768 B -- T tile (128x128 f16, row 256B, swizzled)
//                   (first 16384 B double as A tile 128x64 f16, row 128B)
//   sB1  @ 32768  : 16384 B -- fw1 (f16, swizzled)
//   sB2  @ 49152  : 32768 B -- fw2 (f16, swizzled)
//   sAgg @ 81920  :  8192 B -- 16x128 f32 window accumulator (XOR-rotated)
__device__ __forceinline__ half8_t lds_read8(const char* base, int row,
                                             int rowstride, int col) {
    int off = row * rowstride + ((col * 2) ^ ((row & 7) << 4));
    return *(const half8_t*)(base + off);
}

__global__ __launch_bounds__(1024, 4) void edge_kernel(
    const float* __restrict__ edge_weight,
    const float* __restrict__ edge_attr,
    const float* __restrict__ fw1, const float* __restrict__ fb1,
    const float* __restrict__ fw2, const float* __restrict__ fb2,
    const int* __restrict__ eidx,
    const float* __restrict__ h,
    const int* __restrict__ perm,
    const int* __restrict__ offs,
    int* qctr,
    float* __restrict__ agg,
    int E, int n, int nbk)
{
    extern __shared__ char smem[];
    char*  sT   = smem;
    char*  sB1  = smem + 32768;
    char*  sB2  = smem + 49152;
    float* sAgg = (float*)(smem + 81920);
    __shared__ int sBkt;

    // ---- stage weights once per block (fp32 -> f16, swizzled) ----
    for (int i = threadIdx.x * 8; i < FD * RD; i += blockDim.x * 8) {
        int r = i >> 6, c = i & 63;
        const float4* g = (const float4*)(fw1 + (size_t)r * RD + c);
        float4 v0 = g[0], v1 = g[1];
        half8_t hv;
        hv[0] = (_Float16)v0.x; hv[1] = (_Float16)v0.y;
        hv[2] = (_Float16)v0.z; hv[3] = (_Float16)v0.w;
        hv[4] = (_Float16)v1.x; hv[5] = (_Float16)v1.y;
        hv[6] = (_Float16)v1.z; hv[7] = (_Float16)v1.w;
        *(half8_t*)(sB1 + r * 128 + ((c * 2) ^ ((r & 7) << 4))) = hv;
    }
    for (int i = threadIdx.x * 8; i < FD * FD; i += blockDim.x * 8) {
        int r = i >> 7, c = i & 127;
        const float4* g = (const float4*)(fw2 + (size_t)r * FD + c);
        float4 v0 = g[0], v1 = g[1];
        half8_t hv;
        hv[0] = (_Float16)v0.x; hv[1] = (_Float16)v0.y;
        hv[2] = (_Float16)v0.z; hv[3] = (_Float16)v0.w;
        hv[4] = (_Float16)v1.x; hv[5] = (_Float16)v1.y;
        hv[6] = (_Float16)v1.z; hv[7] = (_Float16)v1.w;
        *(half8_t*)(sB2 + r * 256 + ((c * 2) ^ ((r & 7) << 4))) = hv;
    }
    // zero the window accumulator
    for (int i = threadIdx.x; i < WIN * FD; i += blockDim.x) sAgg[i] = 0.0f;

    const int* srcp = eidx;
    const int* dstp = eidx + E;
    int lane = threadIdx.x & 63;
    int wid  = threadIdx.x >> 6;   // 0..15
    int wm = wid >> 2;             // 0..3  (edge dim, 32 each)
    int wn = wid & 3;              // 0..3  (filter dim, 32 each)
    int l15 = lane & 15;
    int l4  = lane >> 4;

    // hoisted epilogue constants
    float bias2[2];
    float bias1[2];
    int gcol[2];
#pragma unroll
    for (int ni = 0; ni < 2; ++ni) {
        gcol[ni]  = wn * 32 + ni * 16 + l15;
        bias2[ni] = fb2[gcol[ni]];
        bias1[ni] = fb1[gcol[ni]];
    }

    while (true) {
        if (threadIdx.x == 0) sBkt = atomicAdd(qctr, 1);
        __syncthreads();
        int bkt = sBkt;
        if (bkt >= nbk) break;
        int offs0 = offs[bkt];
        int nE    = offs[bkt + 1] - offs0;

        for (int t0 = 0; t0 < nE; t0 += TE) {
            // ---- stage A = edge_attr[perm[...]] as f16 into sT (row 128B) ----
            {
                int i = threadIdx.x * 8;          // single pass: 1024*8 = TE*RD
                int r = i >> 6, c = i & 63;
                half8_t hv;
                int ei = t0 + r;
                if (ei < nE) {
                    int e = perm[offs0 + ei];
                    const float4* g = (const float4*)(edge_attr + (size_t)e * RD + c);
                    float4 v0 = g[0], v1 = g[1];
                    hv[0] = (_Float16)v0.x; hv[1] = (_Float16)v0.y;
                    hv[2] = (_Float16)v0.z; hv[3] = (_Float16)v0.w;
                    hv[4] = (_Float16)v1.x; hv[5] = (_Float16)v1.y;
                    hv[6] = (_Float16)v1.z; hv[7] = (_Float16)v1.w;
                } else {
                    for (int q = 0; q < 8; ++q) hv[q] = (_Float16)0.0f;
                }
                *(half8_t*)(sT + r * 128 + ((c * 2) ^ ((r & 7) << 4))) = hv;
            }
            __syncthreads();

            // ---- GEMM1: C1 = A @ fw1^T   (128e x 128f, K=64) ----
            floatx4 acc[2][2];
#pragma unroll
            for (int mi = 0; mi < 2; ++mi)
#pragma unroll
                for (int ni = 0; ni < 2; ++ni)
                    acc[mi][ni] = (floatx4){0.f, 0.f, 0.f, 0.f};
#pragma unroll
            for (int ks = 0; ks < 2; ++ks) {
                int k = ks * 32 + l4 * 8;
                half8_t a[2], b[2];
#pragma unroll
                for (int mi = 0; mi < 2; ++mi)
                    a[mi] = lds_read8(sT, wm * 32 + mi * 16 + l15, 128, k);
#pragma unroll
                for (int ni = 0; ni < 2; ++ni)
                    b[ni] = lds_read8(sB1, wn * 32 + ni * 16 + l15, 128, k);
#pragma unroll
                for (int mi = 0; mi < 2; ++mi)
#pragma unroll
                    for (int ni = 0; ni < 2; ++ni)
                        acc[mi][ni] = __builtin_amdgcn_mfma_f32_16x16x32_f16(
                            a[mi], b[ni], acc[mi][ni], 0, 0, 0);
            }
            __syncthreads();   // A consumed; sT can be overwritten by T

            // ---- bias + tanh -> T (f16, row 256B, swizzled) ----
#pragma unroll
            for (int ni = 0; ni < 2; ++ni) {
                int f = gcol[ni];
                float bias = bias1[ni];
#pragma unroll
                for (int mi = 0; mi < 2; ++mi) {
#pragma unroll
                    for (int j = 0; j < 4; ++j) {
                        int e = wm * 32 + mi * 16 + l4 * 4 + j;
                        float t = fast_tanh(acc[mi][ni][j] + bias);
                        *(_Float16*)(sT + e * 256 + ((f * 2) ^ ((e & 7) << 4))) =
                            (_Float16)t;
                    }
                }
            }
            __syncthreads();

            // ---- GEMM2: W = T @ fw2^T   (128e x 128g, K=128) ----
            floatx4 acc2[2][2];
#pragma unroll
            for (int mi = 0; mi < 2; ++mi)
#pragma unroll
                for (int ni = 0; ni < 2; ++ni)
                    acc2[mi][ni] = (floatx4){0.f, 0.f, 0.f, 0.f};
#pragma unroll
            for (int ks = 0; ks < 4; ++ks) {
                int k = ks * 32 + l4 * 8;
                half8_t a[2], b[2];
#pragma unroll
                for (int mi = 0; mi < 2; ++mi)
                    a[mi] = lds_read8(sT, wm * 32 + mi * 16 + l15, 256, k);
#pragma unroll
                for (int ni = 0; ni < 2; ++ni)
                    b[ni] = lds_read8(sB2, wn * 32 + ni * 16 + l15, 256, k);
#pragma unroll
                for (int mi = 0; mi < 2; ++mi)
#pragma unroll
                    for (int ni = 0; ni < 2; ++ni)
                        acc2[mi][ni] = __builtin_amdgcn_mfma_f32_16x16x32_f16(
                            a[mi], b[ni], acc2[mi][ni], 0, 0, 0);
            }
            __syncthreads();   // T consumed; next tile may overwrite sT

            // ---- epilogue: cutoff * h[src] gather, LDS window scatter ----
#pragma unroll
            for (int mi = 0; mi < 2; ++mi) {
                int e4[4], s4[4], lr4[4], ok4[4];
                float d4[4];
#pragma unroll
                for (int j = 0; j < 4; ++j) {
                    int el = wm * 32 + mi * 16 + l4 * 4 + j;
                    int ei = t0 + el;
                    ok4[j] = (ei < nE);
                    e4[j]  = perm[offs0 + (ok4[j] ? ei : 0)];
                }
#pragma unroll
                for (int j = 0; j < 4; ++j) {
                    s4[j]  = srcp[e4[j]];
                    lr4[j] = dstp[e4[j]] - (bkt << WIN_SHIFT);
                    d4[j]  = edge_weight[e4[j]];
                }
#pragma unroll
                for (int j = 0; j < 4; ++j) {
                    if (!ok4[j]) continue;
                    float C = (d4[j] < RC_CUT)
                                ? 0.5f * (__cosf(d4[j] * 0.6283185307179586f) + 1.0f)
                                : 0.0f;
                    const float* hrow = h + (size_t)s4[j] * FD;
                    float* arow = sAgg + lr4[j] * FD;
                    int rot = (lr4[j] & 7) << 2;
#pragma unroll
                    for (int ni = 0; ni < 2; ++ni) {
                        int g = gcol[ni];
                        float wv = (acc2[mi][ni][j] + bias2[ni]) * C;
                        atomicAdd(arow + (g ^ rot), wv * hrow[g]);
                    }
                }
            }
        }
        __syncthreads();   // all LDS adds for this bucket done

        // ---- flush window to global (plain stores), re-zero LDS ----
        for (int idx = threadIdx.x; idx < WIN * FD; idx += blockDim.x) {
            int r = idx >> 7, c = idx & 127;
            int row = (bkt << WIN_SHIFT) + r;
            int sa = r * FD + (c ^ ((r & 7) << 2));
            if (row < n) agg[(size_t)row * FD + c] = sAgg[sa];
            sAgg[sa] = 0.0f;
        }
        __syncthreads();
    }
}

// ---------------- final: disc conv + lin2 + tanh + lin ----------------
__global__ __launch_bounds__(256) void final_kernel(
    const float* aggin, const float* __restrict__ h,
    const float* __restrict__ disc_w,
    const float* __restrict__ lin2_w, const float* __restrict__ lin2_b,
    const float* __restrict__ lin_w, const float* __restrict__ lin_b,
    float* out, int n)
{
    __shared__ float sg[16][FD];
    __shared__ float sm[16][FD];
    int base = blockIdx.x * 16;
    for (int i = threadIdx.x; i < 16 * FD; i += 256) {
        int r = i >> 7, c = i & 127;
        int row = base + r;
        float v = 0.0f;
        if (row < n) {
            v = aggin[(size_t)row * FD + c] + disc_w[c] * h[(size_t)row * FD + c];
            if (row + 1 < n) v += disc_w[FD + c] * h[(size_t)(row + 1) * FD + c];
            if (row >= 1)    v += disc_w[2 * FD + c] * h[(size_t)(row - 1) * FD + c];
        }
        sg[r][c] = v;
    }
    __syncthreads();
    int f = threadIdx.x & 127;
    int half = threadIdx.x >> 7;
    {
        float acc[8];
        float b = lin2_b[f];
#pragma unroll
        for (int r = 0; r < 8; ++r) acc[r] = b;
        const float* wrow = lin2_w + (size_t)f * FD;
        for (int k = 0; k < FD; ++k) {
            float wv = wrow[k];
#pragma unroll
            for (int r = 0; r < 8; ++r) acc[r] += sg[half * 8 + r][k] * wv;
        }
#pragma unroll
        for (int r = 0; r < 8; ++r) sm[half * 8 + r][f] = fast_tanh(acc[r]);
    }
    __syncthreads();
    {
        float acc[8];
        float b = lin_b[f];
#pragma unroll
        for (int r = 0; r < 8; ++r) acc[r] = b;
        const float* wrow = lin_w + (size_t)f * HD;
        for (int k = 0; k < FD; ++k) {
            float wv = wrow[k];
#pragma unroll
            for (int r = 0; r < 8; ++r) acc[r] += sm[half * 8 + r][k] * wv;
        }
#pragma unroll
        for (int r = 0; r < 8; ++r) {
            int row = base + half * 8 + r;
            if (row < n) out[(size_t)row * HD + f] = acc[r];
        }
    }
}

extern "C" void kernel_launch(void* const* d_in, const int* in_sizes, int n_in,
                              void* d_out, int out_size, void* d_ws, size_t ws_size,
                              hipStream_t stream)
{
    const float* x      = (const float*)d_in[0];
    const float* ew     = (const float*)d_in[1];
    const float* ea     = (const float*)d_in[2];
    const float* fw1    = (const float*)d_in[3];
    const float* fb1    = (const float*)d_in[4];
    const float* fw2    = (const float*)d_in[5];
    const float* fb2    = (const float*)d_in[6];
    const float* lin1_w = (const float*)d_in[7];
    const float* lin2_w = (const float*)d_in[8];
    const float* lin2_b = (const float*)d_in[9];
    const float* disc_w = (const float*)d_in[10];
    const float* lin_w  = (const float*)d_in[11];
    const float* lin_b  = (const float*)d_in[12];
    const int*   eidx   = (const int*)d_in[13];

    int n = in_sizes[0] / HD;
    int E = in_sizes[1];
    int nbk = (n + WIN - 1) / WIN;
    float* out = (float*)d_out;

    // workspace layout
    char* base = (char*)d_ws;
    float* h    = (float*)base;                                  // n*128 f32
    int*   perm = (int*)(base + (size_t)n * FD * 4);             // E ints
    int*   cnt  = (int*)(base + (size_t)n * FD * 4 + (size_t)E * 4);
    int*   offs = cnt + nbk;                                     // nbk+1 ints
    int*   qctr = offs + nbk + 1;                                // 1 int

    const int* dstp = eidx + E;

    hipMemsetAsync(d_out, 0, (size_t)out_size * sizeof(float), stream);
    hipMemsetAsync(cnt, 0, (size_t)(2 * nbk + 2) * sizeof(int), stream);

    count_kernel<<<2048, 256, 0, stream>>>(dstp, cnt, E);
    scan_kernel<<<1, 64, 0, stream>>>(cnt, offs, nbk);
    scatter_kernel<<<2048, 256, 0, stream>>>(dstp, cnt, perm, E);

    lin1_kernel<<<(n + 15) / 16, 256, 0, stream>>>(x, lin1_w, h, n);

    size_t smem = 90112;   // 88 KB -> 1 block/CU (16 waves)
    hipFuncSetAttribute((const void*)edge_kernel,
                        hipFuncAttributeMaxDynamicSharedMemorySize, (int)smem);
    edge_kernel<<<256, 1024, smem, stream>>>(ew, ea, fw1, fb1, fw2, fb2,
                                             eidx, h, perm, offs, qctr,
                                             out, E, n, nbk);

    final_kernel<<<(n + 15) / 16, 256, 0, stream>>>(out, h, disc_w, lin2_w, lin2_b,
                                                    lin_w, lin_b, out, n);
}

// Round 3
// 1916.265 us; speedup vs baseline: 1.2520x; 1.2520x over previous
//
#include <hip/hip_runtime.h>
#include <math.h>

#define HD 128
#define FD 128
#define RD 64
#define TE 128          // edges per tile
#define RC_CUT 5.0f
#define WIN 16          // dst nodes per bucket window
#define WIN_SHIFT 4

typedef _Float16 half8_t __attribute__((ext_vector_type(8)));
typedef float floatx4 __attribute__((ext_vector_type(4)));

__device__ __forceinline__ float fast_tanh(float x) {
    float ex = __expf(2.0f * x);
    return 1.0f - 2.0f / (ex + 1.0f);
}

// ---------------- lin1: h = x @ lin1_w.T ----------------
__global__ __launch_bounds__(256) void lin1_kernel(const float* __restrict__ x,
                                                   const float* __restrict__ w,
                                                   float* __restrict__ h, int n)
{
    __shared__ float sx[16][HD];
    int base = blockIdx.x * 16;
    for (int i = threadIdx.x; i < 16 * HD; i += 256) {
        int r = i >> 7, c = i & 127;
        int row = base + r;
        sx[r][c] = (row < n) ? x[(size_t)row * HD + c] : 0.0f;
    }
    __syncthreads();
    int f = threadIdx.x & 127;
    int half = threadIdx.x >> 7;
    float acc[8];
#pragma unroll
    for (int r = 0; r < 8; ++r) acc[r] = 0.0f;
    const float* wrow = w + (size_t)f * HD;
    for (int k = 0; k < HD; ++k) {
        float wv = wrow[k];
#pragma unroll
        for (int r = 0; r < 8; ++r) acc[r] += sx[half * 8 + r][k] * wv;
    }
#pragma unroll
    for (int r = 0; r < 8; ++r) {
        int row = base + half * 8 + r;
        if (row < n) h[(size_t)row * FD + f] = acc[r];
    }
}

// ---------------- bucketing: count / scan / scatter ----------------
__global__ __launch_bounds__(256) void count_kernel(const int* __restrict__ dstp,
                                                    int* cnt, int E)
{
    for (int e = blockIdx.x * blockDim.x + threadIdx.x; e < E;
         e += gridDim.x * blockDim.x)
        atomicAdd(&cnt[dstp[e] >> WIN_SHIFT], 1);
}

// single-wave exclusive scan; cnt becomes the cursor copy
__global__ void scan_kernel(int* cnt, int* offs, int nbk)
{
    int lane = threadIdx.x;
    int carry = 0;
    for (int base = 0; base < nbk; base += 64) {
        int i = base + lane;
        int v = (i < nbk) ? cnt[i] : 0;
        int orig = v;
#pragma unroll
        for (int d = 1; d < 64; d <<= 1) {
            int t = __shfl_up(v, d);
            if (lane >= d) v += t;
        }
        if (i < nbk) {
            int excl = carry + v - orig;
            offs[i] = excl;
            cnt[i]  = excl;      // cursor for scatter
        }
        carry += __shfl(v, 63);
    }
    if (lane == 0) offs[nbk] = carry;
}

// writes inv[e] = permuted position, meta[pos] = src | (dst_local << 16)
__global__ __launch_bounds__(256) void scatter_kernel(
    const int* __restrict__ srcp, const int* __restrict__ dstp,
    int* cursor, int* __restrict__ inv, unsigned int* __restrict__ meta, int E)
{
    for (int e = blockIdx.x * blockDim.x + threadIdx.x; e < E;
         e += gridDim.x * blockDim.x) {
        int d = dstp[e];
        int p = atomicAdd(&cursor[d >> WIN_SHIFT], 1);
        inv[e] = p;
        meta[p] = (unsigned int)srcp[e] | ((unsigned int)(d & (WIN - 1)) << 16);
    }
}

// ---------------- shared LDS helpers ----------------
__device__ __forceinline__ half8_t lds_read8(const char* base, int row,
                                             int rowstride, int col) {
    int off = row * rowstride + ((col * 2) ^ ((row & 7) << 4));
    return *(const half8_t*)(base + off);
}

// ==================== PHASE A: filter GEMMs, natural edge order ==============
// LDS (dynamic 80 KB -> 2 blocks/CU, 32 waves/CU):
//   sT @0 (32 KB), sB1 @32768 (16 KB), sB2 @49152 (32 KB)
// Epilogue: scale by cutoff C, cast f16, scatter row e -> Wperm[inv[e]]
// (scattered STORES cross the permutation; all reads stay coalesced)
__global__ __launch_bounds__(1024, 8) void edge_gemm_kernel(
    const float* __restrict__ edge_weight,
    const float* __restrict__ edge_attr,
    const float* __restrict__ fw1, const float* __restrict__ fb1,
    const float* __restrict__ fw2, const float* __restrict__ fb2,
    const int* __restrict__ inv,
    _Float16* __restrict__ Wp,
    int E, int ntiles)
{
    extern __shared__ char smem[];
    char* sT  = smem;
    char* sB1 = smem + 32768;
    char* sB2 = smem + 49152;

    // ---- stage weights once per block (fp32 -> f16, swizzled) ----
    for (int i = threadIdx.x * 8; i < FD * RD; i += blockDim.x * 8) {
        int r = i >> 6, c = i & 63;
        const float4* g = (const float4*)(fw1 + (size_t)r * RD + c);
        float4 v0 = g[0], v1 = g[1];
        half8_t hv;
        hv[0] = (_Float16)v0.x; hv[1] = (_Float16)v0.y;
        hv[2] = (_Float16)v0.z; hv[3] = (_Float16)v0.w;
        hv[4] = (_Float16)v1.x; hv[5] = (_Float16)v1.y;
        hv[6] = (_Float16)v1.z; hv[7] = (_Float16)v1.w;
        *(half8_t*)(sB1 + r * 128 + ((c * 2) ^ ((r & 7) << 4))) = hv;
    }
    for (int i = threadIdx.x * 8; i < FD * FD; i += blockDim.x * 8) {
        int r = i >> 7, c = i & 127;
        const float4* g = (const float4*)(fw2 + (size_t)r * FD + c);
        float4 v0 = g[0], v1 = g[1];
        half8_t hv;
        hv[0] = (_Float16)v0.x; hv[1] = (_Float16)v0.y;
        hv[2] = (_Float16)v0.z; hv[3] = (_Float16)v0.w;
        hv[4] = (_Float16)v1.x; hv[5] = (_Float16)v1.y;
        hv[6] = (_Float16)v1.z; hv[7] = (_Float16)v1.w;
        *(half8_t*)(sB2 + r * 256 + ((c * 2) ^ ((r & 7) << 4))) = hv;
    }
    __syncthreads();

    int lane = threadIdx.x & 63;
    int wid  = threadIdx.x >> 6;   // 0..15
    int wm = wid >> 2;             // 0..3  (edge dim, 32 each)
    int wn = wid & 3;              // 0..3  (filter dim, 32 each)
    int l15 = lane & 15;
    int l4  = lane >> 4;

    float bias1[2], bias2[2];
    int gcol[2];
#pragma unroll
    for (int ni = 0; ni < 2; ++ni) {
        gcol[ni]  = wn * 32 + ni * 16 + l15;
        bias1[ni] = fb1[gcol[ni]];
        bias2[ni] = fb2[gcol[ni]];
    }

    for (int tile = blockIdx.x; tile < ntiles; tile += gridDim.x) {
        int e0 = tile * TE;
        // ---- stage A = edge_attr[e0:e0+128, :] as f16 (coalesced) ----
        for (int i = threadIdx.x * 8; i < TE * RD; i += blockDim.x * 8) {
            int r = i >> 6, c = i & 63;
            half8_t hv;
            if (e0 + r < E) {
                const float4* g = (const float4*)(edge_attr + (size_t)(e0 + r) * RD + c);
                float4 v0 = g[0], v1 = g[1];
                hv[0] = (_Float16)v0.x; hv[1] = (_Float16)v0.y;
                hv[2] = (_Float16)v0.z; hv[3] = (_Float16)v0.w;
                hv[4] = (_Float16)v1.x; hv[5] = (_Float16)v1.y;
                hv[6] = (_Float16)v1.z; hv[7] = (_Float16)v1.w;
            } else {
                for (int q = 0; q < 8; ++q) hv[q] = (_Float16)0.0f;
            }
            *(half8_t*)(sT + r * 128 + ((c * 2) ^ ((r & 7) << 4))) = hv;
        }
        __syncthreads();

        // ---- GEMM1: C1 = A @ fw1^T ----
        floatx4 acc[2][2];
#pragma unroll
        for (int mi = 0; mi < 2; ++mi)
#pragma unroll
            for (int ni = 0; ni < 2; ++ni)
                acc[mi][ni] = (floatx4){0.f, 0.f, 0.f, 0.f};
#pragma unroll
        for (int ks = 0; ks < 2; ++ks) {
            int k = ks * 32 + l4 * 8;
            half8_t a[2], b[2];
#pragma unroll
            for (int mi = 0; mi < 2; ++mi)
                a[mi] = lds_read8(sT, wm * 32 + mi * 16 + l15, 128, k);
#pragma unroll
            for (int ni = 0; ni < 2; ++ni)
                b[ni] = lds_read8(sB1, wn * 32 + ni * 16 + l15, 128, k);
#pragma unroll
            for (int mi = 0; mi < 2; ++mi)
#pragma unroll
                for (int ni = 0; ni < 2; ++ni)
                    acc[mi][ni] = __builtin_amdgcn_mfma_f32_16x16x32_f16(
                        a[mi], b[ni], acc[mi][ni], 0, 0, 0);
        }
        __syncthreads();

        // ---- bias + tanh -> T ----
#pragma unroll
        for (int ni = 0; ni < 2; ++ni) {
            int f = gcol[ni];
            float bias = bias1[ni];
#pragma unroll
            for (int mi = 0; mi < 2; ++mi) {
#pragma unroll
                for (int j = 0; j < 4; ++j) {
                    int e = wm * 32 + mi * 16 + l4 * 4 + j;
                    float t = fast_tanh(acc[mi][ni][j] + bias);
                    *(_Float16*)(sT + e * 256 + ((f * 2) ^ ((e & 7) << 4))) =
                        (_Float16)t;
                }
            }
        }
        __syncthreads();

        // ---- GEMM2: W = T @ fw2^T ----
        floatx4 acc2[2][2];
#pragma unroll
        for (int mi = 0; mi < 2; ++mi)
#pragma unroll
            for (int ni = 0; ni < 2; ++ni)
                acc2[mi][ni] = (floatx4){0.f, 0.f, 0.f, 0.f};
#pragma unroll
        for (int ks = 0; ks < 4; ++ks) {
            int k = ks * 32 + l4 * 8;
            half8_t a[2], b[2];
#pragma unroll
            for (int mi = 0; mi < 2; ++mi)
                a[mi] = lds_read8(sT, wm * 32 + mi * 16 + l15, 256, k);
#pragma unroll
            for (int ni = 0; ni < 2; ++ni)
                b[ni] = lds_read8(sB2, wn * 32 + ni * 16 + l15, 256, k);
#pragma unroll
            for (int mi = 0; mi < 2; ++mi)
#pragma unroll
                for (int ni = 0; ni < 2; ++ni)
                    acc2[mi][ni] = __builtin_amdgcn_mfma_f32_16x16x32_f16(
                        a[mi], b[ni], acc2[mi][ni], 0, 0, 0);
        }
        __syncthreads();

        // ---- epilogue: scale by cutoff, cast f16, scatter to Wperm rows ----
#pragma unroll
        for (int mi = 0; mi < 2; ++mi) {
            int ge[4], pv[4];
            float d4[4];
#pragma unroll
            for (int j = 0; j < 4; ++j) {
                int el = wm * 32 + mi * 16 + l4 * 4 + j;
                ge[j] = e0 + el;
                int idx = (ge[j] < E) ? ge[j] : (E - 1);
                d4[j] = edge_weight[idx];
                pv[j] = inv[idx];
            }
#pragma unroll
            for (int j = 0; j < 4; ++j) {
                if (ge[j] >= E) continue;
                float C = (d4[j] < RC_CUT)
                            ? 0.5f * (__cosf(d4[j] * 0.6283185307179586f) + 1.0f)
                            : 0.0f;
                _Float16* wr = Wp + (size_t)pv[j] * FD;
#pragma unroll
                for (int ni = 0; ni < 2; ++ni)
                    wr[gcol[ni]] = (_Float16)((acc2[mi][ni][j] + bias2[ni]) * C);
            }
        }
    }
}

// ==================== PHASE B: aggregate per dst-window ======================
// One block per bucket; Wperm rows read COALESCED (contiguous in perm order);
// only h[src] is a gather (L3-resident). 8 KB LDS -> 8 blocks/CU (full TLP).
__global__ __launch_bounds__(256) void agg_kernel(
    const _Float16* __restrict__ Wp,
    const unsigned int* __restrict__ meta,
    const int* __restrict__ offs,
    const float* __restrict__ h,
    float* __restrict__ agg, int n)
{
    __shared__ float sAgg[WIN * FD];
    for (int i = threadIdx.x; i < WIN * FD; i += 256) sAgg[i] = 0.0f;
    __syncthreads();

    int bkt = blockIdx.x;
    int o0 = offs[bkt];
    int nE = offs[bkt + 1] - o0;
    int lane = threadIdx.x & 63;
    int wv = threadIdx.x >> 6;

    for (int i = wv; i < nE; i += 4) {
        int p = o0 + i;
        unsigned int m = meta[p];
        int src = m & 0xFFFF;
        int lr = m >> 16;
        const _Float16* wr = Wp + (size_t)p * FD;
        float w0 = (float)wr[lane];
        float w1 = (float)wr[64 + lane];
        const float* hr = h + (size_t)src * FD;
        float h0 = hr[lane];
        float h1 = hr[64 + lane];
        atomicAdd(&sAgg[lr * FD + lane], w0 * h0);
        atomicAdd(&sAgg[lr * FD + 64 + lane], w1 * h1);
    }
    __syncthreads();

    int r0 = bkt << WIN_SHIFT;
    for (int i = threadIdx.x; i < WIN * FD; i += 256) {
        int r = i >> 7;
        if (r0 + r < n) agg[(size_t)(r0 + r) * FD + (i & 127)] = sAgg[i];
    }
}

// ==================== FALLBACK: R1 fused kernel (global atomics) =============
__global__ __launch_bounds__(1024, 8) void edge_kernel_atomic(
    const float* __restrict__ edge_weight,
    const float* __restrict__ edge_attr,
    const float* __restrict__ fw1, const float* __restrict__ fb1,
    const float* __restrict__ fw2, const float* __restrict__ fb2,
    const int* __restrict__ eidx,
    const float* __restrict__ h,
    float* agg, int E, int ntiles)
{
    extern __shared__ char smem[];
    char* sT  = smem;
    char* sB1 = smem + 32768;
    char* sB2 = smem + 49152;

    for (int i = threadIdx.x * 8; i < FD * RD; i += blockDim.x * 8) {
        int r = i >> 6, c = i & 63;
        const float4* g = (const float4*)(fw1 + (size_t)r * RD + c);
        float4 v0 = g[0], v1 = g[1];
        half8_t hv;
        hv[0] = (_Float16)v0.x; hv[1] = (_Float16)v0.y;
        hv[2] = (_Float16)v0.z; hv[3] = (_Float16)v0.w;
        hv[4] = (_Float16)v1.x; hv[5] = (_Float16)v1.y;
        hv[6] = (_Float16)v1.z; hv[7] = (_Float16)v1.w;
        *(half8_t*)(sB1 + r * 128 + ((c * 2) ^ ((r & 7) << 4))) = hv;
    }
    for (int i = threadIdx.x * 8; i < FD * FD; i += blockDim.x * 8) {
        int r = i >> 7, c = i & 127;
        const float4* g = (const float4*)(fw2 + (size_t)r * FD + c);
        float4 v0 = g[0], v1 = g[1];
        half8_t hv;
        hv[0] = (_Float16)v0.x; hv[1] = (_Float16)v0.y;
        hv[2] = (_Float16)v0.z; hv[3] = (_Float16)v0.w;
        hv[4] = (_Float16)v1.x; hv[5] = (_Float16)v1.y;
        hv[6] = (_Float16)v1.z; hv[7] = (_Float16)v1.w;
        *(half8_t*)(sB2 + r * 256 + ((c * 2) ^ ((r & 7) << 4))) = hv;
    }
    __syncthreads();

    const int* srcp = eidx;
    const int* dstp = eidx + E;
    int lane = threadIdx.x & 63;
    int wid  = threadIdx.x >> 6;
    int wm = wid >> 2;
    int wn = wid & 3;
    int l15 = lane & 15;
    int l4  = lane >> 4;

    for (int tile = blockIdx.x; tile < ntiles; tile += gridDim.x) {
        int e0 = tile * TE;
        for (int i = threadIdx.x * 8; i < TE * RD; i += blockDim.x * 8) {
            int r = i >> 6, c = i & 63;
            half8_t hv;
            if (e0 + r < E) {
                const float4* g = (const float4*)(edge_attr + (size_t)(e0 + r) * RD + c);
                float4 v0 = g[0], v1 = g[1];
                hv[0] = (_Float16)v0.x; hv[1] = (_Float16)v0.y;
                hv[2] = (_Float16)v0.z; hv[3] = (_Float16)v0.w;
                hv[4] = (_Float16)v1.x; hv[5] = (_Float16)v1.y;
                hv[6] = (_Float16)v1.z; hv[7] = (_Float16)v1.w;
            } else {
                for (int q = 0; q < 8; ++q) hv[q] = (_Float16)0.0f;
            }
            *(half8_t*)(sT + r * 128 + ((c * 2) ^ ((r & 7) << 4))) = hv;
        }
        __syncthreads();

        floatx4 acc[2][2];
#pragma unroll
        for (int mi = 0; mi < 2; ++mi)
#pragma unroll
            for (int ni = 0; ni < 2; ++ni)
                acc[mi][ni] = (floatx4){0.f, 0.f, 0.f, 0.f};
#pragma unroll
        for (int ks = 0; ks < 2; ++ks) {
            int k = ks * 32 + l4 * 8;
            half8_t a[2], b[2];
#pragma unroll
            for (int mi = 0; mi < 2; ++mi)
                a[mi] = lds_read8(sT, wm * 32 + mi * 16 + l15, 128, k);
#pragma unroll
            for (int ni = 0; ni < 2; ++ni)
                b[ni] = lds_read8(sB1, wn * 32 + ni * 16 + l15, 128, k);
#pragma unroll
            for (int mi = 0; mi < 2; ++mi)
#pragma unroll
                for (int ni = 0; ni < 2; ++ni)
                    acc[mi][ni] = __builtin_amdgcn_mfma_f32_16x16x32_f16(
                        a[mi], b[ni], acc[mi][ni], 0, 0, 0);
        }
        __syncthreads();

#pragma unroll
        for (int ni = 0; ni < 2; ++ni) {
            int f = wn * 32 + ni * 16 + l15;
            float bias = fb1[f];
#pragma unroll
            for (int mi = 0; mi < 2; ++mi) {
#pragma unroll
                for (int j = 0; j < 4; ++j) {
                    int e = wm * 32 + mi * 16 + l4 * 4 + j;
                    float t = fast_tanh(acc[mi][ni][j] + bias);
                    *(_Float16*)(sT + e * 256 + ((f * 2) ^ ((e & 7) << 4))) =
                        (_Float16)t;
                }
            }
        }
        __syncthreads();

        floatx4 acc2[2][2];
#pragma unroll
        for (int mi = 0; mi < 2; ++mi)
#pragma unroll
            for (int ni = 0; ni < 2; ++ni)
                acc2[mi][ni] = (floatx4){0.f, 0.f, 0.f, 0.f};
#pragma unroll
        for (int ks = 0; ks < 4; ++ks) {
            int k = ks * 32 + l4 * 8;
            half8_t a[2], b[2];
#pragma unroll
            for (int mi = 0; mi < 2; ++mi)
                a[mi] = lds_read8(sT, wm * 32 + mi * 16 + l15, 256, k);
#pragma unroll
            for (int ni = 0; ni < 2; ++ni)
                b[ni] = lds_read8(sB2, wn * 32 + ni * 16 + l15, 256, k);
#pragma unroll
            for (int mi = 0; mi < 2; ++mi)
#pragma unroll
                for (int ni = 0; ni < 2; ++ni)
                    acc2[mi][ni] = __builtin_amdgcn_mfma_f32_16x16x32_f16(
                        a[mi], b[ni], acc2[mi][ni], 0, 0, 0);
        }
        __syncthreads();

        float bias2[2];
        int gcol[2];
#pragma unroll
        for (int ni = 0; ni < 2; ++ni) {
            gcol[ni] = wn * 32 + ni * 16 + l15;
            bias2[ni] = fb2[gcol[ni]];
        }
#pragma unroll
        for (int mi = 0; mi < 2; ++mi) {
            int ge[4], s4[4], dn4[4];
            float d4[4];
#pragma unroll
            for (int j = 0; j < 4; ++j) {
                int el = wm * 32 + mi * 16 + l4 * 4 + j;
                ge[j] = e0 + el;
                int idx = (ge[j] < E) ? ge[j] : (E - 1);
                s4[j]  = srcp[idx];
                dn4[j] = dstp[idx];
                d4[j]  = edge_weight[idx];
            }
#pragma unroll
            for (int j = 0; j < 4; ++j) {
                if (ge[j] >= E) continue;
                float C = (d4[j] < RC_CUT)
                            ? 0.5f * (__cosf(d4[j] * 0.6283185307179586f) + 1.0f)
                            : 0.0f;
                const float* hrow = h + (size_t)s4[j] * FD;
                float* ar = agg + (size_t)dn4[j] * FD;
#pragma unroll
                for (int ni = 0; ni < 2; ++ni) {
                    int g = gcol[ni];
                    float wv = (acc2[mi][ni][j] + bias2[ni]) * C;
                    atomicAdd(ar + g, wv * hrow[g]);
                }
            }
        }
    }
}

// ---------------- final: disc conv + lin2 + tanh + lin ----------------
__global__ __launch_bounds__(256) void final_kernel(
    const float* aggin, const float* __restrict__ h,
    const float* __restrict__ disc_w,
    const float* __restrict__ lin2_w, const float* __restrict__ lin2_b,
    const float* __restrict__ lin_w, const float* __restrict__ lin_b,
    float* out, int n)
{
    __shared__ float sg[16][FD];
    __shared__ float sm[16][FD];
    int base = blockIdx.x * 16;
    for (int i = threadIdx.x; i < 16 * FD; i += 256) {
        int r = i >> 7, c = i & 127;
        int row = base + r;
        float v = 0.0f;
        if (row < n) {
            v = aggin[(size_t)row * FD + c] + disc_w[c] * h[(size_t)row * FD + c];
            if (row + 1 < n) v += disc_w[FD + c] * h[(size_t)(row + 1) * FD + c];
            if (row >= 1)    v += disc_w[2 * FD + c] * h[(size_t)(row - 1) * FD + c];
        }
        sg[r][c] = v;
    }
    __syncthreads();
    int f = threadIdx.x & 127;
    int half = threadIdx.x >> 7;
    {
        float acc[8];
        float b = lin2_b[f];
#pragma unroll
        for (int r = 0; r < 8; ++r) acc[r] = b;
        const float* wrow = lin2_w + (size_t)f * FD;
        for (int k = 0; k < FD; ++k) {
            float wv = wrow[k];
#pragma unroll
            for (int r = 0; r < 8; ++r) acc[r] += sg[half * 8 + r][k] * wv;
        }
#pragma unroll
        for (int r = 0; r < 8; ++r) sm[half * 8 + r][f] = fast_tanh(acc[r]);
    }
    __syncthreads();
    {
        float acc[8];
        float b = lin_b[f];
#pragma unroll
        for (int r = 0; r < 8; ++r) acc[r] = b;
        const float* wrow = lin_w + (size_t)f * HD;
        for (int k = 0; k < FD; ++k) {
            float wv = wrow[k];
#pragma unroll
            for (int r = 0; r < 8; ++r) acc[r] += sm[half * 8 + r][k] * wv;
        }
#pragma unroll
        for (int r = 0; r < 8; ++r) {
            int row = base + half * 8 + r;
            if (row < n) out[(size_t)row * HD + f] = acc[r];
        }
    }
}

extern "C" void kernel_launch(void* const* d_in, const int* in_sizes, int n_in,
                              void* d_out, int out_size, void* d_ws, size_t ws_size,
                              hipStream_t stream)
{
    const float* x      = (const float*)d_in[0];
    const float* ew     = (const float*)d_in[1];
    const float* ea     = (const float*)d_in[2];
    const float* fw1    = (const float*)d_in[3];
    const float* fb1    = (const float*)d_in[4];
    const float* fw2    = (const float*)d_in[5];
    const float* fb2    = (const float*)d_in[6];
    const float* lin1_w = (const float*)d_in[7];
    const float* lin2_w = (const float*)d_in[8];
    const float* lin2_b = (const float*)d_in[9];
    const float* disc_w = (const float*)d_in[10];
    const float* lin_w  = (const float*)d_in[11];
    const float* lin_b  = (const float*)d_in[12];
    const int*   eidx   = (const int*)d_in[13];

    int n = in_sizes[0] / HD;
    int E = in_sizes[1];
    int nbk = (n + WIN - 1) / WIN;
    int ntiles = (E + TE - 1) / TE;
    float* out = (float*)d_out;

    const int* srcp = eidx;
    const int* dstp = eidx + E;

    // workspace layout (all 16B-aligned sections)
    char* base = (char*)d_ws;
    float*     h    = (float*)base;                       // n*128 f32
    size_t off_h    = (size_t)n * FD * 4;
    _Float16*  Wp   = (_Float16*)(base + off_h);          // E*128 f16
    size_t off_w    = off_h + (size_t)E * FD * 2;
    int*       inv  = (int*)(base + off_w);               // E ints
    size_t off_i    = off_w + (size_t)E * 4;
    unsigned int* meta = (unsigned int*)(base + off_i);   // E u32
    size_t off_m    = off_i + (size_t)E * 4;
    int*       cnt  = (int*)(base + off_m);               // nbk ints
    int*       offs = cnt + nbk;                          // nbk+1 ints
    size_t need     = off_m + (size_t)(2 * nbk + 8) * 4;

    hipMemsetAsync(d_out, 0, (size_t)out_size * sizeof(float), stream);
    lin1_kernel<<<(n + 15) / 16, 256, 0, stream>>>(x, lin1_w, h, n);

    size_t smem = 81920;   // 80 KB -> 2 blocks/CU
    if (ws_size >= need && n <= 65535) {
        // ---------- two-phase path: no global float atomics ----------
        hipMemsetAsync(cnt, 0, (size_t)(2 * nbk + 2) * sizeof(int), stream);
        count_kernel<<<2048, 256, 0, stream>>>(dstp, cnt, E);
        scan_kernel<<<1, 64, 0, stream>>>(cnt, offs, nbk);
        scatter_kernel<<<2048, 256, 0, stream>>>(srcp, dstp, cnt, inv, meta, E);

        hipFuncSetAttribute((const void*)edge_gemm_kernel,
                            hipFuncAttributeMaxDynamicSharedMemorySize, (int)smem);
        int nblocks = ntiles < 512 ? ntiles : 512;
        edge_gemm_kernel<<<nblocks, 1024, smem, stream>>>(ew, ea, fw1, fb1, fw2, fb2,
                                                          inv, Wp, E, ntiles);

        agg_kernel<<<nbk, 256, 0, stream>>>(Wp, meta, offs, h, out, n);
    } else {
        // ---------- fallback: proven fused atomic kernel ----------
        hipFuncSetAttribute((const void*)edge_kernel_atomic,
                            hipFuncAttributeMaxDynamicSharedMemorySize, (int)smem);
        int nblocks = ntiles < 512 ? ntiles : 512;
        edge_kernel_atomic<<<nblocks, 1024, smem, stream>>>(ew, ea, fw1, fb1, fw2, fb2,
                                                            eidx, h, out, E, ntiles);
    }

    final_kernel<<<(n + 15) / 16, 256, 0, stream>>>(out, h, disc_w, lin2_w, lin2_b,
                                                    lin_w, lin_b, out, n);
}

// Round 4
// 1458.078 us; speedup vs baseline: 1.6454x; 1.3142x over previous
//
#include <hip/hip_runtime.h>
#include <math.h>

#define HD 128
#define FD 128
#define RD 64
#define TE 128          // edges per tile
#define RC_CUT 5.0f
#define CH 64           // permuted positions per 16-lane group (phase B)

typedef _Float16 half8_t __attribute__((ext_vector_type(8)));
typedef float floatx4 __attribute__((ext_vector_type(4)));

__device__ __forceinline__ float fast_tanh(float x) {
    float ex = __expf(2.0f * x);
    return 1.0f - 2.0f / (ex + 1.0f);
}

// ---------------- lin1: h = x @ lin1_w.T ----------------
__global__ __launch_bounds__(256) void lin1_kernel(const float* __restrict__ x,
                                                   const float* __restrict__ w,
                                                   float* __restrict__ h, int n)
{
    __shared__ float sx[16][HD];
    int base = blockIdx.x * 16;
    for (int i = threadIdx.x; i < 16 * HD; i += 256) {
        int r = i >> 7, c = i & 127;
        int row = base + r;
        sx[r][c] = (row < n) ? x[(size_t)row * HD + c] : 0.0f;
    }
    __syncthreads();
    int f = threadIdx.x & 127;
    int half = threadIdx.x >> 7;
    float acc[8];
#pragma unroll
    for (int r = 0; r < 8; ++r) acc[r] = 0.0f;
    const float* wrow = w + (size_t)f * HD;
    for (int k = 0; k < HD; ++k) {
        float wv = wrow[k];
#pragma unroll
        for (int r = 0; r < 8; ++r) acc[r] += sx[half * 8 + r][k] * wv;
    }
#pragma unroll
    for (int r = 0; r < 8; ++r) {
        int row = base + half * 8 + r;
        if (row < n) h[(size_t)row * FD + f] = acc[r];
    }
}

// ---------------- bucketing by dst: count / scan / scatter ----------------
__global__ __launch_bounds__(256) void count_kernel(const int* __restrict__ dstp,
                                                    int* cnt, int E)
{
    for (int e = blockIdx.x * blockDim.x + threadIdx.x; e < E;
         e += gridDim.x * blockDim.x)
        atomicAdd(&cnt[dstp[e]], 1);
}

// single-wave exclusive scan; cnt becomes the cursor copy
__global__ void scan_kernel(int* cnt, int* offs, int nbk)
{
    int lane = threadIdx.x;
    int carry = 0;
    for (int base = 0; base < nbk; base += 64) {
        int i = base + lane;
        int v = (i < nbk) ? cnt[i] : 0;
        int orig = v;
#pragma unroll
        for (int d = 1; d < 64; d <<= 1) {
            int t = __shfl_up(v, d);
            if (lane >= d) v += t;
        }
        if (i < nbk) {
            int excl = carry + v - orig;
            offs[i] = excl;
            cnt[i]  = excl;      // cursor for scatter
        }
        carry += __shfl(v, 63);
    }
    if (lane == 0) offs[nbk] = carry;
}

// inv[e] = permuted position; meta[pos] = src | (dst << 16)
__global__ __launch_bounds__(256) void scatter_kernel(
    const int* __restrict__ srcp, const int* __restrict__ dstp,
    int* cursor, int* __restrict__ inv, unsigned int* __restrict__ meta, int E)
{
    for (int e = blockIdx.x * blockDim.x + threadIdx.x; e < E;
         e += gridDim.x * blockDim.x) {
        int d = dstp[e];
        int p = atomicAdd(&cursor[d], 1);
        inv[e] = p;
        meta[p] = (unsigned int)srcp[e] | ((unsigned int)d << 16);
    }
}

// ---------------- shared LDS helpers ----------------
__device__ __forceinline__ half8_t lds_read8(const char* base, int row,
                                             int rowstride, int col) {
    int off = row * rowstride + ((col * 2) ^ ((row & 7) << 4));
    return *(const half8_t*)(base + off);
}

// ==================== PHASE A: filter GEMMs, natural edge order ==============
// LDS (dynamic 80 KB -> 2 blocks/CU): sT @0 (32 KB), sB1 @32768, sB2 @49152
// Epilogue: C-scale -> f16 rows in sT -> scatter WHOLE rows (half8 chunks)
// to Wp[inv[e]]. 16-B stores, full sectors; reads all stay coalesced.
__global__ __launch_bounds__(1024, 8) void edge_gemm_kernel(
    const float* __restrict__ edge_weight,
    const float* __restrict__ edge_attr,
    const float* __restrict__ fw1, const float* __restrict__ fb1,
    const float* __restrict__ fw2, const float* __restrict__ fb2,
    const int* __restrict__ inv,
    _Float16* __restrict__ Wp,
    int E, int ntiles)
{
    extern __shared__ char smem[];
    char* sT  = smem;
    char* sB1 = smem + 32768;
    char* sB2 = smem + 49152;

    // ---- stage weights once per block (fp32 -> f16, swizzled) ----
    for (int i = threadIdx.x * 8; i < FD * RD; i += blockDim.x * 8) {
        int r = i >> 6, c = i & 63;
        const float4* g = (const float4*)(fw1 + (size_t)r * RD + c);
        float4 v0 = g[0], v1 = g[1];
        half8_t hv;
        hv[0] = (_Float16)v0.x; hv[1] = (_Float16)v0.y;
        hv[2] = (_Float16)v0.z; hv[3] = (_Float16)v0.w;
        hv[4] = (_Float16)v1.x; hv[5] = (_Float16)v1.y;
        hv[6] = (_Float16)v1.z; hv[7] = (_Float16)v1.w;
        *(half8_t*)(sB1 + r * 128 + ((c * 2) ^ ((r & 7) << 4))) = hv;
    }
    for (int i = threadIdx.x * 8; i < FD * FD; i += blockDim.x * 8) {
        int r = i >> 7, c = i & 127;
        const float4* g = (const float4*)(fw2 + (size_t)r * FD + c);
        float4 v0 = g[0], v1 = g[1];
        half8_t hv;
        hv[0] = (_Float16)v0.x; hv[1] = (_Float16)v0.y;
        hv[2] = (_Float16)v0.z; hv[3] = (_Float16)v0.w;
        hv[4] = (_Float16)v1.x; hv[5] = (_Float16)v1.y;
        hv[6] = (_Float16)v1.z; hv[7] = (_Float16)v1.w;
        *(half8_t*)(sB2 + r * 256 + ((c * 2) ^ ((r & 7) << 4))) = hv;
    }
    __syncthreads();

    int lane = threadIdx.x & 63;
    int wid  = threadIdx.x >> 6;   // 0..15
    int wm = wid >> 2;             // 0..3  (edge dim, 32 each)
    int wn = wid & 3;              // 0..3  (filter dim, 32 each)
    int l15 = lane & 15;
    int l4  = lane >> 4;

    float bias1[2], bias2[2];
    int gcol[2];
#pragma unroll
    for (int ni = 0; ni < 2; ++ni) {
        gcol[ni]  = wn * 32 + ni * 16 + l15;
        bias1[ni] = fb1[gcol[ni]];
        bias2[ni] = fb2[gcol[ni]];
    }

    for (int tile = blockIdx.x; tile < ntiles; tile += gridDim.x) {
        int e0 = tile * TE;
        // ---- stage A = edge_attr[e0:e0+128, :] as f16 (coalesced) ----
        for (int i = threadIdx.x * 8; i < TE * RD; i += blockDim.x * 8) {
            int r = i >> 6, c = i & 63;
            half8_t hv;
            if (e0 + r < E) {
                const float4* g = (const float4*)(edge_attr + (size_t)(e0 + r) * RD + c);
                float4 v0 = g[0], v1 = g[1];
                hv[0] = (_Float16)v0.x; hv[1] = (_Float16)v0.y;
                hv[2] = (_Float16)v0.z; hv[3] = (_Float16)v0.w;
                hv[4] = (_Float16)v1.x; hv[5] = (_Float16)v1.y;
                hv[6] = (_Float16)v1.z; hv[7] = (_Float16)v1.w;
            } else {
                for (int q = 0; q < 8; ++q) hv[q] = (_Float16)0.0f;
            }
            *(half8_t*)(sT + r * 128 + ((c * 2) ^ ((r & 7) << 4))) = hv;
        }
        __syncthreads();

        // ---- GEMM1: C1 = A @ fw1^T ----
        floatx4 acc[2][2];
#pragma unroll
        for (int mi = 0; mi < 2; ++mi)
#pragma unroll
            for (int ni = 0; ni < 2; ++ni)
                acc[mi][ni] = (floatx4){0.f, 0.f, 0.f, 0.f};
#pragma unroll
        for (int ks = 0; ks < 2; ++ks) {
            int k = ks * 32 + l4 * 8;
            half8_t a[2], b[2];
#pragma unroll
            for (int mi = 0; mi < 2; ++mi)
                a[mi] = lds_read8(sT, wm * 32 + mi * 16 + l15, 128, k);
#pragma unroll
            for (int ni = 0; ni < 2; ++ni)
                b[ni] = lds_read8(sB1, wn * 32 + ni * 16 + l15, 128, k);
#pragma unroll
            for (int mi = 0; mi < 2; ++mi)
#pragma unroll
                for (int ni = 0; ni < 2; ++ni)
                    acc[mi][ni] = __builtin_amdgcn_mfma_f32_16x16x32_f16(
                        a[mi], b[ni], acc[mi][ni], 0, 0, 0);
        }
        __syncthreads();

        // ---- bias + tanh -> T ----
#pragma unroll
        for (int ni = 0; ni < 2; ++ni) {
            int f = gcol[ni];
            float bias = bias1[ni];
#pragma unroll
            for (int mi = 0; mi < 2; ++mi) {
#pragma unroll
                for (int j = 0; j < 4; ++j) {
                    int e = wm * 32 + mi * 16 + l4 * 4 + j;
                    float t = fast_tanh(acc[mi][ni][j] + bias);
                    *(_Float16*)(sT + e * 256 + ((f * 2) ^ ((e & 7) << 4))) =
                        (_Float16)t;
                }
            }
        }
        __syncthreads();

        // ---- GEMM2: W = T @ fw2^T ----
        floatx4 acc2[2][2];
#pragma unroll
        for (int mi = 0; mi < 2; ++mi)
#pragma unroll
            for (int ni = 0; ni < 2; ++ni)
                acc2[mi][ni] = (floatx4){0.f, 0.f, 0.f, 0.f};
#pragma unroll
        for (int ks = 0; ks < 4; ++ks) {
            int k = ks * 32 + l4 * 8;
            half8_t a[2], b[2];
#pragma unroll
            for (int mi = 0; mi < 2; ++mi)
                a[mi] = lds_read8(sT, wm * 32 + mi * 16 + l15, 256, k);
#pragma unroll
            for (int ni = 0; ni < 2; ++ni)
                b[ni] = lds_read8(sB2, wn * 32 + ni * 16 + l15, 256, k);
#pragma unroll
            for (int mi = 0; mi < 2; ++mi)
#pragma unroll
                for (int ni = 0; ni < 2; ++ni)
                    acc2[mi][ni] = __builtin_amdgcn_mfma_f32_16x16x32_f16(
                        a[mi], b[ni], acc2[mi][ni], 0, 0, 0);
        }
        __syncthreads();   // T consumed; sT reused as W row buffer

        // ---- epilogue 1: cutoff-scale, write f16 W rows into sT ----
#pragma unroll
        for (int mi = 0; mi < 2; ++mi) {
            float d4[4];
#pragma unroll
            for (int j = 0; j < 4; ++j) {
                int el = wm * 32 + mi * 16 + l4 * 4 + j;
                int idx = (e0 + el < E) ? (e0 + el) : (E - 1);
                d4[j] = edge_weight[idx];
            }
#pragma unroll
            for (int j = 0; j < 4; ++j) {
                int el = wm * 32 + mi * 16 + l4 * 4 + j;
                float C = (d4[j] < RC_CUT)
                            ? 0.5f * (__cosf(d4[j] * 0.6283185307179586f) + 1.0f)
                            : 0.0f;
#pragma unroll
                for (int ni = 0; ni < 2; ++ni) {
                    int f = gcol[ni];
                    float wv = (acc2[mi][ni][j] + bias2[ni]) * C;
                    *(_Float16*)(sT + el * 256 + ((f * 2) ^ ((el & 7) << 4))) =
                        (_Float16)wv;
                }
            }
        }
        __syncthreads();

        // ---- epilogue 2: scatter whole rows to Wp (16-B chunks) ----
#pragma unroll
        for (int k = 0; k < 2; ++k) {
            int t = threadIdx.x + k * 1024;
            int r = t >> 4, ch = t & 15;
            int e = e0 + r;
            if (e < E) {
                half8_t v = lds_read8(sT, r, 256, ch * 8);
                int pv = inv[e];
                *(half8_t*)(Wp + (size_t)pv * FD + ch * 8) = v;
            }
        }
        __syncthreads();   // sT fully consumed; next tile may overwrite
    }
}

// ==================== PHASE B: dst-sorted register aggregation ===============
// 16-lane group owns CH consecutive permuted positions (sorted by dst).
// Lane lg handles cols [lg*8, lg*8+8): half8 Wp load (coalesced streaming),
// 2x float4 h load (L3 gather), register accumulate; flush on dst change
// with 8 global atomics per lane (~9.6M total vs 204.8M in the naive path).
__global__ __launch_bounds__(256) void agg_kernel(
    const _Float16* __restrict__ Wp,
    const unsigned int* __restrict__ meta,
    const float* __restrict__ h,
    float* __restrict__ agg, int E)
{
    int gid = (blockIdx.x * 256 + (int)threadIdx.x) >> 4;
    int lg  = threadIdx.x & 15;
    int p0 = gid * CH;
    if (p0 >= E) return;
    int pend = p0 + CH < E ? p0 + CH : E;

    float acc[8];
#pragma unroll
    for (int q = 0; q < 8; ++q) acc[q] = 0.0f;

    unsigned m = meta[p0];
    for (int p = p0; p < pend; ++p) {
        int src = (int)(m & 0xFFFFu);
        unsigned d = m >> 16;
        half8_t w = *(const half8_t*)(Wp + (size_t)p * FD + lg * 8);
        const float* hr = h + (size_t)src * FD + lg * 8;
        float4 h0 = *(const float4*)(hr);
        float4 h1 = *(const float4*)(hr + 4);
        acc[0] += (float)w[0] * h0.x;
        acc[1] += (float)w[1] * h0.y;
        acc[2] += (float)w[2] * h0.z;
        acc[3] += (float)w[3] * h0.w;
        acc[4] += (float)w[4] * h1.x;
        acc[5] += (float)w[5] * h1.y;
        acc[6] += (float)w[6] * h1.z;
        acc[7] += (float)w[7] * h1.w;
        unsigned mn = (p + 1 < pend) ? meta[p + 1] : 0xFFFFFFFFu;
        if ((mn >> 16) != d) {
            float* ar = agg + (size_t)d * FD + lg * 8;
#pragma unroll
            for (int q = 0; q < 8; ++q) { atomicAdd(ar + q, acc[q]); acc[q] = 0.0f; }
        }
        m = mn;
    }
}

// ==================== FALLBACK: fused kernel (global atomics) ================
__global__ __launch_bounds__(1024, 8) void edge_kernel_atomic(
    const float* __restrict__ edge_weight,
    const float* __restrict__ edge_attr,
    const float* __restrict__ fw1, const float* __restrict__ fb1,
    const float* __restrict__ fw2, const float* __restrict__ fb2,
    const int* __restrict__ eidx,
    const float* __restrict__ h,
    float* agg, int E, int ntiles)
{
    extern __shared__ char smem[];
    char* sT  = smem;
    char* sB1 = smem + 32768;
    char* sB2 = smem + 49152;

    for (int i = threadIdx.x * 8; i < FD * RD; i += blockDim.x * 8) {
        int r = i >> 6, c = i & 63;
        const float4* g = (const float4*)(fw1 + (size_t)r * RD + c);
        float4 v0 = g[0], v1 = g[1];
        half8_t hv;
        hv[0] = (_Float16)v0.x; hv[1] = (_Float16)v0.y;
        hv[2] = (_Float16)v0.z; hv[3] = (_Float16)v0.w;
        hv[4] = (_Float16)v1.x; hv[5] = (_Float16)v1.y;
        hv[6] = (_Float16)v1.z; hv[7] = (_Float16)v1.w;
        *(half8_t*)(sB1 + r * 128 + ((c * 2) ^ ((r & 7) << 4))) = hv;
    }
    for (int i = threadIdx.x * 8; i < FD * FD; i += blockDim.x * 8) {
        int r = i >> 7, c = i & 127;
        const float4* g = (const float4*)(fw2 + (size_t)r * FD + c);
        float4 v0 = g[0], v1 = g[1];
        half8_t hv;
        hv[0] = (_Float16)v0.x; hv[1] = (_Float16)v0.y;
        hv[2] = (_Float16)v0.z; hv[3] = (_Float16)v0.w;
        hv[4] = (_Float16)v1.x; hv[5] = (_Float16)v1.y;
        hv[6] = (_Float16)v1.z; hv[7] = (_Float16)v1.w;
        *(half8_t*)(sB2 + r * 256 + ((c * 2) ^ ((r & 7) << 4))) = hv;
    }
    __syncthreads();

    const int* srcp = eidx;
    const int* dstp = eidx + E;
    int lane = threadIdx.x & 63;
    int wid  = threadIdx.x >> 6;
    int wm = wid >> 2;
    int wn = wid & 3;
    int l15 = lane & 15;
    int l4  = lane >> 4;

    for (int tile = blockIdx.x; tile < ntiles; tile += gridDim.x) {
        int e0 = tile * TE;
        for (int i = threadIdx.x * 8; i < TE * RD; i += blockDim.x * 8) {
            int r = i >> 6, c = i & 63;
            half8_t hv;
            if (e0 + r < E) {
                const float4* g = (const float4*)(edge_attr + (size_t)(e0 + r) * RD + c);
                float4 v0 = g[0], v1 = g[1];
                hv[0] = (_Float16)v0.x; hv[1] = (_Float16)v0.y;
                hv[2] = (_Float16)v0.z; hv[3] = (_Float16)v0.w;
                hv[4] = (_Float16)v1.x; hv[5] = (_Float16)v1.y;
                hv[6] = (_Float16)v1.z; hv[7] = (_Float16)v1.w;
            } else {
                for (int q = 0; q < 8; ++q) hv[q] = (_Float16)0.0f;
            }
            *(half8_t*)(sT + r * 128 + ((c * 2) ^ ((r & 7) << 4))) = hv;
        }
        __syncthreads();

        floatx4 acc[2][2];
#pragma unroll
        for (int mi = 0; mi < 2; ++mi)
#pragma unroll
            for (int ni = 0; ni < 2; ++ni)
                acc[mi][ni] = (floatx4){0.f, 0.f, 0.f, 0.f};
#pragma unroll
        for (int ks = 0; ks < 2; ++ks) {
            int k = ks * 32 + l4 * 8;
            half8_t a[2], b[2];
#pragma unroll
            for (int mi = 0; mi < 2; ++mi)
                a[mi] = lds_read8(sT, wm * 32 + mi * 16 + l15, 128, k);
#pragma unroll
            for (int ni = 0; ni < 2; ++ni)
                b[ni] = lds_read8(sB1, wn * 32 + ni * 16 + l15, 128, k);
#pragma unroll
            for (int mi = 0; mi < 2; ++mi)
#pragma unroll
                for (int ni = 0; ni < 2; ++ni)
                    acc[mi][ni] = __builtin_amdgcn_mfma_f32_16x16x32_f16(
                        a[mi], b[ni], acc[mi][ni], 0, 0, 0);
        }
        __syncthreads();

#pragma unroll
        for (int ni = 0; ni < 2; ++ni) {
            int f = wn * 32 + ni * 16 + l15;
            float bias = fb1[f];
#pragma unroll
            for (int mi = 0; mi < 2; ++mi) {
#pragma unroll
                for (int j = 0; j < 4; ++j) {
                    int e = wm * 32 + mi * 16 + l4 * 4 + j;
                    float t = fast_tanh(acc[mi][ni][j] + bias);
                    *(_Float16*)(sT + e * 256 + ((f * 2) ^ ((e & 7) << 4))) =
                        (_Float16)t;
                }
            }
        }
        __syncthreads();

        floatx4 acc2[2][2];
#pragma unroll
        for (int mi = 0; mi < 2; ++mi)
#pragma unroll
            for (int ni = 0; ni < 2; ++ni)
                acc2[mi][ni] = (floatx4){0.f, 0.f, 0.f, 0.f};
#pragma unroll
        for (int ks = 0; ks < 4; ++ks) {
            int k = ks * 32 + l4 * 8;
            half8_t a[2], b[2];
#pragma unroll
            for (int mi = 0; mi < 2; ++mi)
                a[mi] = lds_read8(sT, wm * 32 + mi * 16 + l15, 256, k);
#pragma unroll
            for (int ni = 0; ni < 2; ++ni)
                b[ni] = lds_read8(sB2, wn * 32 + ni * 16 + l15, 256, k);
#pragma unroll
            for (int mi = 0; mi < 2; ++mi)
#pragma unroll
                for (int ni = 0; ni < 2; ++ni)
                    acc2[mi][ni] = __builtin_amdgcn_mfma_f32_16x16x32_f16(
                        a[mi], b[ni], acc2[mi][ni], 0, 0, 0);
        }
        __syncthreads();

        float bias2[2];
        int gcol[2];
#pragma unroll
        for (int ni = 0; ni < 2; ++ni) {
            gcol[ni] = wn * 32 + ni * 16 + l15;
            bias2[ni] = fb2[gcol[ni]];
        }
#pragma unroll
        for (int mi = 0; mi < 2; ++mi) {
            int ge[4], s4[4], dn4[4];
            float d4[4];
#pragma unroll
            for (int j = 0; j < 4; ++j) {
                int el = wm * 32 + mi * 16 + l4 * 4 + j;
                ge[j] = e0 + el;
                int idx = (ge[j] < E) ? ge[j] : (E - 1);
                s4[j]  = srcp[idx];
                dn4[j] = dstp[idx];
                d4[j]  = edge_weight[idx];
            }
#pragma unroll
            for (int j = 0; j < 4; ++j) {
                if (ge[j] >= E) continue;
                float C = (d4[j] < RC_CUT)
                            ? 0.5f * (__cosf(d4[j] * 0.6283185307179586f) + 1.0f)
                            : 0.0f;
                const float* hrow = h + (size_t)s4[j] * FD;
                float* ar = agg + (size_t)dn4[j] * FD;
#pragma unroll
                for (int ni = 0; ni < 2; ++ni) {
                    int g = gcol[ni];
                    float wv = (acc2[mi][ni][j] + bias2[ni]) * C;
                    atomicAdd(ar + g, wv * hrow[g]);
                }
            }
        }
    }
}

// ---------------- final: disc conv + lin2 + tanh + lin ----------------
__global__ __launch_bounds__(256) void final_kernel(
    const float* aggin, const float* __restrict__ h,
    const float* __restrict__ disc_w,
    const float* __restrict__ lin2_w, const float* __restrict__ lin2_b,
    const float* __restrict__ lin_w, const float* __restrict__ lin_b,
    float* out, int n)
{
    __shared__ float sg[16][FD];
    __shared__ float sm[16][FD];
    int base = blockIdx.x * 16;
    for (int i = threadIdx.x; i < 16 * FD; i += 256) {
        int r = i >> 7, c = i & 127;
        int row = base + r;
        float v = 0.0f;
        if (row < n) {
            v = aggin[(size_t)row * FD + c] + disc_w[c] * h[(size_t)row * FD + c];
            if (row + 1 < n) v += disc_w[FD + c] * h[(size_t)(row + 1) * FD + c];
            if (row >= 1)    v += disc_w[2 * FD + c] * h[(size_t)(row - 1) * FD + c];
        }
        sg[r][c] = v;
    }
    __syncthreads();
    int f = threadIdx.x & 127;
    int half = threadIdx.x >> 7;
    {
        float acc[8];
        float b = lin2_b[f];
#pragma unroll
        for (int r = 0; r < 8; ++r) acc[r] = b;
        const float* wrow = lin2_w + (size_t)f * FD;
        for (int k = 0; k < FD; ++k) {
            float wv = wrow[k];
#pragma unroll
            for (int r = 0; r < 8; ++r) acc[r] += sg[half * 8 + r][k] * wv;
        }
#pragma unroll
        for (int r = 0; r < 8; ++r) sm[half * 8 + r][f] = fast_tanh(acc[r]);
    }
    __syncthreads();
    {
        float acc[8];
        float b = lin_b[f];
#pragma unroll
        for (int r = 0; r < 8; ++r) acc[r] = b;
        const float* wrow = lin_w + (size_t)f * HD;
        for (int k = 0; k < FD; ++k) {
            float wv = wrow[k];
#pragma unroll
            for (int r = 0; r < 8; ++r) acc[r] += sm[half * 8 + r][k] * wv;
        }
#pragma unroll
        for (int r = 0; r < 8; ++r) {
            int row = base + half * 8 + r;
            if (row < n) out[(size_t)row * HD + f] = acc[r];
        }
    }
}

extern "C" void kernel_launch(void* const* d_in, const int* in_sizes, int n_in,
                              void* d_out, int out_size, void* d_ws, size_t ws_size,
                              hipStream_t stream)
{
    const float* x      = (const float*)d_in[0];
    const float* ew     = (const float*)d_in[1];
    const float* ea     = (const float*)d_in[2];
    const float* fw1    = (const float*)d_in[3];
    const float* fb1    = (const float*)d_in[4];
    const float* fw2    = (const float*)d_in[5];
    const float* fb2    = (const float*)d_in[6];
    const float* lin1_w = (const float*)d_in[7];
    const float* lin2_w = (const float*)d_in[8];
    const float* lin2_b = (const float*)d_in[9];
    const float* disc_w = (const float*)d_in[10];
    const float* lin_w  = (const float*)d_in[11];
    const float* lin_b  = (const float*)d_in[12];
    const int*   eidx   = (const int*)d_in[13];

    int n = in_sizes[0] / HD;
    int E = in_sizes[1];
    int ntiles = (E + TE - 1) / TE;
    float* out = (float*)d_out;

    const int* srcp = eidx;
    const int* dstp = eidx + E;

    // workspace layout (16B-aligned sections)
    char* base = (char*)d_ws;
    float*     h    = (float*)base;                       // n*128 f32
    size_t off_h    = (size_t)n * FD * 4;
    _Float16*  Wp   = (_Float16*)(base + off_h);          // E*128 f16
    size_t off_w    = off_h + (size_t)E * FD * 2;
    int*       inv  = (int*)(base + off_w);               // E ints
    size_t off_i    = off_w + (size_t)E * 4;
    unsigned int* meta = (unsigned int*)(base + off_i);   // E u32
    size_t off_m    = off_i + (size_t)E * 4;
    int*       cnt  = (int*)(base + off_m);               // n ints (per-dst)
    int*       offs = cnt + n;                            // n+1 ints
    size_t need     = off_m + (size_t)(2 * n + 8) * 4;

    hipMemsetAsync(d_out, 0, (size_t)out_size * sizeof(float), stream);
    lin1_kernel<<<(n + 15) / 16, 256, 0, stream>>>(x, lin1_w, h, n);

    size_t smem = 81920;   // 80 KB -> 2 blocks/CU
    if (ws_size >= need && n <= 65535) {
        // ---------- two-phase path: sorted-by-dst, register aggregation ----
        hipMemsetAsync(cnt, 0, (size_t)n * sizeof(int), stream);
        count_kernel<<<2048, 256, 0, stream>>>(dstp, cnt, E);
        scan_kernel<<<1, 64, 0, stream>>>(cnt, offs, n);
        scatter_kernel<<<2048, 256, 0, stream>>>(srcp, dstp, cnt, inv, meta, E);

        hipFuncSetAttribute((const void*)edge_gemm_kernel,
                            hipFuncAttributeMaxDynamicSharedMemorySize, (int)smem);
        int nblocks = ntiles < 512 ? ntiles : 512;
        edge_gemm_kernel<<<nblocks, 1024, smem, stream>>>(ew, ea, fw1, fb1, fw2, fb2,
                                                          inv, Wp, E, ntiles);

        int ngroups = (E + CH - 1) / CH;
        int ablocks = (ngroups * 16 + 255) / 256;
        agg_kernel<<<ablocks, 256, 0, stream>>>(Wp, meta, h, out, E);
    } else {
        // ---------- fallback: proven fused atomic kernel ----------
        hipFuncSetAttribute((const void*)edge_kernel_atomic,
                            hipFuncAttributeMaxDynamicSharedMemorySize, (int)smem);
        int nblocks = ntiles < 512 ? ntiles : 512;
        edge_kernel_atomic<<<nblocks, 1024, smem, stream>>>(ew, ea, fw1, fb1, fw2, fb2,
                                                            eidx, h, out, E, ntiles);
    }

    final_kernel<<<(n + 15) / 16, 256, 0, stream>>>(out, h, disc_w, lin2_w, lin2_b,
                                                    lin_w, lin_b, out, n);
}

// Round 5
// 982.961 us; speedup vs baseline: 2.4407x; 1.4834x over previous
//
#include <hip/hip_runtime.h>
#include <math.h>

#define HD 128
#define FD 128
#define RD 64
#define TE 128          // edges per tile
#define RC_CUT 5.0f

typedef _Float16 half8_t __attribute__((ext_vector_type(8)));
typedef float floatx4 __attribute__((ext_vector_type(4)));

__device__ __forceinline__ float fast_tanh(float x) {
    float ex = __expf(2.0f * x);
    return 1.0f - 2.0f / (ex + 1.0f);
}

// ---------------- lin1: h = x @ lin1_w.T ----------------
__global__ __launch_bounds__(256) void lin1_kernel(const float* __restrict__ x,
                                                   const float* __restrict__ w,
                                                   float* __restrict__ h, int n)
{
    __shared__ float sx[16][HD];
    int base = blockIdx.x * 16;
    for (int i = threadIdx.x; i < 16 * HD; i += 256) {
        int r = i >> 7, c = i & 127;
        int row = base + r;
        sx[r][c] = (row < n) ? x[(size_t)row * HD + c] : 0.0f;
    }
    __syncthreads();
    int f = threadIdx.x & 127;
    int half = threadIdx.x >> 7;
    float acc[8];
#pragma unroll
    for (int r = 0; r < 8; ++r) acc[r] = 0.0f;
    const float* wrow = w + (size_t)f * HD;
    for (int k = 0; k < HD; ++k) {
        float wv = wrow[k];
#pragma unroll
        for (int r = 0; r < 8; ++r) acc[r] += sx[half * 8 + r][k] * wv;
    }
#pragma unroll
    for (int r = 0; r < 8; ++r) {
        int row = base + half * 8 + r;
        if (row < n) h[(size_t)row * FD + f] = acc[r];
    }
}

// ---------------- bucketing by dst: count / 3-level scan / scatter ----------
__global__ __launch_bounds__(256) void count_kernel(const int* __restrict__ dstp,
                                                    int* cnt, int E)
{
    for (int e = blockIdx.x * blockDim.x + threadIdx.x; e < E;
         e += gridDim.x * blockDim.x)
        atomicAdd(&cnt[dstp[e]], 1);
}

// level 1: per-256-chunk block sums
__global__ __launch_bounds__(256) void scan1_kernel(const int* __restrict__ cnt,
                                                    int* bsum, int n)
{
    int i = blockIdx.x * 256 + threadIdx.x;
    int v = (i < n) ? cnt[i] : 0;
    int lane = threadIdx.x & 63;
    int wv = threadIdx.x >> 6;
    int s = v;
#pragma unroll
    for (int d = 1; d < 64; d <<= 1) s += __shfl_xor(s, d);
    __shared__ int ws[4];
    if (lane == 0) ws[wv] = s;
    __syncthreads();
    if (threadIdx.x == 0) bsum[blockIdx.x] = ws[0] + ws[1] + ws[2] + ws[3];
}

// level 2: single-wave exclusive scan of ~196 block sums; writes total -> *totalp
__global__ void scan2_kernel(int* bsum, int nb, int* totalp)
{
    int lane = threadIdx.x;
    int carry = 0;
    for (int base = 0; base < nb; base += 64) {
        int i = base + lane;
        int v = (i < nb) ? bsum[i] : 0;
        int orig = v;
#pragma unroll
        for (int d = 1; d < 64; d <<= 1) {
            int t = __shfl_up(v, d);
            if (lane >= d) v += t;
        }
        if (i < nb) bsum[i] = carry + v - orig;
        carry += __shfl(v, 63);
    }
    if (lane == 0) *totalp = carry;
}

// level 3: per-block exclusive rescan + block offset; offs & cursor copy
__global__ __launch_bounds__(256) void scan3_kernel(int* cnt, const int* __restrict__ bsum,
                                                    int* offs, int n)
{
    int i = blockIdx.x * 256 + threadIdx.x;
    int v = (i < n) ? cnt[i] : 0;
    int lane = threadIdx.x & 63;
    int wv = threadIdx.x >> 6;
    int incl = v;
#pragma unroll
    for (int d = 1; d < 64; d <<= 1) {
        int t = __shfl_up(incl, d);
        if (lane >= d) incl += t;
    }
    __shared__ int ws[4];
    if (lane == 63) ws[wv] = incl;
    __syncthreads();
    int wbase = 0;
#pragma unroll
    for (int w = 0; w < 4; ++w) wbase += (w < wv) ? ws[w] : 0;
    int excl = bsum[blockIdx.x] + wbase + incl - v;
    if (i < n) { offs[i] = excl; cnt[i] = excl; }   // cnt becomes scatter cursor
}

// inv[e] = permuted position; meta[pos] = src | (dst << 16)  (n < 65536)
__global__ __launch_bounds__(256) void scatter_kernel(
    const int* __restrict__ srcp, const int* __restrict__ dstp,
    int* cursor, int* __restrict__ inv, unsigned int* __restrict__ meta, int E)
{
    for (int e = blockIdx.x * blockDim.x + threadIdx.x; e < E;
         e += gridDim.x * blockDim.x) {
        int d = dstp[e];
        int p = atomicAdd(&cursor[d], 1);
        inv[e] = p;
        meta[p] = (unsigned int)srcp[e] | ((unsigned int)d << 16);
    }
}

// ---------------- shared LDS helpers ----------------
__device__ __forceinline__ half8_t lds_read8(const char* base, int row,
                                             int rowstride, int col) {
    int off = row * rowstride + ((col * 2) ^ ((row & 7) << 4));
    return *(const half8_t*)(base + off);
}

// ==================== PHASE A: filter GEMMs, natural edge order ==============
// LDS (80 KB -> 2 blocks/CU): sT @0 (32 KB), sB1 @32768, sB2 @49152
// T14 async-stage: next tile's edge_attr prefetched into 8 VGPRs/thread right
// after the stage barrier; HBM latency hides under GEMM1+tanh+GEMM2.
// Epilogue: C-scale -> f16 rows in sT -> scatter whole rows (half8 chunks).
__global__ __launch_bounds__(1024, 8) void edge_gemm_kernel(
    const float* __restrict__ edge_weight,
    const float* __restrict__ edge_attr,
    const float* __restrict__ fw1, const float* __restrict__ fb1,
    const float* __restrict__ fw2, const float* __restrict__ fb2,
    const int* __restrict__ inv,
    _Float16* __restrict__ Wp,
    int E, int ntiles)
{
    extern __shared__ char smem[];
    char* sT  = smem;
    char* sB1 = smem + 32768;
    char* sB2 = smem + 49152;

    // ---- stage weights once per block (fp32 -> f16, swizzled) ----
    for (int i = threadIdx.x * 8; i < FD * RD; i += blockDim.x * 8) {
        int r = i >> 6, c = i & 63;
        const float4* g = (const float4*)(fw1 + (size_t)r * RD + c);
        float4 v0 = g[0], v1 = g[1];
        half8_t hv;
        hv[0] = (_Float16)v0.x; hv[1] = (_Float16)v0.y;
        hv[2] = (_Float16)v0.z; hv[3] = (_Float16)v0.w;
        hv[4] = (_Float16)v1.x; hv[5] = (_Float16)v1.y;
        hv[6] = (_Float16)v1.z; hv[7] = (_Float16)v1.w;
        *(half8_t*)(sB1 + r * 128 + ((c * 2) ^ ((r & 7) << 4))) = hv;
    }
    for (int i = threadIdx.x * 8; i < FD * FD; i += blockDim.x * 8) {
        int r = i >> 7, c = i & 127;
        const float4* g = (const float4*)(fw2 + (size_t)r * FD + c);
        float4 v0 = g[0], v1 = g[1];
        half8_t hv;
        hv[0] = (_Float16)v0.x; hv[1] = (_Float16)v0.y;
        hv[2] = (_Float16)v0.z; hv[3] = (_Float16)v0.w;
        hv[4] = (_Float16)v1.x; hv[5] = (_Float16)v1.y;
        hv[6] = (_Float16)v1.z; hv[7] = (_Float16)v1.w;
        *(half8_t*)(sB2 + r * 256 + ((c * 2) ^ ((r & 7) << 4))) = hv;
    }

    int lane = threadIdx.x & 63;
    int wid  = threadIdx.x >> 6;   // 0..15
    int wm = wid >> 2;             // 0..3  (edge dim, 32 each)
    int wn = wid & 3;              // 0..3  (filter dim, 32 each)
    int l15 = lane & 15;
    int l4  = lane >> 4;

    float bias1[2], bias2[2];
    int gcol[2];
#pragma unroll
    for (int ni = 0; ni < 2; ++ni) {
        gcol[ni]  = wn * 32 + ni * 16 + l15;
        bias1[ni] = fb1[gcol[ni]];
        bias2[ni] = fb2[gcol[ni]];
    }

    // prefetch lane mapping: thread -> (row, col8) of the 128x64 A tile
    int pr = threadIdx.x >> 3;          // 0..127
    int pc = (threadIdx.x & 7) * 8;     // 0..56

    // ---- prologue: prefetch first tile's A into registers ----
    float4 pA0 = {0.f, 0.f, 0.f, 0.f}, pA1 = {0.f, 0.f, 0.f, 0.f};
    {
        int e = blockIdx.x * TE + pr;
        if (e < E) {
            const float4* g = (const float4*)(edge_attr + (size_t)e * RD + pc);
            pA0 = g[0]; pA1 = g[1];
        }
    }
    __syncthreads();   // weights staged

    for (int tile = blockIdx.x; tile < ntiles; tile += gridDim.x) {
        int e0 = tile * TE;
        // ---- stage A from prefetch registers (cvt + ds_write only) ----
        {
            half8_t hv;
            hv[0] = (_Float16)pA0.x; hv[1] = (_Float16)pA0.y;
            hv[2] = (_Float16)pA0.z; hv[3] = (_Float16)pA0.w;
            hv[4] = (_Float16)pA1.x; hv[5] = (_Float16)pA1.y;
            hv[6] = (_Float16)pA1.z; hv[7] = (_Float16)pA1.w;
            *(half8_t*)(sT + pr * 128 + ((pc * 2) ^ ((pr & 7) << 4))) = hv;
        }
        __syncthreads();

        // ---- issue next tile's prefetch (completes under the GEMMs) ----
        {
            int nt = tile + gridDim.x;
            pA0 = (float4){0.f, 0.f, 0.f, 0.f};
            pA1 = (float4){0.f, 0.f, 0.f, 0.f};
            if (nt < ntiles) {
                int e = nt * TE + pr;
                if (e < E) {
                    const float4* g = (const float4*)(edge_attr + (size_t)e * RD + pc);
                    pA0 = g[0]; pA1 = g[1];
                }
            }
        }

        // ---- GEMM1: C1 = A @ fw1^T ----
        floatx4 acc[2][2];
#pragma unroll
        for (int mi = 0; mi < 2; ++mi)
#pragma unroll
            for (int ni = 0; ni < 2; ++ni)
                acc[mi][ni] = (floatx4){0.f, 0.f, 0.f, 0.f};
#pragma unroll
        for (int ks = 0; ks < 2; ++ks) {
            int k = ks * 32 + l4 * 8;
            half8_t a[2], b[2];
#pragma unroll
            for (int mi = 0; mi < 2; ++mi)
                a[mi] = lds_read8(sT, wm * 32 + mi * 16 + l15, 128, k);
#pragma unroll
            for (int ni = 0; ni < 2; ++ni)
                b[ni] = lds_read8(sB1, wn * 32 + ni * 16 + l15, 128, k);
#pragma unroll
            for (int mi = 0; mi < 2; ++mi)
#pragma unroll
                for (int ni = 0; ni < 2; ++ni)
                    acc[mi][ni] = __builtin_amdgcn_mfma_f32_16x16x32_f16(
                        a[mi], b[ni], acc[mi][ni], 0, 0, 0);
        }
        __syncthreads();

        // ---- bias + tanh -> T ----
#pragma unroll
        for (int ni = 0; ni < 2; ++ni) {
            int f = gcol[ni];
            float bias = bias1[ni];
#pragma unroll
            for (int mi = 0; mi < 2; ++mi) {
#pragma unroll
                for (int j = 0; j < 4; ++j) {
                    int e = wm * 32 + mi * 16 + l4 * 4 + j;
                    float t = fast_tanh(acc[mi][ni][j] + bias);
                    *(_Float16*)(sT + e * 256 + ((f * 2) ^ ((e & 7) << 4))) =
                        (_Float16)t;
                }
            }
        }
        __syncthreads();

        // ---- GEMM2: W = T @ fw2^T ----
        floatx4 acc2[2][2];
#pragma unroll
        for (int mi = 0; mi < 2; ++mi)
#pragma unroll
            for (int ni = 0; ni < 2; ++ni)
                acc2[mi][ni] = (floatx4){0.f, 0.f, 0.f, 0.f};
#pragma unroll
        for (int ks = 0; ks < 4; ++ks) {
            int k = ks * 32 + l4 * 8;
            half8_t a[2], b[2];
#pragma unroll
            for (int mi = 0; mi < 2; ++mi)
                a[mi] = lds_read8(sT, wm * 32 + mi * 16 + l15, 256, k);
#pragma unroll
            for (int ni = 0; ni < 2; ++ni)
                b[ni] = lds_read8(sB2, wn * 32 + ni * 16 + l15, 256, k);
#pragma unroll
            for (int mi = 0; mi < 2; ++mi)
#pragma unroll
                for (int ni = 0; ni < 2; ++ni)
                    acc2[mi][ni] = __builtin_amdgcn_mfma_f32_16x16x32_f16(
                        a[mi], b[ni], acc2[mi][ni], 0, 0, 0);
        }
        __syncthreads();   // T consumed; sT reused as W row buffer

        // ---- epilogue 1: cutoff-scale, write f16 W rows into sT ----
#pragma unroll
        for (int mi = 0; mi < 2; ++mi) {
            float d4[4];
#pragma unroll
            for (int j = 0; j < 4; ++j) {
                int el = wm * 32 + mi * 16 + l4 * 4 + j;
                int idx = (e0 + el < E) ? (e0 + el) : (E - 1);
                d4[j] = edge_weight[idx];
            }
#pragma unroll
            for (int j = 0; j < 4; ++j) {
                int el = wm * 32 + mi * 16 + l4 * 4 + j;
                float C = (d4[j] < RC_CUT)
                            ? 0.5f * (__cosf(d4[j] * 0.6283185307179586f) + 1.0f)
                            : 0.0f;
#pragma unroll
                for (int ni = 0; ni < 2; ++ni) {
                    int f = gcol[ni];
                    float wv = (acc2[mi][ni][j] + bias2[ni]) * C;
                    *(_Float16*)(sT + el * 256 + ((f * 2) ^ ((el & 7) << 4))) =
                        (_Float16)wv;
                }
            }
        }
        __syncthreads();

        // ---- epilogue 2: scatter whole rows to Wp (16-B chunks) ----
#pragma unroll
        for (int k = 0; k < 2; ++k) {
            int t = threadIdx.x + k * 1024;
            int r = t >> 4, ch = t & 15;
            int e = e0 + r;
            if (e < E) {
                half8_t v = lds_read8(sT, r, 256, ch * 8);
                int pv = inv[e];
                *(half8_t*)(Wp + (size_t)pv * FD + ch * 8) = v;
            }
        }
        __syncthreads();   // sT fully consumed; next tile may overwrite
    }
}

// ==================== PHASE B: CSR per-dst register aggregation ==============
// 16-lane group owns ONE dst row. Run bounds from offs[] (sorted positions are
// contiguous). Wp reads coalesced-sequential, h reads L3 gather, zero atomics,
// one plain float4x2 store per lane. Unrolled x2 for load-level parallelism.
__global__ __launch_bounds__(256) void agg_kernel(
    const _Float16* __restrict__ Wp,
    const unsigned int* __restrict__ meta,
    const int* __restrict__ offs,
    const float* __restrict__ h,
    float* __restrict__ agg, int n)
{
    int g = (blockIdx.x * 256 + (int)threadIdx.x) >> 4;
    if (g >= n) return;
    int lg = threadIdx.x & 15;
    int p  = offs[g];
    int p1 = offs[g + 1];

    float acc[8];
#pragma unroll
    for (int q = 0; q < 8; ++q) acc[q] = 0.0f;

    for (; p + 2 <= p1; p += 2) {
        int s0 = (int)(meta[p] & 0xFFFFu);
        int s1 = (int)(meta[p + 1] & 0xFFFFu);
        half8_t w0 = *(const half8_t*)(Wp + (size_t)p * FD + lg * 8);
        half8_t w1 = *(const half8_t*)(Wp + (size_t)(p + 1) * FD + lg * 8);
        const float4* ha = (const float4*)(h + (size_t)s0 * FD + lg * 8);
        const float4* hb = (const float4*)(h + (size_t)s1 * FD + lg * 8);
        float4 a0 = ha[0], a1 = ha[1];
        float4 b0 = hb[0], b1 = hb[1];
        acc[0] += (float)w0[0] * a0.x + (float)w1[0] * b0.x;
        acc[1] += (float)w0[1] * a0.y + (float)w1[1] * b0.y;
        acc[2] += (float)w0[2] * a0.z + (float)w1[2] * b0.z;
        acc[3] += (float)w0[3] * a0.w + (float)w1[3] * b0.w;
        acc[4] += (float)w0[4] * a1.x + (float)w1[4] * b1.x;
        acc[5] += (float)w0[5] * a1.y + (float)w1[5] * b1.y;
        acc[6] += (float)w0[6] * a1.z + (float)w1[6] * b1.z;
        acc[7] += (float)w0[7] * a1.w + (float)w1[7] * b1.w;
    }
    if (p < p1) {
        int s0 = (int)(meta[p] & 0xFFFFu);
        half8_t w0 = *(const half8_t*)(Wp + (size_t)p * FD + lg * 8);
        const float4* ha = (const float4*)(h + (size_t)s0 * FD + lg * 8);
        float4 a0 = ha[0], a1 = ha[1];
        acc[0] += (float)w0[0] * a0.x;
        acc[1] += (float)w0[1] * a0.y;
        acc[2] += (float)w0[2] * a0.z;
        acc[3] += (float)w0[3] * a0.w;
        acc[4] += (float)w0[4] * a1.x;
        acc[5] += (float)w0[5] * a1.y;
        acc[6] += (float)w0[6] * a1.z;
        acc[7] += (float)w0[7] * a1.w;
    }
    float* ar = agg + (size_t)g * FD + lg * 8;
    *(float4*)ar       = (float4){acc[0], acc[1], acc[2], acc[3]};
    *(float4*)(ar + 4) = (float4){acc[4], acc[5], acc[6], acc[7]};
}

// ==================== FALLBACK: fused kernel (global atomics) ================
__global__ __launch_bounds__(1024, 8) void edge_kernel_atomic(
    const float* __restrict__ edge_weight,
    const float* __restrict__ edge_attr,
    const float* __restrict__ fw1, const float* __restrict__ fb1,
    const float* __restrict__ fw2, const float* __restrict__ fb2,
    const int* __restrict__ eidx,
    const float* __restrict__ h,
    float* agg, int E, int ntiles)
{
    extern __shared__ char smem[];
    char* sT  = smem;
    char* sB1 = smem + 32768;
    char* sB2 = smem + 49152;

    for (int i = threadIdx.x * 8; i < FD * RD; i += blockDim.x * 8) {
        int r = i >> 6, c = i & 63;
        const float4* g = (const float4*)(fw1 + (size_t)r * RD + c);
        float4 v0 = g[0], v1 = g[1];
        half8_t hv;
        hv[0] = (_Float16)v0.x; hv[1] = (_Float16)v0.y;
        hv[2] = (_Float16)v0.z; hv[3] = (_Float16)v0.w;
        hv[4] = (_Float16)v1.x; hv[5] = (_Float16)v1.y;
        hv[6] = (_Float16)v1.z; hv[7] = (_Float16)v1.w;
        *(half8_t*)(sB1 + r * 128 + ((c * 2) ^ ((r & 7) << 4))) = hv;
    }
    for (int i = threadIdx.x * 8; i < FD * FD; i += blockDim.x * 8) {
        int r = i >> 7, c = i & 127;
        const float4* g = (const float4*)(fw2 + (size_t)r * FD + c);
        float4 v0 = g[0], v1 = g[1];
        half8_t hv;
        hv[0] = (_Float16)v0.x; hv[1] = (_Float16)v0.y;
        hv[2] = (_Float16)v0.z; hv[3] = (_Float16)v0.w;
        hv[4] = (_Float16)v1.x; hv[5] = (_Float16)v1.y;
        hv[6] = (_Float16)v1.z; hv[7] = (_Float16)v1.w;
        *(half8_t*)(sB2 + r * 256 + ((c * 2) ^ ((r & 7) << 4))) = hv;
    }
    __syncthreads();

    const int* srcp = eidx;
    const int* dstp = eidx + E;
    int lane = threadIdx.x & 63;
    int wid  = threadIdx.x >> 6;
    int wm = wid >> 2;
    int wn = wid & 3;
    int l15 = lane & 15;
    int l4  = lane >> 4;

    for (int tile = blockIdx.x; tile < ntiles; tile += gridDim.x) {
        int e0 = tile * TE;
        for (int i = threadIdx.x * 8; i < TE * RD; i += blockDim.x * 8) {
            int r = i >> 6, c = i & 63;
            half8_t hv;
            if (e0 + r < E) {
                const float4* g = (const float4*)(edge_attr + (size_t)(e0 + r) * RD + c);
                float4 v0 = g[0], v1 = g[1];
                hv[0] = (_Float16)v0.x; hv[1] = (_Float16)v0.y;
                hv[2] = (_Float16)v0.z; hv[3] = (_Float16)v0.w;
                hv[4] = (_Float16)v1.x; hv[5] = (_Float16)v1.y;
                hv[6] = (_Float16)v1.z; hv[7] = (_Float16)v1.w;
            } else {
                for (int q = 0; q < 8; ++q) hv[q] = (_Float16)0.0f;
            }
            *(half8_t*)(sT + r * 128 + ((c * 2) ^ ((r & 7) << 4))) = hv;
        }
        __syncthreads();

        floatx4 acc[2][2];
#pragma unroll
        for (int mi = 0; mi < 2; ++mi)
#pragma unroll
            for (int ni = 0; ni < 2; ++ni)
                acc[mi][ni] = (floatx4){0.f, 0.f, 0.f, 0.f};
#pragma unroll
        for (int ks = 0; ks < 2; ++ks) {
            int k = ks * 32 + l4 * 8;
            half8_t a[2], b[2];
#pragma unroll
            for (int mi = 0; mi < 2; ++mi)
                a[mi] = lds_read8(sT, wm * 32 + mi * 16 + l15, 128, k);
#pragma unroll
            for (int ni = 0; ni < 2; ++ni)
                b[ni] = lds_read8(sB1, wn * 32 + ni * 16 + l15, 128, k);
#pragma unroll
            for (int mi = 0; mi < 2; ++mi)
#pragma unroll
                for (int ni = 0; ni < 2; ++ni)
                    acc[mi][ni] = __builtin_amdgcn_mfma_f32_16x16x32_f16(
                        a[mi], b[ni], acc[mi][ni], 0, 0, 0);
        }
        __syncthreads();

#pragma unroll
        for (int ni = 0; ni < 2; ++ni) {
            int f = wn * 32 + ni * 16 + l15;
            float bias = fb1[f];
#pragma unroll
            for (int mi = 0; mi < 2; ++mi) {
#pragma unroll
                for (int j = 0; j < 4; ++j) {
                    int e = wm * 32 + mi * 16 + l4 * 4 + j;
                    float t = fast_tanh(acc[mi][ni][j] + bias);
                    *(_Float16*)(sT + e * 256 + ((f * 2) ^ ((e & 7) << 4))) =
                        (_Float16)t;
                }
            }
        }
        __syncthreads();

        floatx4 acc2[2][2];
#pragma unroll
        for (int mi = 0; mi < 2; ++mi)
#pragma unroll
            for (int ni = 0; ni < 2; ++ni)
                acc2[mi][ni] = (floatx4){0.f, 0.f, 0.f, 0.f};
#pragma unroll
        for (int ks = 0; ks < 4; ++ks) {
            int k = ks * 32 + l4 * 8;
            half8_t a[2], b[2];
#pragma unroll
            for (int mi = 0; mi < 2; ++mi)
                a[mi] = lds_read8(sT, wm * 32 + mi * 16 + l15, 256, k);
#pragma unroll
            for (int ni = 0; ni < 2; ++ni)
                b[ni] = lds_read8(sB2, wn * 32 + ni * 16 + l15, 256, k);
#pragma unroll
            for (int mi = 0; mi < 2; ++mi)
#pragma unroll
                for (int ni = 0; ni < 2; ++ni)
                    acc2[mi][ni] = __builtin_amdgcn_mfma_f32_16x16x32_f16(
                        a[mi], b[ni], acc2[mi][ni], 0, 0, 0);
        }
        __syncthreads();

        float bias2[2];
        int gcol[2];
#pragma unroll
        for (int ni = 0; ni < 2; ++ni) {
            gcol[ni] = wn * 32 + ni * 16 + l15;
            bias2[ni] = fb2[gcol[ni]];
        }
#pragma unroll
        for (int mi = 0; mi < 2; ++mi) {
            int ge[4], s4[4], dn4[4];
            float d4[4];
#pragma unroll
            for (int j = 0; j < 4; ++j) {
                int el = wm * 32 + mi * 16 + l4 * 4 + j;
                ge[j] = e0 + el;
                int idx = (ge[j] < E) ? ge[j] : (E - 1);
                s4[j]  = srcp[idx];
                dn4[j] = dstp[idx];
                d4[j]  = edge_weight[idx];
            }
#pragma unroll
            for (int j = 0; j < 4; ++j) {
                if (ge[j] >= E) continue;
                float C = (d4[j] < RC_CUT)
                            ? 0.5f * (__cosf(d4[j] * 0.6283185307179586f) + 1.0f)
                            : 0.0f;
                const float* hrow = h + (size_t)s4[j] * FD;
                float* ar = agg + (size_t)dn4[j] * FD;
#pragma unroll
                for (int ni = 0; ni < 2; ++ni) {
                    int g = gcol[ni];
                    float wv = (acc2[mi][ni][j] + bias2[ni]) * C;
                    atomicAdd(ar + g, wv * hrow[g]);
                }
            }
        }
    }
}

// ---------------- final: disc conv + lin2 + tanh + lin ----------------
__global__ __launch_bounds__(256) void final_kernel(
    const float* aggin, const float* __restrict__ h,
    const float* __restrict__ disc_w,
    const float* __restrict__ lin2_w, const float* __restrict__ lin2_b,
    const float* __restrict__ lin_w, const float* __restrict__ lin_b,
    float* out, int n)
{
    __shared__ float sg[16][FD];
    __shared__ float sm[16][FD];
    int base = blockIdx.x * 16;
    for (int i = threadIdx.x; i < 16 * FD; i += 256) {
        int r = i >> 7, c = i & 127;
        int row = base + r;
        float v = 0.0f;
        if (row < n) {
            v = aggin[(size_t)row * FD + c] + disc_w[c] * h[(size_t)row * FD + c];
            if (row + 1 < n) v += disc_w[FD + c] * h[(size_t)(row + 1) * FD + c];
            if (row >= 1)    v += disc_w[2 * FD + c] * h[(size_t)(row - 1) * FD + c];
        }
        sg[r][c] = v;
    }
    __syncthreads();
    int f = threadIdx.x & 127;
    int half = threadIdx.x >> 7;
    {
        float acc[8];
        float b = lin2_b[f];
#pragma unroll
        for (int r = 0; r < 8; ++r) acc[r] = b;
        const float* wrow = lin2_w + (size_t)f * FD;
        for (int k = 0; k < FD; ++k) {
            float wv = wrow[k];
#pragma unroll
            for (int r = 0; r < 8; ++r) acc[r] += sg[half * 8 + r][k] * wv;
        }
#pragma unroll
        for (int r = 0; r < 8; ++r) sm[half * 8 + r][f] = fast_tanh(acc[r]);
    }
    __syncthreads();
    {
        float acc[8];
        float b = lin_b[f];
#pragma unroll
        for (int r = 0; r < 8; ++r) acc[r] = b;
        const float* wrow = lin_w + (size_t)f * HD;
        for (int k = 0; k < FD; ++k) {
            float wv = wrow[k];
#pragma unroll
            for (int r = 0; r < 8; ++r) acc[r] += sm[half * 8 + r][k] * wv;
        }
#pragma unroll
        for (int r = 0; r < 8; ++r) {
            int row = base + half * 8 + r;
            if (row < n) out[(size_t)row * HD + f] = acc[r];
        }
    }
}

extern "C" void kernel_launch(void* const* d_in, const int* in_sizes, int n_in,
                              void* d_out, int out_size, void* d_ws, size_t ws_size,
                              hipStream_t stream)
{
    const float* x      = (const float*)d_in[0];
    const float* ew     = (const float*)d_in[1];
    const float* ea     = (const float*)d_in[2];
    const float* fw1    = (const float*)d_in[3];
    const float* fb1    = (const float*)d_in[4];
    const float* fw2    = (const float*)d_in[5];
    const float* fb2    = (const float*)d_in[6];
    const float* lin1_w = (const float*)d_in[7];
    const float* lin2_w = (const float*)d_in[8];
    const float* lin2_b = (const float*)d_in[9];
    const float* disc_w = (const float*)d_in[10];
    const float* lin_w  = (const float*)d_in[11];
    const float* lin_b  = (const float*)d_in[12];
    const int*   eidx   = (const int*)d_in[13];

    int n = in_sizes[0] / HD;
    int E = in_sizes[1];
    int ntiles = (E + TE - 1) / TE;
    int nb = (n + 255) / 256;
    float* out = (float*)d_out;

    const int* srcp = eidx;
    const int* dstp = eidx + E;

    // workspace layout (16B-aligned sections)
    char* base = (char*)d_ws;
    float*     h    = (float*)base;                       // n*128 f32
    size_t off_h    = (size_t)n * FD * 4;
    _Float16*  Wp   = (_Float16*)(base + off_h);          // E*128 f16
    size_t off_w    = off_h + (size_t)E * FD * 2;
    int*       inv  = (int*)(base + off_w);               // E ints
    size_t off_i    = off_w + (size_t)E * 4;
    unsigned int* meta = (unsigned int*)(base + off_i);   // E u32
    size_t off_m    = off_i + (size_t)E * 4;
    int*       cnt  = (int*)(base + off_m);               // n ints (per-dst)
    int*       offs = cnt + n;                            // n+1 ints
    int*       bsum = offs + n + 1;                       // nb ints
    size_t need     = off_m + (size_t)(2 * n + nb + 16) * 4;

    hipMemsetAsync(d_out, 0, (size_t)out_size * sizeof(float), stream);
    lin1_kernel<<<(n + 15) / 16, 256, 0, stream>>>(x, lin1_w, h, n);

    size_t smem = 81920;   // 80 KB -> 2 blocks/CU
    if (ws_size >= need && n <= 65535) {
        // ---------- two-phase path: sorted-by-dst, CSR register agg ----------
        hipMemsetAsync(cnt, 0, (size_t)n * sizeof(int), stream);
        count_kernel<<<2048, 256, 0, stream>>>(dstp, cnt, E);
        scan1_kernel<<<nb, 256, 0, stream>>>(cnt, bsum, n);
        scan2_kernel<<<1, 64, 0, stream>>>(bsum, nb, offs + n);
        scan3_kernel<<<nb, 256, 0, stream>>>(cnt, bsum, offs, n);
        scatter_kernel<<<2048, 256, 0, stream>>>(srcp, dstp, cnt, inv, meta, E);

        hipFuncSetAttribute((const void*)edge_gemm_kernel,
                            hipFuncAttributeMaxDynamicSharedMemorySize, (int)smem);
        int nblocks = ntiles < 512 ? ntiles : 512;
        edge_gemm_kernel<<<nblocks, 1024, smem, stream>>>(ew, ea, fw1, fb1, fw2, fb2,
                                                          inv, Wp, E, ntiles);

        int ablocks = (n * 16 + 255) / 256;
        agg_kernel<<<ablocks, 256, 0, stream>>>(Wp, meta, offs, h, out, n);
    } else {
        // ---------- fallback: proven fused atomic kernel ----------
        hipFuncSetAttribute((const void*)edge_kernel_atomic,
                            hipFuncAttributeMaxDynamicSharedMemorySize, (int)smem);
        int nblocks = ntiles < 512 ? ntiles : 512;
        edge_kernel_atomic<<<nblocks, 1024, smem, stream>>>(ew, ea, fw1, fb1, fw2, fb2,
                                                            eidx, h, out, E, ntiles);
    }

    final_kernel<<<(n + 15) / 16, 256, 0, stream>>>(out, h, disc_w, lin2_w, lin2_b,
                                                    lin_w, lin_b, out, n);
}

// Round 6
// 918.397 us; speedup vs baseline: 2.6123x; 1.0703x over previous
//
#include <hip/hip_runtime.h>
#include <math.h>

#define HD 128
#define FD 128
#define RD 64
#define TE 128          // edges per tile
#define RC_CUT 5.0f

typedef _Float16 half8_t __attribute__((ext_vector_type(8)));
typedef float floatx4 __attribute__((ext_vector_type(4)));

__device__ __forceinline__ float fast_tanh(float x) {
    float ex = __expf(2.0f * x);
    return 1.0f - 2.0f / (ex + 1.0f);
}

// ---------------- lin1: h = x @ lin1_w.T ----------------
__global__ __launch_bounds__(256) void lin1_kernel(const float* __restrict__ x,
                                                   const float* __restrict__ w,
                                                   float* __restrict__ h, int n)
{
    __shared__ float sx[16][HD];
    int base = blockIdx.x * 16;
    for (int i = threadIdx.x; i < 16 * HD; i += 256) {
        int r = i >> 7, c = i & 127;
        int row = base + r;
        sx[r][c] = (row < n) ? x[(size_t)row * HD + c] : 0.0f;
    }
    __syncthreads();
    int f = threadIdx.x & 127;
    int half = threadIdx.x >> 7;
    float acc[8];
#pragma unroll
    for (int r = 0; r < 8; ++r) acc[r] = 0.0f;
    const float* wrow = w + (size_t)f * HD;
    for (int k = 0; k < HD; ++k) {
        float wv = wrow[k];
#pragma unroll
        for (int r = 0; r < 8; ++r) acc[r] += sx[half * 8 + r][k] * wv;
    }
#pragma unroll
    for (int r = 0; r < 8; ++r) {
        int row = base + half * 8 + r;
        if (row < n) h[(size_t)row * FD + f] = acc[r];
    }
}

// ---------------- bucketing by dst: count / 3-level scan / scatter ----------
__global__ __launch_bounds__(256) void count_kernel(const int* __restrict__ dstp,
                                                    int* cnt, int E)
{
    for (int e = blockIdx.x * blockDim.x + threadIdx.x; e < E;
         e += gridDim.x * blockDim.x)
        atomicAdd(&cnt[dstp[e]], 1);
}

// level 1: per-256-chunk block sums
__global__ __launch_bounds__(256) void scan1_kernel(const int* __restrict__ cnt,
                                                    int* bsum, int n)
{
    int i = blockIdx.x * 256 + threadIdx.x;
    int v = (i < n) ? cnt[i] : 0;
    int lane = threadIdx.x & 63;
    int wv = threadIdx.x >> 6;
    int s = v;
#pragma unroll
    for (int d = 1; d < 64; d <<= 1) s += __shfl_xor(s, d);
    __shared__ int ws[4];
    if (lane == 0) ws[wv] = s;
    __syncthreads();
    if (threadIdx.x == 0) bsum[blockIdx.x] = ws[0] + ws[1] + ws[2] + ws[3];
}

// level 2: single-wave exclusive scan of block sums
__global__ void scan2_kernel(int* bsum, int nb, int* totalp)
{
    int lane = threadIdx.x;
    int carry = 0;
    for (int base = 0; base < nb; base += 64) {
        int i = base + lane;
        int v = (i < nb) ? bsum[i] : 0;
        int orig = v;
#pragma unroll
        for (int d = 1; d < 64; d <<= 1) {
            int t = __shfl_up(v, d);
            if (lane >= d) v += t;
        }
        if (i < nb) bsum[i] = carry + v - orig;
        carry += __shfl(v, 63);
    }
    if (lane == 0) *totalp = carry;
}

// level 3: per-block exclusive rescan + block offset; offs & cursor copy
__global__ __launch_bounds__(256) void scan3_kernel(int* cnt, const int* __restrict__ bsum,
                                                    int* offs, int n)
{
    int i = blockIdx.x * 256 + threadIdx.x;
    int v = (i < n) ? cnt[i] : 0;
    int lane = threadIdx.x & 63;
    int wv = threadIdx.x >> 6;
    int incl = v;
#pragma unroll
    for (int d = 1; d < 64; d <<= 1) {
        int t = __shfl_up(incl, d);
        if (lane >= d) incl += t;
    }
    __shared__ int ws[4];
    if (lane == 63) ws[wv] = incl;
    __syncthreads();
    int wbase = 0;
#pragma unroll
    for (int w = 0; w < 4; ++w) wbase += (w < wv) ? ws[w] : 0;
    int excl = bsum[blockIdx.x] + wbase + incl - v;
    if (i < n) { offs[i] = excl; cnt[i] = excl; }   // cnt becomes scatter cursor
}

// inv[e] = permuted position; meta[pos] = src | (dst << 16)  (n < 65536)
__global__ __launch_bounds__(256) void scatter_kernel(
    const int* __restrict__ srcp, const int* __restrict__ dstp,
    int* cursor, int* __restrict__ inv, unsigned int* __restrict__ meta, int E)
{
    for (int e = blockIdx.x * blockDim.x + threadIdx.x; e < E;
         e += gridDim.x * blockDim.x) {
        int d = dstp[e];
        int p = atomicAdd(&cursor[d], 1);
        inv[e] = p;
        meta[p] = (unsigned int)srcp[e] | ((unsigned int)d << 16);
    }
}

// ---------------- shared LDS helpers ----------------
__device__ __forceinline__ half8_t lds_read8(const char* base, int row,
                                             int rowstride, int col) {
    int off = row * rowstride + ((col * 2) ^ ((row & 7) << 4));
    return *(const half8_t*)(base + off);
}

// ==================== PHASE A: filter GEMMs, natural edge order ==============
// LDS (80 KB -> 2 blocks/CU): sT @0 (32 KB), sB1 @32768, sB2 @49152
// T14 LATE prefetch: next tile's edge_attr loads issued AFTER epilogue-1
// (acc/acc2 dead -> minimal live range, no spill at the 64-VGPR bound);
// consumed at next loop-top stage. Latency hides under epilogue-2 + barrier.
__global__ __launch_bounds__(1024, 8) void edge_gemm_kernel(
    const float* __restrict__ edge_weight,
    const float* __restrict__ edge_attr,
    const float* __restrict__ fw1, const float* __restrict__ fb1,
    const float* __restrict__ fw2, const float* __restrict__ fb2,
    const int* __restrict__ inv,
    _Float16* __restrict__ Wp,
    int E, int ntiles)
{
    extern __shared__ char smem[];
    char* sT  = smem;
    char* sB1 = smem + 32768;
    char* sB2 = smem + 49152;

    // ---- stage weights once per block (fp32 -> f16, swizzled) ----
    for (int i = threadIdx.x * 8; i < FD * RD; i += blockDim.x * 8) {
        int r = i >> 6, c = i & 63;
        const float4* g = (const float4*)(fw1 + (size_t)r * RD + c);
        float4 v0 = g[0], v1 = g[1];
        half8_t hv;
        hv[0] = (_Float16)v0.x; hv[1] = (_Float16)v0.y;
        hv[2] = (_Float16)v0.z; hv[3] = (_Float16)v0.w;
        hv[4] = (_Float16)v1.x; hv[5] = (_Float16)v1.y;
        hv[6] = (_Float16)v1.z; hv[7] = (_Float16)v1.w;
        *(half8_t*)(sB1 + r * 128 + ((c * 2) ^ ((r & 7) << 4))) = hv;
    }
    for (int i = threadIdx.x * 8; i < FD * FD; i += blockDim.x * 8) {
        int r = i >> 7, c = i & 127;
        const float4* g = (const float4*)(fw2 + (size_t)r * FD + c);
        float4 v0 = g[0], v1 = g[1];
        half8_t hv;
        hv[0] = (_Float16)v0.x; hv[1] = (_Float16)v0.y;
        hv[2] = (_Float16)v0.z; hv[3] = (_Float16)v0.w;
        hv[4] = (_Float16)v1.x; hv[5] = (_Float16)v1.y;
        hv[6] = (_Float16)v1.z; hv[7] = (_Float16)v1.w;
        *(half8_t*)(sB2 + r * 256 + ((c * 2) ^ ((r & 7) << 4))) = hv;
    }

    int lane = threadIdx.x & 63;
    int wid  = threadIdx.x >> 6;   // 0..15
    int wm = wid >> 2;             // 0..3  (edge dim, 32 each)
    int wn = wid & 3;              // 0..3  (filter dim, 32 each)
    int l15 = lane & 15;
    int l4  = lane >> 4;

    float bias1[2], bias2[2];
    int gcol[2];
#pragma unroll
    for (int ni = 0; ni < 2; ++ni) {
        gcol[ni]  = wn * 32 + ni * 16 + l15;
        bias1[ni] = fb1[gcol[ni]];
        bias2[ni] = fb2[gcol[ni]];
    }

    // prefetch lane mapping: thread -> (row, col8) of the 128x64 A tile
    int pr = threadIdx.x >> 3;          // 0..127
    int pc = (threadIdx.x & 7) * 8;     // 0..56

    // ---- prologue: prefetch first tile's A into registers ----
    float4 pA0 = {0.f, 0.f, 0.f, 0.f}, pA1 = {0.f, 0.f, 0.f, 0.f};
    {
        int e = blockIdx.x * TE + pr;
        if (e < E) {
            const float4* g = (const float4*)(edge_attr + (size_t)e * RD + pc);
            pA0 = g[0]; pA1 = g[1];
        }
    }
    __syncthreads();   // weights staged

    for (int tile = blockIdx.x; tile < ntiles; tile += gridDim.x) {
        int e0 = tile * TE;
        // ---- stage A from prefetch registers (cvt + ds_write only) ----
        {
            half8_t hv;
            hv[0] = (_Float16)pA0.x; hv[1] = (_Float16)pA0.y;
            hv[2] = (_Float16)pA0.z; hv[3] = (_Float16)pA0.w;
            hv[4] = (_Float16)pA1.x; hv[5] = (_Float16)pA1.y;
            hv[6] = (_Float16)pA1.z; hv[7] = (_Float16)pA1.w;
            *(half8_t*)(sT + pr * 128 + ((pc * 2) ^ ((pr & 7) << 4))) = hv;
        }
        __syncthreads();

        // ---- GEMM1: C1 = A @ fw1^T ----
        floatx4 acc[2][2];
#pragma unroll
        for (int mi = 0; mi < 2; ++mi)
#pragma unroll
            for (int ni = 0; ni < 2; ++ni)
                acc[mi][ni] = (floatx4){0.f, 0.f, 0.f, 0.f};
#pragma unroll
        for (int ks = 0; ks < 2; ++ks) {
            int k = ks * 32 + l4 * 8;
            half8_t a[2], b[2];
#pragma unroll
            for (int mi = 0; mi < 2; ++mi)
                a[mi] = lds_read8(sT, wm * 32 + mi * 16 + l15, 128, k);
#pragma unroll
            for (int ni = 0; ni < 2; ++ni)
                b[ni] = lds_read8(sB1, wn * 32 + ni * 16 + l15, 128, k);
#pragma unroll
            for (int mi = 0; mi < 2; ++mi)
#pragma unroll
                for (int ni = 0; ni < 2; ++ni)
                    acc[mi][ni] = __builtin_amdgcn_mfma_f32_16x16x32_f16(
                        a[mi], b[ni], acc[mi][ni], 0, 0, 0);
        }
        __syncthreads();

        // ---- bias + tanh -> T ----
#pragma unroll
        for (int ni = 0; ni < 2; ++ni) {
            int f = gcol[ni];
            float bias = bias1[ni];
#pragma unroll
            for (int mi = 0; mi < 2; ++mi) {
#pragma unroll
                for (int j = 0; j < 4; ++j) {
                    int e = wm * 32 + mi * 16 + l4 * 4 + j;
                    float t = fast_tanh(acc[mi][ni][j] + bias);
                    *(_Float16*)(sT + e * 256 + ((f * 2) ^ ((e & 7) << 4))) =
                        (_Float16)t;
                }
            }
        }
        __syncthreads();

        // ---- GEMM2: W = T @ fw2^T ----
        floatx4 acc2[2][2];
#pragma unroll
        for (int mi = 0; mi < 2; ++mi)
#pragma unroll
            for (int ni = 0; ni < 2; ++ni)
                acc2[mi][ni] = (floatx4){0.f, 0.f, 0.f, 0.f};
#pragma unroll
        for (int ks = 0; ks < 4; ++ks) {
            int k = ks * 32 + l4 * 8;
            half8_t a[2], b[2];
#pragma unroll
            for (int mi = 0; mi < 2; ++mi)
                a[mi] = lds_read8(sT, wm * 32 + mi * 16 + l15, 256, k);
#pragma unroll
            for (int ni = 0; ni < 2; ++ni)
                b[ni] = lds_read8(sB2, wn * 32 + ni * 16 + l15, 256, k);
#pragma unroll
            for (int mi = 0; mi < 2; ++mi)
#pragma unroll
                for (int ni = 0; ni < 2; ++ni)
                    acc2[mi][ni] = __builtin_amdgcn_mfma_f32_16x16x32_f16(
                        a[mi], b[ni], acc2[mi][ni], 0, 0, 0);
        }
        __syncthreads();   // T consumed; sT reused as W row buffer

        // ---- epilogue 1: cutoff-scale, write f16 W rows into sT ----
#pragma unroll
        for (int mi = 0; mi < 2; ++mi) {
            float d4[4];
#pragma unroll
            for (int j = 0; j < 4; ++j) {
                int el = wm * 32 + mi * 16 + l4 * 4 + j;
                int idx = (e0 + el < E) ? (e0 + el) : (E - 1);
                d4[j] = edge_weight[idx];
            }
#pragma unroll
            for (int j = 0; j < 4; ++j) {
                int el = wm * 32 + mi * 16 + l4 * 4 + j;
                float C = (d4[j] < RC_CUT)
                            ? 0.5f * (__cosf(d4[j] * 0.6283185307179586f) + 1.0f)
                            : 0.0f;
#pragma unroll
                for (int ni = 0; ni < 2; ++ni) {
                    int f = gcol[ni];
                    float wv = (acc2[mi][ni][j] + bias2[ni]) * C;
                    *(_Float16*)(sT + el * 256 + ((f * 2) ^ ((el & 7) << 4))) =
                        (_Float16)wv;
                }
            }
        }

        // ---- T14 late prefetch: acc/acc2 now dead, pressure minimal ----
        {
            int nt = tile + gridDim.x;
            pA0 = (float4){0.f, 0.f, 0.f, 0.f};
            pA1 = (float4){0.f, 0.f, 0.f, 0.f};
            if (nt < ntiles) {
                int e = nt * TE + pr;
                if (e < E) {
                    const float4* g = (const float4*)(edge_attr + (size_t)e * RD + pc);
                    pA0 = g[0]; pA1 = g[1];
                }
            }
        }
        __syncthreads();

        // ---- epilogue 2: scatter whole rows to Wp (16-B chunks) ----
#pragma unroll
        for (int k = 0; k < 2; ++k) {
            int t = threadIdx.x + k * 1024;
            int r = t >> 4, ch = t & 15;
            int e = e0 + r;
            if (e < E) {
                half8_t v = lds_read8(sT, r, 256, ch * 8);
                int pv = inv[e];
                *(half8_t*)(Wp + (size_t)pv * FD + ch * 8) = v;
            }
        }
        __syncthreads();   // sT fully consumed; next tile may overwrite
    }
}

// ==================== PHASE B: CSR per-dst register aggregation ==============
// 16-lane group owns ONE dst row; unroll x4 for load-level parallelism.
// Wp reads coalesced-sequential, h reads L3 gather, zero atomics,
// one plain float4x2 store per lane.
__global__ __launch_bounds__(256) void agg_kernel(
    const _Float16* __restrict__ Wp,
    const unsigned int* __restrict__ meta,
    const int* __restrict__ offs,
    const float* __restrict__ h,
    float* __restrict__ agg, int n)
{
    int g = (blockIdx.x * 256 + (int)threadIdx.x) >> 4;
    if (g >= n) return;
    int lg = threadIdx.x & 15;
    int p  = offs[g];
    int p1 = offs[g + 1];

    float acc[8];
#pragma unroll
    for (int q = 0; q < 8; ++q) acc[q] = 0.0f;

    for (; p + 4 <= p1; p += 4) {
        int s[4];
#pragma unroll
        for (int u = 0; u < 4; ++u) s[u] = (int)(meta[p + u] & 0xFFFFu);
        half8_t w[4];
#pragma unroll
        for (int u = 0; u < 4; ++u)
            w[u] = *(const half8_t*)(Wp + (size_t)(p + u) * FD + lg * 8);
        float4 h0[4], h1[4];
#pragma unroll
        for (int u = 0; u < 4; ++u) {
            const float4* hr = (const float4*)(h + (size_t)s[u] * FD + lg * 8);
            h0[u] = hr[0]; h1[u] = hr[1];
        }
#pragma unroll
        for (int u = 0; u < 4; ++u) {
            acc[0] += (float)w[u][0] * h0[u].x;
            acc[1] += (float)w[u][1] * h0[u].y;
            acc[2] += (float)w[u][2] * h0[u].z;
            acc[3] += (float)w[u][3] * h0[u].w;
            acc[4] += (float)w[u][4] * h1[u].x;
            acc[5] += (float)w[u][5] * h1[u].y;
            acc[6] += (float)w[u][6] * h1[u].z;
            acc[7] += (float)w[u][7] * h1[u].w;
        }
    }
    for (; p < p1; ++p) {
        int s0 = (int)(meta[p] & 0xFFFFu);
        half8_t w0 = *(const half8_t*)(Wp + (size_t)p * FD + lg * 8);
        const float4* ha = (const float4*)(h + (size_t)s0 * FD + lg * 8);
        float4 a0 = ha[0], a1 = ha[1];
        acc[0] += (float)w0[0] * a0.x;
        acc[1] += (float)w0[1] * a0.y;
        acc[2] += (float)w0[2] * a0.z;
        acc[3] += (float)w0[3] * a0.w;
        acc[4] += (float)w0[4] * a1.x;
        acc[5] += (float)w0[5] * a1.y;
        acc[6] += (float)w0[6] * a1.z;
        acc[7] += (float)w0[7] * a1.w;
    }
    float* ar = agg + (size_t)g * FD + lg * 8;
    *(float4*)ar       = (float4){acc[0], acc[1], acc[2], acc[3]};
    *(float4*)(ar + 4) = (float4){acc[4], acc[5], acc[6], acc[7]};
}

// ==================== FALLBACK: fused kernel (global atomics) ================
__global__ __launch_bounds__(1024, 8) void edge_kernel_atomic(
    const float* __restrict__ edge_weight,
    const float* __restrict__ edge_attr,
    const float* __restrict__ fw1, const float* __restrict__ fb1,
    const float* __restrict__ fw2, const float* __restrict__ fb2,
    const int* __restrict__ eidx,
    const float* __restrict__ h,
    float* agg, int E, int ntiles)
{
    extern __shared__ char smem[];
    char* sT  = smem;
    char* sB1 = smem + 32768;
    char* sB2 = smem + 49152;

    for (int i = threadIdx.x * 8; i < FD * RD; i += blockDim.x * 8) {
        int r = i >> 6, c = i & 63;
        const float4* g = (const float4*)(fw1 + (size_t)r * RD + c);
        float4 v0 = g[0], v1 = g[1];
        half8_t hv;
        hv[0] = (_Float16)v0.x; hv[1] = (_Float16)v0.y;
        hv[2] = (_Float16)v0.z; hv[3] = (_Float16)v0.w;
        hv[4] = (_Float16)v1.x; hv[5] = (_Float16)v1.y;
        hv[6] = (_Float16)v1.z; hv[7] = (_Float16)v1.w;
        *(half8_t*)(sB1 + r * 128 + ((c * 2) ^ ((r & 7) << 4))) = hv;
    }
    for (int i = threadIdx.x * 8; i < FD * FD; i += blockDim.x * 8) {
        int r = i >> 7, c = i & 127;
        const float4* g = (const float4*)(fw2 + (size_t)r * FD + c);
        float4 v0 = g[0], v1 = g[1];
        half8_t hv;
        hv[0] = (_Float16)v0.x; hv[1] = (_Float16)v0.y;
        hv[2] = (_Float16)v0.z; hv[3] = (_Float16)v0.w;
        hv[4] = (_Float16)v1.x; hv[5] = (_Float16)v1.y;
        hv[6] = (_Float16)v1.z; hv[7] = (_Float16)v1.w;
        *(half8_t*)(sB2 + r * 256 + ((c * 2) ^ ((r & 7) << 4))) = hv;
    }
    __syncthreads();

    const int* srcp = eidx;
    const int* dstp = eidx + E;
    int lane = threadIdx.x & 63;
    int wid  = threadIdx.x >> 6;
    int wm = wid >> 2;
    int wn = wid & 3;
    int l15 = lane & 15;
    int l4  = lane >> 4;

    for (int tile = blockIdx.x; tile < ntiles; tile += gridDim.x) {
        int e0 = tile * TE;
        for (int i = threadIdx.x * 8; i < TE * RD; i += blockDim.x * 8) {
            int r = i >> 6, c = i & 63;
            half8_t hv;
            if (e0 + r < E) {
                const float4* g = (const float4*)(edge_attr + (size_t)(e0 + r) * RD + c);
                float4 v0 = g[0], v1 = g[1];
                hv[0] = (_Float16)v0.x; hv[1] = (_Float16)v0.y;
                hv[2] = (_Float16)v0.z; hv[3] = (_Float16)v0.w;
                hv[4] = (_Float16)v1.x; hv[5] = (_Float16)v1.y;
                hv[6] = (_Float16)v1.z; hv[7] = (_Float16)v1.w;
            } else {
                for (int q = 0; q < 8; ++q) hv[q] = (_Float16)0.0f;
            }
            *(half8_t*)(sT + r * 128 + ((c * 2) ^ ((r & 7) << 4))) = hv;
        }
        __syncthreads();

        floatx4 acc[2][2];
#pragma unroll
        for (int mi = 0; mi < 2; ++mi)
#pragma unroll
            for (int ni = 0; ni < 2; ++ni)
                acc[mi][ni] = (floatx4){0.f, 0.f, 0.f, 0.f};
#pragma unroll
        for (int ks = 0; ks < 2; ++ks) {
            int k = ks * 32 + l4 * 8;
            half8_t a[2], b[2];
#pragma unroll
            for (int mi = 0; mi < 2; ++mi)
                a[mi] = lds_read8(sT, wm * 32 + mi * 16 + l15, 128, k);
#pragma unroll
            for (int ni = 0; ni < 2; ++ni)
                b[ni] = lds_read8(sB1, wn * 32 + ni * 16 + l15, 128, k);
#pragma unroll
            for (int mi = 0; mi < 2; ++mi)
#pragma unroll
                for (int ni = 0; ni < 2; ++ni)
                    acc[mi][ni] = __builtin_amdgcn_mfma_f32_16x16x32_f16(
                        a[mi], b[ni], acc[mi][ni], 0, 0, 0);
        }
        __syncthreads();

#pragma unroll
        for (int ni = 0; ni < 2; ++ni) {
            int f = wn * 32 + ni * 16 + l15;
            float bias = fb1[f];
#pragma unroll
            for (int mi = 0; mi < 2; ++mi) {
#pragma unroll
                for (int j = 0; j < 4; ++j) {
                    int e = wm * 32 + mi * 16 + l4 * 4 + j;
                    float t = fast_tanh(acc[mi][ni][j] + bias);
                    *(_Float16*)(sT + e * 256 + ((f * 2) ^ ((e & 7) << 4))) =
                        (_Float16)t;
                }
            }
        }
        __syncthreads();

        floatx4 acc2[2][2];
#pragma unroll
        for (int mi = 0; mi < 2; ++mi)
#pragma unroll
            for (int ni = 0; ni < 2; ++ni)
                acc2[mi][ni] = (floatx4){0.f, 0.f, 0.f, 0.f};
#pragma unroll
        for (int ks = 0; ks < 4; ++ks) {
            int k = ks * 32 + l4 * 8;
            half8_t a[2], b[2];
#pragma unroll
            for (int mi = 0; mi < 2; ++mi)
                a[mi] = lds_read8(sT, wm * 32 + mi * 16 + l15, 256, k);
#pragma unroll
            for (int ni = 0; ni < 2; ++ni)
                b[ni] = lds_read8(sB2, wn * 32 + ni * 16 + l15, 256, k);
#pragma unroll
            for (int mi = 0; mi < 2; ++mi)
#pragma unroll
                for (int ni = 0; ni < 2; ++ni)
                    acc2[mi][ni] = __builtin_amdgcn_mfma_f32_16x16x32_f16(
                        a[mi], b[ni], acc2[mi][ni], 0, 0, 0);
        }
        __syncthreads();

        float bias2[2];
        int gcol[2];
#pragma unroll
        for (int ni = 0; ni < 2; ++ni) {
            gcol[ni] = wn * 32 + ni * 16 + l15;
            bias2[ni] = fb2[gcol[ni]];
        }
#pragma unroll
        for (int mi = 0; mi < 2; ++mi) {
            int ge[4], s4[4], dn4[4];
            float d4[4];
#pragma unroll
            for (int j = 0; j < 4; ++j) {
                int el = wm * 32 + mi * 16 + l4 * 4 + j;
                ge[j] = e0 + el;
                int idx = (ge[j] < E) ? ge[j] : (E - 1);
                s4[j]  = srcp[idx];
                dn4[j] = dstp[idx];
                d4[j]  = edge_weight[idx];
            }
#pragma unroll
            for (int j = 0; j < 4; ++j) {
                if (ge[j] >= E) continue;
                float C = (d4[j] < RC_CUT)
                            ? 0.5f * (__cosf(d4[j] * 0.6283185307179586f) + 1.0f)
                            : 0.0f;
                const float* hrow = h + (size_t)s4[j] * FD;
                float* ar = agg + (size_t)dn4[j] * FD;
#pragma unroll
                for (int ni = 0; ni < 2; ++ni) {
                    int g = gcol[ni];
                    float wv = (acc2[mi][ni][j] + bias2[ni]) * C;
                    atomicAdd(ar + g, wv * hrow[g]);
                }
            }
        }
    }
}

// ---------------- final: disc conv + lin2 + tanh + lin ----------------
__global__ __launch_bounds__(256) void final_kernel(
    const float* aggin, const float* __restrict__ h,
    const float* __restrict__ disc_w,
    const float* __restrict__ lin2_w, const float* __restrict__ lin2_b,
    const float* __restrict__ lin_w, const float* __restrict__ lin_b,
    float* out, int n)
{
    __shared__ float sg[16][FD];
    __shared__ float sm[16][FD];
    int base = blockIdx.x * 16;
    for (int i = threadIdx.x; i < 16 * FD; i += 256) {
        int r = i >> 7, c = i & 127;
        int row = base + r;
        float v = 0.0f;
        if (row < n) {
            v = aggin[(size_t)row * FD + c] + disc_w[c] * h[(size_t)row * FD + c];
            if (row + 1 < n) v += disc_w[FD + c] * h[(size_t)(row + 1) * FD + c];
            if (row >= 1)    v += disc_w[2 * FD + c] * h[(size_t)(row - 1) * FD + c];
        }
        sg[r][c] = v;
    }
    __syncthreads();
    int f = threadIdx.x & 127;
    int half = threadIdx.x >> 7;
    {
        float acc[8];
        float b = lin2_b[f];
#pragma unroll
        for (int r = 0; r < 8; ++r) acc[r] = b;
        const float* wrow = lin2_w + (size_t)f * FD;
        for (int k = 0; k < FD; ++k) {
            float wv = wrow[k];
#pragma unroll
            for (int r = 0; r < 8; ++r) acc[r] += sg[half * 8 + r][k] * wv;
        }
#pragma unroll
        for (int r = 0; r < 8; ++r) sm[half * 8 + r][f] = fast_tanh(acc[r]);
    }
    __syncthreads();
    {
        float acc[8];
        float b = lin_b[f];
#pragma unroll
        for (int r = 0; r < 8; ++r) acc[r] = b;
        const float* wrow = lin_w + (size_t)f * HD;
        for (int k = 0; k < FD; ++k) {
            float wv = wrow[k];
#pragma unroll
            for (int r = 0; r < 8; ++r) acc[r] += sm[half * 8 + r][k] * wv;
        }
#pragma unroll
        for (int r = 0; r < 8; ++r) {
            int row = base + half * 8 + r;
            if (row < n) out[(size_t)row * HD + f] = acc[r];
        }
    }
}

extern "C" void kernel_launch(void* const* d_in, const int* in_sizes, int n_in,
                              void* d_out, int out_size, void* d_ws, size_t ws_size,
                              hipStream_t stream)
{
    const float* x      = (const float*)d_in[0];
    const float* ew     = (const float*)d_in[1];
    const float* ea     = (const float*)d_in[2];
    const float* fw1    = (const float*)d_in[3];
    const float* fb1    = (const float*)d_in[4];
    const float* fw2    = (const float*)d_in[5];
    const float* fb2    = (const float*)d_in[6];
    const float* lin1_w = (const float*)d_in[7];
    const float* lin2_w = (const float*)d_in[8];
    const float* lin2_b = (const float*)d_in[9];
    const float* disc_w = (const float*)d_in[10];
    const float* lin_w  = (const float*)d_in[11];
    const float* lin_b  = (const float*)d_in[12];
    const int*   eidx   = (const int*)d_in[13];

    int n = in_sizes[0] / HD;
    int E = in_sizes[1];
    int ntiles = (E + TE - 1) / TE;
    int nb = (n + 255) / 256;
    float* out = (float*)d_out;

    const int* srcp = eidx;
    const int* dstp = eidx + E;

    // workspace layout (16B-aligned sections)
    char* base = (char*)d_ws;
    float*     h    = (float*)base;                       // n*128 f32
    size_t off_h    = (size_t)n * FD * 4;
    _Float16*  Wp   = (_Float16*)(base + off_h);          // E*128 f16
    size_t off_w    = off_h + (size_t)E * FD * 2;
    int*       inv  = (int*)(base + off_w);               // E ints
    size_t off_i    = off_w + (size_t)E * 4;
    unsigned int* meta = (unsigned int*)(base + off_i);   // E u32
    size_t off_m    = off_i + (size_t)E * 4;
    int*       cnt  = (int*)(base + off_m);               // n ints (per-dst)
    int*       offs = cnt + n;                            // n+1 ints
    int*       bsum = offs + n + 1;                       // nb ints
    size_t need     = off_m + (size_t)(2 * n + nb + 16) * 4;

    hipMemsetAsync(d_out, 0, (size_t)out_size * sizeof(float), stream);
    lin1_kernel<<<(n + 15) / 16, 256, 0, stream>>>(x, lin1_w, h, n);

    size_t smem = 81920;   // 80 KB -> 2 blocks/CU
    if (ws_size >= need && n <= 65535) {
        // ---------- two-phase path: sorted-by-dst, CSR register agg ----------
        hipMemsetAsync(cnt, 0, (size_t)n * sizeof(int), stream);
        count_kernel<<<2048, 256, 0, stream>>>(dstp, cnt, E);
        scan1_kernel<<<nb, 256, 0, stream>>>(cnt, bsum, n);
        scan2_kernel<<<1, 64, 0, stream>>>(bsum, nb, offs + n);
        scan3_kernel<<<nb, 256, 0, stream>>>(cnt, bsum, offs, n);
        scatter_kernel<<<2048, 256, 0, stream>>>(srcp, dstp, cnt, inv, meta, E);

        hipFuncSetAttribute((const void*)edge_gemm_kernel,
                            hipFuncAttributeMaxDynamicSharedMemorySize, (int)smem);
        int nblocks = ntiles < 512 ? ntiles : 512;
        edge_gemm_kernel<<<nblocks, 1024, smem, stream>>>(ew, ea, fw1, fb1, fw2, fb2,
                                                          inv, Wp, E, ntiles);

        int ablocks = (n * 16 + 255) / 256;
        agg_kernel<<<ablocks, 256, 0, stream>>>(Wp, meta, offs, h, out, n);
    } else {
        // ---------- fallback: proven fused atomic kernel ----------
        hipFuncSetAttribute((const void*)edge_kernel_atomic,
                            hipFuncAttributeMaxDynamicSharedMemorySize, (int)smem);
        int nblocks = ntiles < 512 ? ntiles : 512;
        edge_kernel_atomic<<<nblocks, 1024, smem, stream>>>(ew, ea, fw1, fb1, fw2, fb2,
                                                            eidx, h, out, E, ntiles);
    }

    final_kernel<<<(n + 15) / 16, 256, 0, stream>>>(out, h, disc_w, lin2_w, lin2_b,
                                                    lin_w, lin_b, out, n);
}

// Round 7
// 883.427 us; speedup vs baseline: 2.7157x; 1.0396x over previous
//
#include <hip/hip_runtime.h>
#include <math.h>

#define HD 128
#define FD 128
#define RD 64
#define TE 128          // edges per tile
#define RC_CUT 5.0f

typedef _Float16 half8_t __attribute__((ext_vector_type(8)));
typedef float floatx4 __attribute__((ext_vector_type(4)));

__device__ __forceinline__ float fast_tanh(float x) {
    float ex = __expf(2.0f * x);
    return 1.0f - 2.0f / (ex + 1.0f);
}

// ---------------- lin1: h = x @ lin1_w.T ----------------
__global__ __launch_bounds__(256) void lin1_kernel(const float* __restrict__ x,
                                                   const float* __restrict__ w,
                                                   float* __restrict__ h, int n)
{
    __shared__ float sx[16][HD];
    int base = blockIdx.x * 16;
    for (int i = threadIdx.x; i < 16 * HD; i += 256) {
        int r = i >> 7, c = i & 127;
        int row = base + r;
        sx[r][c] = (row < n) ? x[(size_t)row * HD + c] : 0.0f;
    }
    __syncthreads();
    int f = threadIdx.x & 127;
    int half = threadIdx.x >> 7;
    float acc[8];
#pragma unroll
    for (int r = 0; r < 8; ++r) acc[r] = 0.0f;
    const float* wrow = w + (size_t)f * HD;
    for (int k = 0; k < HD; k += 4) {
        float4 wv = *(const float4*)(wrow + k);
#pragma unroll
        for (int r = 0; r < 8; ++r) {
            acc[r] += sx[half * 8 + r][k]     * wv.x;
            acc[r] += sx[half * 8 + r][k + 1] * wv.y;
            acc[r] += sx[half * 8 + r][k + 2] * wv.z;
            acc[r] += sx[half * 8 + r][k + 3] * wv.w;
        }
    }
#pragma unroll
    for (int r = 0; r < 8; ++r) {
        int row = base + half * 8 + r;
        if (row < n) h[(size_t)row * FD + f] = acc[r];
    }
}

// ---------------- bucketing by dst: count / 3-level scan / scatter ----------
__global__ __launch_bounds__(256) void count_kernel(const int* __restrict__ dstp,
                                                    int* cnt, int E)
{
    for (int e = blockIdx.x * blockDim.x + threadIdx.x; e < E;
         e += gridDim.x * blockDim.x)
        atomicAdd(&cnt[dstp[e]], 1);
}

// level 1: per-256-chunk block sums
__global__ __launch_bounds__(256) void scan1_kernel(const int* __restrict__ cnt,
                                                    int* bsum, int n)
{
    int i = blockIdx.x * 256 + threadIdx.x;
    int v = (i < n) ? cnt[i] : 0;
    int lane = threadIdx.x & 63;
    int wv = threadIdx.x >> 6;
    int s = v;
#pragma unroll
    for (int d = 1; d < 64; d <<= 1) s += __shfl_xor(s, d);
    __shared__ int ws[4];
    if (lane == 0) ws[wv] = s;
    __syncthreads();
    if (threadIdx.x == 0) bsum[blockIdx.x] = ws[0] + ws[1] + ws[2] + ws[3];
}

// level 2: single-wave exclusive scan of block sums
__global__ void scan2_kernel(int* bsum, int nb, int* totalp)
{
    int lane = threadIdx.x;
    int carry = 0;
    for (int base = 0; base < nb; base += 64) {
        int i = base + lane;
        int v = (i < nb) ? bsum[i] : 0;
        int orig = v;
#pragma unroll
        for (int d = 1; d < 64; d <<= 1) {
            int t = __shfl_up(v, d);
            if (lane >= d) v += t;
        }
        if (i < nb) bsum[i] = carry + v - orig;
        carry += __shfl(v, 63);
    }
    if (lane == 0) *totalp = carry;
}

// level 3: per-block exclusive rescan + block offset; offs & cursor copy
__global__ __launch_bounds__(256) void scan3_kernel(int* cnt, const int* __restrict__ bsum,
                                                    int* offs, int n)
{
    int i = blockIdx.x * 256 + threadIdx.x;
    int v = (i < n) ? cnt[i] : 0;
    int lane = threadIdx.x & 63;
    int wv = threadIdx.x >> 6;
    int incl = v;
#pragma unroll
    for (int d = 1; d < 64; d <<= 1) {
        int t = __shfl_up(incl, d);
        if (lane >= d) incl += t;
    }
    __shared__ int ws[4];
    if (lane == 63) ws[wv] = incl;
    __syncthreads();
    int wbase = 0;
#pragma unroll
    for (int w = 0; w < 4; ++w) wbase += (w < wv) ? ws[w] : 0;
    int excl = bsum[blockIdx.x] + wbase + incl - v;
    if (i < n) { offs[i] = excl; cnt[i] = excl; }   // cnt becomes scatter cursor
}

// inv[e] = permuted position; meta[pos] = src | (dst << 16)  (n < 65536)
__global__ __launch_bounds__(256) void scatter_kernel(
    const int* __restrict__ srcp, const int* __restrict__ dstp,
    int* cursor, int* __restrict__ inv, unsigned int* __restrict__ meta, int E)
{
    for (int e = blockIdx.x * blockDim.x + threadIdx.x; e < E;
         e += gridDim.x * blockDim.x) {
        int d = dstp[e];
        int p = atomicAdd(&cursor[d], 1);
        inv[e] = p;
        meta[p] = (unsigned int)srcp[e] | ((unsigned int)d << 16);
    }
}

// ---------------- shared LDS helpers ----------------
__device__ __forceinline__ half8_t lds_read8(const char* base, int row,
                                             int rowstride, int col) {
    int off = row * rowstride + ((col * 2) ^ ((row & 7) << 4));
    return *(const half8_t*)(base + off);
}

// ==================== PHASE A: filter GEMMs, natural edge order ==============
// LDS (80 KB -> 2 blocks/CU): sT @0 (32 KB), sB1 @32768, sB2 @49152
// T14 LATE prefetch (proven R6): next tile's edge_attr loads issued AFTER
// epilogue-1 (acc/acc2 dead -> no spill at the 64-VGPR bound).
__global__ __launch_bounds__(1024, 8) void edge_gemm_kernel(
    const float* __restrict__ edge_weight,
    const float* __restrict__ edge_attr,
    const float* __restrict__ fw1, const float* __restrict__ fb1,
    const float* __restrict__ fw2, const float* __restrict__ fb2,
    const int* __restrict__ inv,
    _Float16* __restrict__ Wp,
    int E, int ntiles)
{
    extern __shared__ char smem[];
    char* sT  = smem;
    char* sB1 = smem + 32768;
    char* sB2 = smem + 49152;

    // ---- stage weights once per block (fp32 -> f16, swizzled) ----
    for (int i = threadIdx.x * 8; i < FD * RD; i += blockDim.x * 8) {
        int r = i >> 6, c = i & 63;
        const float4* g = (const float4*)(fw1 + (size_t)r * RD + c);
        float4 v0 = g[0], v1 = g[1];
        half8_t hv;
        hv[0] = (_Float16)v0.x; hv[1] = (_Float16)v0.y;
        hv[2] = (_Float16)v0.z; hv[3] = (_Float16)v0.w;
        hv[4] = (_Float16)v1.x; hv[5] = (_Float16)v1.y;
        hv[6] = (_Float16)v1.z; hv[7] = (_Float16)v1.w;
        *(half8_t*)(sB1 + r * 128 + ((c * 2) ^ ((r & 7) << 4))) = hv;
    }
    for (int i = threadIdx.x * 8; i < FD * FD; i += blockDim.x * 8) {
        int r = i >> 7, c = i & 127;
        const float4* g = (const float4*)(fw2 + (size_t)r * FD + c);
        float4 v0 = g[0], v1 = g[1];
        half8_t hv;
        hv[0] = (_Float16)v0.x; hv[1] = (_Float16)v0.y;
        hv[2] = (_Float16)v0.z; hv[3] = (_Float16)v0.w;
        hv[4] = (_Float16)v1.x; hv[5] = (_Float16)v1.y;
        hv[6] = (_Float16)v1.z; hv[7] = (_Float16)v1.w;
        *(half8_t*)(sB2 + r * 256 + ((c * 2) ^ ((r & 7) << 4))) = hv;
    }

    int lane = threadIdx.x & 63;
    int wid  = threadIdx.x >> 6;   // 0..15
    int wm = wid >> 2;             // 0..3  (edge dim, 32 each)
    int wn = wid & 3;              // 0..3  (filter dim, 32 each)
    int l15 = lane & 15;
    int l4  = lane >> 4;

    float bias1[2], bias2[2];
    int gcol[2];
#pragma unroll
    for (int ni = 0; ni < 2; ++ni) {
        gcol[ni]  = wn * 32 + ni * 16 + l15;
        bias1[ni] = fb1[gcol[ni]];
        bias2[ni] = fb2[gcol[ni]];
    }

    // prefetch lane mapping: thread -> (row, col8) of the 128x64 A tile
    int pr = threadIdx.x >> 3;          // 0..127
    int pc = (threadIdx.x & 7) * 8;     // 0..56

    // ---- prologue: prefetch first tile's A into registers ----
    float4 pA0 = {0.f, 0.f, 0.f, 0.f}, pA1 = {0.f, 0.f, 0.f, 0.f};
    {
        int e = blockIdx.x * TE + pr;
        if (e < E) {
            const float4* g = (const float4*)(edge_attr + (size_t)e * RD + pc);
            pA0 = g[0]; pA1 = g[1];
        }
    }
    __syncthreads();   // weights staged

    for (int tile = blockIdx.x; tile < ntiles; tile += gridDim.x) {
        int e0 = tile * TE;
        // ---- stage A from prefetch registers (cvt + ds_write only) ----
        {
            half8_t hv;
            hv[0] = (_Float16)pA0.x; hv[1] = (_Float16)pA0.y;
            hv[2] = (_Float16)pA0.z; hv[3] = (_Float16)pA0.w;
            hv[4] = (_Float16)pA1.x; hv[5] = (_Float16)pA1.y;
            hv[6] = (_Float16)pA1.z; hv[7] = (_Float16)pA1.w;
            *(half8_t*)(sT + pr * 128 + ((pc * 2) ^ ((pr & 7) << 4))) = hv;
        }
        __syncthreads();

        // ---- GEMM1: C1 = A @ fw1^T ----
        floatx4 acc[2][2];
#pragma unroll
        for (int mi = 0; mi < 2; ++mi)
#pragma unroll
            for (int ni = 0; ni < 2; ++ni)
                acc[mi][ni] = (floatx4){0.f, 0.f, 0.f, 0.f};
#pragma unroll
        for (int ks = 0; ks < 2; ++ks) {
            int k = ks * 32 + l4 * 8;
            half8_t a[2], b[2];
#pragma unroll
            for (int mi = 0; mi < 2; ++mi)
                a[mi] = lds_read8(sT, wm * 32 + mi * 16 + l15, 128, k);
#pragma unroll
            for (int ni = 0; ni < 2; ++ni)
                b[ni] = lds_read8(sB1, wn * 32 + ni * 16 + l15, 128, k);
#pragma unroll
            for (int mi = 0; mi < 2; ++mi)
#pragma unroll
                for (int ni = 0; ni < 2; ++ni)
                    acc[mi][ni] = __builtin_amdgcn_mfma_f32_16x16x32_f16(
                        a[mi], b[ni], acc[mi][ni], 0, 0, 0);
        }
        __syncthreads();

        // ---- bias + tanh -> T ----
#pragma unroll
        for (int ni = 0; ni < 2; ++ni) {
            int f = gcol[ni];
            float bias = bias1[ni];
#pragma unroll
            for (int mi = 0; mi < 2; ++mi) {
#pragma unroll
                for (int j = 0; j < 4; ++j) {
                    int e = wm * 32 + mi * 16 + l4 * 4 + j;
                    float t = fast_tanh(acc[mi][ni][j] + bias);
                    *(_Float16*)(sT + e * 256 + ((f * 2) ^ ((e & 7) << 4))) =
                        (_Float16)t;
                }
            }
        }
        __syncthreads();

        // ---- GEMM2: W = T @ fw2^T ----
        floatx4 acc2[2][2];
#pragma unroll
        for (int mi = 0; mi < 2; ++mi)
#pragma unroll
            for (int ni = 0; ni < 2; ++ni)
                acc2[mi][ni] = (floatx4){0.f, 0.f, 0.f, 0.f};
#pragma unroll
        for (int ks = 0; ks < 4; ++ks) {
            int k = ks * 32 + l4 * 8;
            half8_t a[2], b[2];
#pragma unroll
            for (int mi = 0; mi < 2; ++mi)
                a[mi] = lds_read8(sT, wm * 32 + mi * 16 + l15, 256, k);
#pragma unroll
            for (int ni = 0; ni < 2; ++ni)
                b[ni] = lds_read8(sB2, wn * 32 + ni * 16 + l15, 256, k);
#pragma unroll
            for (int mi = 0; mi < 2; ++mi)
#pragma unroll
                for (int ni = 0; ni < 2; ++ni)
                    acc2[mi][ni] = __builtin_amdgcn_mfma_f32_16x16x32_f16(
                        a[mi], b[ni], acc2[mi][ni], 0, 0, 0);
        }
        __syncthreads();   // T consumed; sT reused as W row buffer

        // ---- epilogue 1: cutoff-scale, write f16 W rows into sT ----
#pragma unroll
        for (int mi = 0; mi < 2; ++mi) {
            float d4[4];
#pragma unroll
            for (int j = 0; j < 4; ++j) {
                int el = wm * 32 + mi * 16 + l4 * 4 + j;
                int idx = (e0 + el < E) ? (e0 + el) : (E - 1);
                d4[j] = edge_weight[idx];
            }
#pragma unroll
            for (int j = 0; j < 4; ++j) {
                int el = wm * 32 + mi * 16 + l4 * 4 + j;
                float C = (d4[j] < RC_CUT)
                            ? 0.5f * (__cosf(d4[j] * 0.6283185307179586f) + 1.0f)
                            : 0.0f;
#pragma unroll
                for (int ni = 0; ni < 2; ++ni) {
                    int f = gcol[ni];
                    float wv = (acc2[mi][ni][j] + bias2[ni]) * C;
                    *(_Float16*)(sT + el * 256 + ((f * 2) ^ ((el & 7) << 4))) =
                        (_Float16)wv;
                }
            }
        }

        // ---- T14 late prefetch: acc/acc2 now dead, pressure minimal ----
        {
            int nt = tile + gridDim.x;
            pA0 = (float4){0.f, 0.f, 0.f, 0.f};
            pA1 = (float4){0.f, 0.f, 0.f, 0.f};
            if (nt < ntiles) {
                int e = nt * TE + pr;
                if (e < E) {
                    const float4* g = (const float4*)(edge_attr + (size_t)e * RD + pc);
                    pA0 = g[0]; pA1 = g[1];
                }
            }
        }
        __syncthreads();

        // ---- epilogue 2: scatter whole rows to Wp (16-B chunks) ----
#pragma unroll
        for (int k = 0; k < 2; ++k) {
            int t = threadIdx.x + k * 1024;
            int r = t >> 4, ch = t & 15;
            int e = e0 + r;
            if (e < E) {
                half8_t v = lds_read8(sT, r, 256, ch * 8);
                int pv = inv[e];
                *(half8_t*)(Wp + (size_t)pv * FD + ch * 8) = v;
            }
        }
        __syncthreads();   // sT fully consumed; next tile may overwrite
    }
}

// ==================== PHASE B: CSR per-dst register aggregation ==============
// 16-lane group owns ONE dst row. 2-deep software pipeline (ping-pong, static
// names): chunk c+1's meta + h rows prefetched while chunk c FMAs. Wp reads
// coalesced-sequential, zero atomics, one float4x2 store per lane.
#define AGG_PREF(MV, H0, H1, BASE)                                           \
    {                                                                        \
        MV##0 = meta[(BASE)];     MV##1 = meta[(BASE) + 1];                  \
        MV##2 = meta[(BASE) + 2]; MV##3 = meta[(BASE) + 3];                  \
        const float4* q0 = (const float4*)(h + (size_t)(MV##0 & 0xFFFFu) * FD + lg); \
        const float4* q1 = (const float4*)(h + (size_t)(MV##1 & 0xFFFFu) * FD + lg); \
        const float4* q2 = (const float4*)(h + (size_t)(MV##2 & 0xFFFFu) * FD + lg); \
        const float4* q3 = (const float4*)(h + (size_t)(MV##3 & 0xFFFFu) * FD + lg); \
        H0[0] = q0[0]; H1[0] = q0[1];                                        \
        H0[1] = q1[0]; H1[1] = q1[1];                                        \
        H0[2] = q2[0]; H1[2] = q2[1];                                        \
        H0[3] = q3[0]; H1[3] = q3[1];                                        \
    }

#define AGG_STEP(H0, H1, BASE)                                               \
    {                                                                        \
        half8_t w_[4];                                                       \
        _Pragma("unroll")                                                    \
        for (int u = 0; u < 4; ++u)                                          \
            w_[u] = *(const half8_t*)(Wp + (size_t)((BASE) + u) * FD + lg);  \
        _Pragma("unroll")                                                    \
        for (int u = 0; u < 4; ++u) {                                        \
            acc[0] += (float)w_[u][0] * H0[u].x;                             \
            acc[1] += (float)w_[u][1] * H0[u].y;                             \
            acc[2] += (float)w_[u][2] * H0[u].z;                             \
            acc[3] += (float)w_[u][3] * H0[u].w;                             \
            acc[4] += (float)w_[u][4] * H1[u].x;                             \
            acc[5] += (float)w_[u][5] * H1[u].y;                             \
            acc[6] += (float)w_[u][6] * H1[u].z;                             \
            acc[7] += (float)w_[u][7] * H1[u].w;                             \
        }                                                                    \
    }

__global__ __launch_bounds__(256) void agg_kernel(
    const _Float16* __restrict__ Wp,
    const unsigned int* __restrict__ meta,
    const int* __restrict__ offs,
    const float* __restrict__ h,
    float* __restrict__ agg, int n)
{
    int g = (blockIdx.x * 256 + (int)threadIdx.x) >> 4;
    if (g >= n) return;
    int lg = (threadIdx.x & 15) * 8;    // element offset within the 128-col row
    int p  = offs[g];
    int p1 = offs[g + 1];

    float acc[8];
#pragma unroll
    for (int q = 0; q < 8; ++q) acc[q] = 0.0f;

    int nfull = (p1 - p) >> 2;
    int pc = p;
    unsigned mA0, mA1, mA2, mA3, mB0, mB1, mB2, mB3;
    float4 A0[4], A1[4], B0[4], B1[4];

    if (nfull > 0) AGG_PREF(mA, A0, A1, pc);
    int c = 0;
    for (; c + 2 <= nfull; c += 2) {
        AGG_PREF(mB, B0, B1, pc + 4);        // prefetch chunk c+1
        AGG_STEP(A0, A1, pc);                // consume chunk c
        pc += 4;
        if (c + 2 < nfull) AGG_PREF(mA, A0, A1, pc + 4);   // prefetch c+2
        AGG_STEP(B0, B1, pc);                // consume chunk c+1
        pc += 4;
    }
    if (c < nfull) {                          // one leftover full chunk
        AGG_STEP(A0, A1, pc);
        pc += 4;
    }
    for (; pc < p1; ++pc) {                   // scalar tail (0..3 edges)
        unsigned m = meta[pc];
        int s0 = (int)(m & 0xFFFFu);
        half8_t w0 = *(const half8_t*)(Wp + (size_t)pc * FD + lg);
        const float4* ha = (const float4*)(h + (size_t)s0 * FD + lg);
        float4 a0 = ha[0], a1 = ha[1];
        acc[0] += (float)w0[0] * a0.x;
        acc[1] += (float)w0[1] * a0.y;
        acc[2] += (float)w0[2] * a0.z;
        acc[3] += (float)w0[3] * a0.w;
        acc[4] += (float)w0[4] * a1.x;
        acc[5] += (float)w0[5] * a1.y;
        acc[6] += (float)w0[6] * a1.z;
        acc[7] += (float)w0[7] * a1.w;
    }
    float* ar = agg + (size_t)g * FD + lg;
    *(float4*)ar       = (float4){acc[0], acc[1], acc[2], acc[3]};
    *(float4*)(ar + 4) = (float4){acc[4], acc[5], acc[6], acc[7]};
}

// ==================== FALLBACK: fused kernel (global atomics) ================
__global__ __launch_bounds__(1024, 8) void edge_kernel_atomic(
    const float* __restrict__ edge_weight,
    const float* __restrict__ edge_attr,
    const float* __restrict__ fw1, const float* __restrict__ fb1,
    const float* __restrict__ fw2, const float* __restrict__ fb2,
    const int* __restrict__ eidx,
    const float* __restrict__ h,
    float* agg, int E, int ntiles)
{
    extern __shared__ char smem[];
    char* sT  = smem;
    char* sB1 = smem + 32768;
    char* sB2 = smem + 49152;

    for (int i = threadIdx.x * 8; i < FD * RD; i += blockDim.x * 8) {
        int r = i >> 6, c = i & 63;
        const float4* g = (const float4*)(fw1 + (size_t)r * RD + c);
        float4 v0 = g[0], v1 = g[1];
        half8_t hv;
        hv[0] = (_Float16)v0.x; hv[1] = (_Float16)v0.y;
        hv[2] = (_Float16)v0.z; hv[3] = (_Float16)v0.w;
        hv[4] = (_Float16)v1.x; hv[5] = (_Float16)v1.y;
        hv[6] = (_Float16)v1.z; hv[7] = (_Float16)v1.w;
        *(half8_t*)(sB1 + r * 128 + ((c * 2) ^ ((r & 7) << 4))) = hv;
    }
    for (int i = threadIdx.x * 8; i < FD * FD; i += blockDim.x * 8) {
        int r = i >> 7, c = i & 127;
        const float4* g = (const float4*)(fw2 + (size_t)r * FD + c);
        float4 v0 = g[0], v1 = g[1];
        half8_t hv;
        hv[0] = (_Float16)v0.x; hv[1] = (_Float16)v0.y;
        hv[2] = (_Float16)v0.z; hv[3] = (_Float16)v0.w;
        hv[4] = (_Float16)v1.x; hv[5] = (_Float16)v1.y;
        hv[6] = (_Float16)v1.z; hv[7] = (_Float16)v1.w;
        *(half8_t*)(sB2 + r * 256 + ((c * 2) ^ ((r & 7) << 4))) = hv;
    }
    __syncthreads();

    const int* srcp = eidx;
    const int* dstp = eidx + E;
    int lane = threadIdx.x & 63;
    int wid  = threadIdx.x >> 6;
    int wm = wid >> 2;
    int wn = wid & 3;
    int l15 = lane & 15;
    int l4  = lane >> 4;

    for (int tile = blockIdx.x; tile < ntiles; tile += gridDim.x) {
        int e0 = tile * TE;
        for (int i = threadIdx.x * 8; i < TE * RD; i += blockDim.x * 8) {
            int r = i >> 6, c = i & 63;
            half8_t hv;
            if (e0 + r < E) {
                const float4* g = (const float4*)(edge_attr + (size_t)(e0 + r) * RD + c);
                float4 v0 = g[0], v1 = g[1];
                hv[0] = (_Float16)v0.x; hv[1] = (_Float16)v0.y;
                hv[2] = (_Float16)v0.z; hv[3] = (_Float16)v0.w;
                hv[4] = (_Float16)v1.x; hv[5] = (_Float16)v1.y;
                hv[6] = (_Float16)v1.z; hv[7] = (_Float16)v1.w;
            } else {
                for (int q = 0; q < 8; ++q) hv[q] = (_Float16)0.0f;
            }
            *(half8_t*)(sT + r * 128 + ((c * 2) ^ ((r & 7) << 4))) = hv;
        }
        __syncthreads();

        floatx4 acc[2][2];
#pragma unroll
        for (int mi = 0; mi < 2; ++mi)
#pragma unroll
            for (int ni = 0; ni < 2; ++ni)
                acc[mi][ni] = (floatx4){0.f, 0.f, 0.f, 0.f};
#pragma unroll
        for (int ks = 0; ks < 2; ++ks) {
            int k = ks * 32 + l4 * 8;
            half8_t a[2], b[2];
#pragma unroll
            for (int mi = 0; mi < 2; ++mi)
                a[mi] = lds_read8(sT, wm * 32 + mi * 16 + l15, 128, k);
#pragma unroll
            for (int ni = 0; ni < 2; ++ni)
                b[ni] = lds_read8(sB1, wn * 32 + ni * 16 + l15, 128, k);
#pragma unroll
            for (int mi = 0; mi < 2; ++mi)
#pragma unroll
                for (int ni = 0; ni < 2; ++ni)
                    acc[mi][ni] = __builtin_amdgcn_mfma_f32_16x16x32_f16(
                        a[mi], b[ni], acc[mi][ni], 0, 0, 0);
        }
        __syncthreads();

#pragma unroll
        for (int ni = 0; ni < 2; ++ni) {
            int f = wn * 32 + ni * 16 + l15;
            float bias = fb1[f];
#pragma unroll
            for (int mi = 0; mi < 2; ++mi) {
#pragma unroll
                for (int j = 0; j < 4; ++j) {
                    int e = wm * 32 + mi * 16 + l4 * 4 + j;
                    float t = fast_tanh(acc[mi][ni][j] + bias);
                    *(_Float16*)(sT + e * 256 + ((f * 2) ^ ((e & 7) << 4))) =
                        (_Float16)t;
                }
            }
        }
        __syncthreads();

        floatx4 acc2[2][2];
#pragma unroll
        for (int mi = 0; mi < 2; ++mi)
#pragma unroll
            for (int ni = 0; ni < 2; ++ni)
                acc2[mi][ni] = (floatx4){0.f, 0.f, 0.f, 0.f};
#pragma unroll
        for (int ks = 0; ks < 4; ++ks) {
            int k = ks * 32 + l4 * 8;
            half8_t a[2], b[2];
#pragma unroll
            for (int mi = 0; mi < 2; ++mi)
                a[mi] = lds_read8(sT, wm * 32 + mi * 16 + l15, 256, k);
#pragma unroll
            for (int ni = 0; ni < 2; ++ni)
                b[ni] = lds_read8(sB2, wn * 32 + ni * 16 + l15, 256, k);
#pragma unroll
            for (int mi = 0; mi < 2; ++mi)
#pragma unroll
                for (int ni = 0; ni < 2; ++ni)
                    acc2[mi][ni] = __builtin_amdgcn_mfma_f32_16x16x32_f16(
                        a[mi], b[ni], acc2[mi][ni], 0, 0, 0);
        }
        __syncthreads();

        float bias2[2];
        int gcol[2];
#pragma unroll
        for (int ni = 0; ni < 2; ++ni) {
            gcol[ni] = wn * 32 + ni * 16 + l15;
            bias2[ni] = fb2[gcol[ni]];
        }
#pragma unroll
        for (int mi = 0; mi < 2; ++mi) {
            int ge[4], s4[4], dn4[4];
            float d4[4];
#pragma unroll
            for (int j = 0; j < 4; ++j) {
                int el = wm * 32 + mi * 16 + l4 * 4 + j;
                ge[j] = e0 + el;
                int idx = (ge[j] < E) ? ge[j] : (E - 1);
                s4[j]  = srcp[idx];
                dn4[j] = dstp[idx];
                d4[j]  = edge_weight[idx];
            }
#pragma unroll
            for (int j = 0; j < 4; ++j) {
                if (ge[j] >= E) continue;
                float C = (d4[j] < RC_CUT)
                            ? 0.5f * (__cosf(d4[j] * 0.6283185307179586f) + 1.0f)
                            : 0.0f;
                const float* hrow = h + (size_t)s4[j] * FD;
                float* ar = agg + (size_t)dn4[j] * FD;
#pragma unroll
                for (int ni = 0; ni < 2; ++ni) {
                    int g = gcol[ni];
                    float wv = (acc2[mi][ni][j] + bias2[ni]) * C;
                    atomicAdd(ar + g, wv * hrow[g]);
                }
            }
        }
    }
}

// ---------------- final: disc conv + lin2 + tanh + lin ----------------
__global__ __launch_bounds__(256) void final_kernel(
    const float* aggin, const float* __restrict__ h,
    const float* __restrict__ disc_w,
    const float* __restrict__ lin2_w, const float* __restrict__ lin2_b,
    const float* __restrict__ lin_w, const float* __restrict__ lin_b,
    float* out, int n)
{
    __shared__ float sg[16][FD];
    __shared__ float sm[16][FD];
    int base = blockIdx.x * 16;
    for (int i = threadIdx.x; i < 16 * FD; i += 256) {
        int r = i >> 7, c = i & 127;
        int row = base + r;
        float v = 0.0f;
        if (row < n) {
            v = aggin[(size_t)row * FD + c] + disc_w[c] * h[(size_t)row * FD + c];
            if (row + 1 < n) v += disc_w[FD + c] * h[(size_t)(row + 1) * FD + c];
            if (row >= 1)    v += disc_w[2 * FD + c] * h[(size_t)(row - 1) * FD + c];
        }
        sg[r][c] = v;
    }
    __syncthreads();
    int f = threadIdx.x & 127;
    int half = threadIdx.x >> 7;
    {
        float acc[8];
        float b = lin2_b[f];
#pragma unroll
        for (int r = 0; r < 8; ++r) acc[r] = b;
        const float* wrow = lin2_w + (size_t)f * FD;
        for (int k = 0; k < FD; k += 4) {
            float4 wv = *(const float4*)(wrow + k);
#pragma unroll
            for (int r = 0; r < 8; ++r) {
                acc[r] += sg[half * 8 + r][k]     * wv.x;
                acc[r] += sg[half * 8 + r][k + 1] * wv.y;
                acc[r] += sg[half * 8 + r][k + 2] * wv.z;
                acc[r] += sg[half * 8 + r][k + 3] * wv.w;
            }
        }
#pragma unroll
        for (int r = 0; r < 8; ++r) sm[half * 8 + r][f] = fast_tanh(acc[r]);
    }
    __syncthreads();
    {
        float acc[8];
        float b = lin_b[f];
#pragma unroll
        for (int r = 0; r < 8; ++r) acc[r] = b;
        const float* wrow = lin_w + (size_t)f * HD;
        for (int k = 0; k < FD; k += 4) {
            float4 wv = *(const float4*)(wrow + k);
#pragma unroll
            for (int r = 0; r < 8; ++r) {
                acc[r] += sm[half * 8 + r][k]     * wv.x;
                acc[r] += sm[half * 8 + r][k + 1] * wv.y;
                acc[r] += sm[half * 8 + r][k + 2] * wv.z;
                acc[r] += sm[half * 8 + r][k + 3] * wv.w;
            }
        }
#pragma unroll
        for (int r = 0; r < 8; ++r) {
            int row = base + half * 8 + r;
            if (row < n) out[(size_t)row * HD + f] = acc[r];
        }
    }
}

extern "C" void kernel_launch(void* const* d_in, const int* in_sizes, int n_in,
                              void* d_out, int out_size, void* d_ws, size_t ws_size,
                              hipStream_t stream)
{
    const float* x      = (const float*)d_in[0];
    const float* ew     = (const float*)d_in[1];
    const float* ea     = (const float*)d_in[2];
    const float* fw1    = (const float*)d_in[3];
    const float* fb1    = (const float*)d_in[4];
    const float* fw2    = (const float*)d_in[5];
    const float* fb2    = (const float*)d_in[6];
    const float* lin1_w = (const float*)d_in[7];
    const float* lin2_w = (const float*)d_in[8];
    const float* lin2_b = (const float*)d_in[9];
    const float* disc_w = (const float*)d_in[10];
    const float* lin_w  = (const float*)d_in[11];
    const float* lin_b  = (const float*)d_in[12];
    const int*   eidx   = (const int*)d_in[13];

    int n = in_sizes[0] / HD;
    int E = in_sizes[1];
    int ntiles = (E + TE - 1) / TE;
    int nb = (n + 255) / 256;
    float* out = (float*)d_out;

    const int* srcp = eidx;
    const int* dstp = eidx + E;

    // workspace layout (16B-aligned sections)
    char* base = (char*)d_ws;
    float*     h    = (float*)base;                       // n*128 f32
    size_t off_h    = (size_t)n * FD * 4;
    _Float16*  Wp   = (_Float16*)(base + off_h);          // E*128 f16
    size_t off_w    = off_h + (size_t)E * FD * 2;
    int*       inv  = (int*)(base + off_w);               // E ints
    size_t off_i    = off_w + (size_t)E * 4;
    unsigned int* meta = (unsigned int*)(base + off_i);   // E u32
    size_t off_m    = off_i + (size_t)E * 4;
    int*       cnt  = (int*)(base + off_m);               // n ints (per-dst)
    int*       offs = cnt + n;                            // n+1 ints
    int*       bsum = offs + n + 1;                       // nb ints
    size_t need     = off_m + (size_t)(2 * n + nb + 16) * 4;

    lin1_kernel<<<(n + 15) / 16, 256, 0, stream>>>(x, lin1_w, h, n);

    size_t smem = 81920;   // 80 KB -> 2 blocks/CU
    if (ws_size >= need && n <= 65535) {
        // ---------- two-phase path: sorted-by-dst, CSR register agg ----------
        // (no out-memset: agg_kernel plain-stores every row)
        hipMemsetAsync(cnt, 0, (size_t)n * sizeof(int), stream);
        count_kernel<<<2048, 256, 0, stream>>>(dstp, cnt, E);
        scan1_kernel<<<nb, 256, 0, stream>>>(cnt, bsum, n);
        scan2_kernel<<<1, 64, 0, stream>>>(bsum, nb, offs + n);
        scan3_kernel<<<nb, 256, 0, stream>>>(cnt, bsum, offs, n);
        scatter_kernel<<<2048, 256, 0, stream>>>(srcp, dstp, cnt, inv, meta, E);

        hipFuncSetAttribute((const void*)edge_gemm_kernel,
                            hipFuncAttributeMaxDynamicSharedMemorySize, (int)smem);
        int nblocks = ntiles < 512 ? ntiles : 512;
        edge_gemm_kernel<<<nblocks, 1024, smem, stream>>>(ew, ea, fw1, fb1, fw2, fb2,
                                                          inv, Wp, E, ntiles);

        int ablocks = (n * 16 + 255) / 256;
        agg_kernel<<<ablocks, 256, 0, stream>>>(Wp, meta, offs, h, out, n);
    } else {
        // ---------- fallback: proven fused atomic kernel ----------
        hipMemsetAsync(d_out, 0, (size_t)out_size * sizeof(float), stream);
        hipFuncSetAttribute((const void*)edge_kernel_atomic,
                            hipFuncAttributeMaxDynamicSharedMemorySize, (int)smem);
        int nblocks = ntiles < 512 ? ntiles : 512;
        edge_kernel_atomic<<<nblocks, 1024, smem, stream>>>(ew, ea, fw1, fb1, fw2, fb2,
                                                            eidx, h, out, E, ntiles);
    }

    final_kernel<<<(n + 15) / 16, 256, 0, stream>>>(out, h, disc_w, lin2_w, lin2_b,
                                                    lin_w, lin_b, out, n);
}

// Round 8
// 863.457 us; speedup vs baseline: 2.7785x; 1.0231x over previous
//
#include <hip/hip_runtime.h>
#include <math.h>

#define HD 128
#define FD 128
#define RD 64
#define TE 128          // edges per tile
#define RC_CUT 5.0f

typedef _Float16 half8_t __attribute__((ext_vector_type(8)));
typedef _Float16 half4_t __attribute__((ext_vector_type(4)));
typedef _Float16 half2_t __attribute__((ext_vector_type(2)));
typedef float floatx4 __attribute__((ext_vector_type(4)));

__device__ __forceinline__ float fast_tanh(float x) {
    float ex = __expf(2.0f * x);
    return 1.0f - 2.0f / (ex + 1.0f);
}

// ---------------- lin1: h = x @ lin1_w.T ----------------
__global__ __launch_bounds__(256) void lin1_kernel(const float* __restrict__ x,
                                                   const float* __restrict__ w,
                                                   float* __restrict__ h, int n)
{
    __shared__ float sx[16][HD];
    int base = blockIdx.x * 16;
    for (int i = threadIdx.x; i < 16 * HD; i += 256) {
        int r = i >> 7, c = i & 127;
        int row = base + r;
        sx[r][c] = (row < n) ? x[(size_t)row * HD + c] : 0.0f;
    }
    __syncthreads();
    int f = threadIdx.x & 127;
    int half = threadIdx.x >> 7;
    float acc[8];
#pragma unroll
    for (int r = 0; r < 8; ++r) acc[r] = 0.0f;
    const float* wrow = w + (size_t)f * HD;
    for (int k = 0; k < HD; k += 4) {
        float4 wv = *(const float4*)(wrow + k);
#pragma unroll
        for (int r = 0; r < 8; ++r) {
            acc[r] += sx[half * 8 + r][k]     * wv.x;
            acc[r] += sx[half * 8 + r][k + 1] * wv.y;
            acc[r] += sx[half * 8 + r][k + 2] * wv.z;
            acc[r] += sx[half * 8 + r][k + 3] * wv.w;
        }
    }
#pragma unroll
    for (int r = 0; r < 8; ++r) {
        int row = base + half * 8 + r;
        if (row < n) h[(size_t)row * FD + f] = acc[r];
    }
}

// ---------------- bucketing by dst: count / 3-level scan / scatter ----------
__global__ __launch_bounds__(256) void count_kernel(const int* __restrict__ dstp,
                                                    int* cnt, int E)
{
    for (int e = blockIdx.x * blockDim.x + threadIdx.x; e < E;
         e += gridDim.x * blockDim.x)
        atomicAdd(&cnt[dstp[e]], 1);
}

__global__ __launch_bounds__(256) void scan1_kernel(const int* __restrict__ cnt,
                                                    int* bsum, int n)
{
    int i = blockIdx.x * 256 + threadIdx.x;
    int v = (i < n) ? cnt[i] : 0;
    int lane = threadIdx.x & 63;
    int wv = threadIdx.x >> 6;
    int s = v;
#pragma unroll
    for (int d = 1; d < 64; d <<= 1) s += __shfl_xor(s, d);
    __shared__ int ws[4];
    if (lane == 0) ws[wv] = s;
    __syncthreads();
    if (threadIdx.x == 0) bsum[blockIdx.x] = ws[0] + ws[1] + ws[2] + ws[3];
}

__global__ void scan2_kernel(int* bsum, int nb, int* totalp)
{
    int lane = threadIdx.x;
    int carry = 0;
    for (int base = 0; base < nb; base += 64) {
        int i = base + lane;
        int v = (i < nb) ? bsum[i] : 0;
        int orig = v;
#pragma unroll
        for (int d = 1; d < 64; d <<= 1) {
            int t = __shfl_up(v, d);
            if (lane >= d) v += t;
        }
        if (i < nb) bsum[i] = carry + v - orig;
        carry += __shfl(v, 63);
    }
    if (lane == 0) *totalp = carry;
}

__global__ __launch_bounds__(256) void scan3_kernel(int* cnt, const int* __restrict__ bsum,
                                                    int* offs, int n)
{
    int i = blockIdx.x * 256 + threadIdx.x;
    int v = (i < n) ? cnt[i] : 0;
    int lane = threadIdx.x & 63;
    int wv = threadIdx.x >> 6;
    int incl = v;
#pragma unroll
    for (int d = 1; d < 64; d <<= 1) {
        int t = __shfl_up(incl, d);
        if (lane >= d) incl += t;
    }
    __shared__ int ws[4];
    if (lane == 63) ws[wv] = incl;
    __syncthreads();
    int wbase = 0;
#pragma unroll
    for (int w = 0; w < 4; ++w) wbase += (w < wv) ? ws[w] : 0;
    int excl = bsum[blockIdx.x] + wbase + incl - v;
    if (i < n) { offs[i] = excl; cnt[i] = excl; }   // cnt becomes scatter cursor
}

// inv[e] = permuted position; meta[pos] = src | (dst << 16)  (n < 65536)
__global__ __launch_bounds__(256) void scatter_kernel(
    const int* __restrict__ srcp, const int* __restrict__ dstp,
    int* cursor, int* __restrict__ inv, unsigned int* __restrict__ meta, int E)
{
    for (int e = blockIdx.x * blockDim.x + threadIdx.x; e < E;
         e += gridDim.x * blockDim.x) {
        int d = dstp[e];
        int p = atomicAdd(&cursor[d], 1);
        inv[e] = p;
        meta[p] = (unsigned int)srcp[e] | ((unsigned int)d << 16);
    }
}

// ---------------- shared LDS helpers ----------------
__device__ __forceinline__ half8_t lds_read8(const char* base, int row,
                                             int rowstride, int col) {
    int off = row * rowstride + ((col * 2) ^ ((row & 7) << 4));
    return *(const half8_t*)(base + off);
}

// ==================== PHASE A: filter GEMMs, natural edge order ==============
// LDS (80 KB -> 2 blocks/CU): sT @0 (32 KB), sB1 @32768, sB2 @49152
// SWAPPED MFMA (mfma(b,a) -> transposed fragment): lane holds 4 consecutive
// f-cols of ONE edge -> tanh stage uses ds_write_b64 (4x fewer LDS ops) and
// the W epilogue stores half4 DIRECTLY to Wp[inv[e]] (no LDS round trip).
// T14 LATE prefetch (proven R6) for next tile's edge_attr.
__global__ __launch_bounds__(1024, 8) void edge_gemm_kernel(
    const float* __restrict__ edge_weight,
    const float* __restrict__ edge_attr,
    const float* __restrict__ fw1, const float* __restrict__ fb1,
    const float* __restrict__ fw2, const float* __restrict__ fb2,
    const int* __restrict__ inv,
    _Float16* __restrict__ Wp,
    int E, int ntiles)
{
    extern __shared__ char smem[];
    char* sT  = smem;
    char* sB1 = smem + 32768;
    char* sB2 = smem + 49152;

    // ---- stage weights once per block (fp32 -> f16, swizzled) ----
    for (int i = threadIdx.x * 8; i < FD * RD; i += blockDim.x * 8) {
        int r = i >> 6, c = i & 63;
        const float4* g = (const float4*)(fw1 + (size_t)r * RD + c);
        float4 v0 = g[0], v1 = g[1];
        half8_t hv;
        hv[0] = (_Float16)v0.x; hv[1] = (_Float16)v0.y;
        hv[2] = (_Float16)v0.z; hv[3] = (_Float16)v0.w;
        hv[4] = (_Float16)v1.x; hv[5] = (_Float16)v1.y;
        hv[6] = (_Float16)v1.z; hv[7] = (_Float16)v1.w;
        *(half8_t*)(sB1 + r * 128 + ((c * 2) ^ ((r & 7) << 4))) = hv;
    }
    for (int i = threadIdx.x * 8; i < FD * FD; i += blockDim.x * 8) {
        int r = i >> 7, c = i & 127;
        const float4* g = (const float4*)(fw2 + (size_t)r * FD + c);
        float4 v0 = g[0], v1 = g[1];
        half8_t hv;
        hv[0] = (_Float16)v0.x; hv[1] = (_Float16)v0.y;
        hv[2] = (_Float16)v0.z; hv[3] = (_Float16)v0.w;
        hv[4] = (_Float16)v1.x; hv[5] = (_Float16)v1.y;
        hv[6] = (_Float16)v1.z; hv[7] = (_Float16)v1.w;
        *(half8_t*)(sB2 + r * 256 + ((c * 2) ^ ((r & 7) << 4))) = hv;
    }

    int lane = threadIdx.x & 63;
    int wid  = threadIdx.x >> 6;   // 0..15
    int wm = wid >> 2;             // 0..3  (edge dim, 32 each)
    int wn = wid & 3;              // 0..3  (filter dim, 32 each)
    int l15 = lane & 15;
    int l4  = lane >> 4;

    // swapped-fragment f-base per (ni): 4 consecutive f columns
    int fbase[2];
#pragma unroll
    for (int ni = 0; ni < 2; ++ni) fbase[ni] = wn * 32 + ni * 16 + l4 * 4;

    // prefetch lane mapping: thread -> (row, col8) of the 128x64 A tile
    int pr = threadIdx.x >> 3;          // 0..127
    int pc = (threadIdx.x & 7) * 8;     // 0..56

    // ---- prologue: prefetch first tile's A into registers ----
    float4 pA0 = {0.f, 0.f, 0.f, 0.f}, pA1 = {0.f, 0.f, 0.f, 0.f};
    {
        int e = blockIdx.x * TE + pr;
        if (e < E) {
            const float4* g = (const float4*)(edge_attr + (size_t)e * RD + pc);
            pA0 = g[0]; pA1 = g[1];
        }
    }
    __syncthreads();   // weights staged

    for (int tile = blockIdx.x; tile < ntiles; tile += gridDim.x) {
        int e0 = tile * TE;
        // ---- stage A from prefetch registers (cvt + ds_write only) ----
        {
            half8_t hv;
            hv[0] = (_Float16)pA0.x; hv[1] = (_Float16)pA0.y;
            hv[2] = (_Float16)pA0.z; hv[3] = (_Float16)pA0.w;
            hv[4] = (_Float16)pA1.x; hv[5] = (_Float16)pA1.y;
            hv[6] = (_Float16)pA1.z; hv[7] = (_Float16)pA1.w;
            *(half8_t*)(sT + pr * 128 + ((pc * 2) ^ ((pr & 7) << 4))) = hv;
        }
        __syncthreads();

        // ---- GEMM1 (swapped): accT[f-frag][e-col] ----
        floatx4 acc[2][2];
#pragma unroll
        for (int mi = 0; mi < 2; ++mi)
#pragma unroll
            for (int ni = 0; ni < 2; ++ni)
                acc[mi][ni] = (floatx4){0.f, 0.f, 0.f, 0.f};
#pragma unroll
        for (int ks = 0; ks < 2; ++ks) {
            int k = ks * 32 + l4 * 8;
            half8_t a[2], b[2];
#pragma unroll
            for (int mi = 0; mi < 2; ++mi)
                a[mi] = lds_read8(sT, wm * 32 + mi * 16 + l15, 128, k);
#pragma unroll
            for (int ni = 0; ni < 2; ++ni)
                b[ni] = lds_read8(sB1, wn * 32 + ni * 16 + l15, 128, k);
#pragma unroll
            for (int mi = 0; mi < 2; ++mi)
#pragma unroll
                for (int ni = 0; ni < 2; ++ni)
                    acc[mi][ni] = __builtin_amdgcn_mfma_f32_16x16x32_f16(
                        b[ni], a[mi], acc[mi][ni], 0, 0, 0);
        }
        __syncthreads();

        // ---- bias + tanh -> T (one ds_write_b64 per fragment) ----
#pragma unroll
        for (int ni = 0; ni < 2; ++ni) {
            float4 bv = *(const float4*)(fb1 + fbase[ni]);
#pragma unroll
            for (int mi = 0; mi < 2; ++mi) {
                int e = wm * 32 + mi * 16 + l15;
                half4_t hv;
                hv[0] = (_Float16)fast_tanh(acc[mi][ni][0] + bv.x);
                hv[1] = (_Float16)fast_tanh(acc[mi][ni][1] + bv.y);
                hv[2] = (_Float16)fast_tanh(acc[mi][ni][2] + bv.z);
                hv[3] = (_Float16)fast_tanh(acc[mi][ni][3] + bv.w);
                *(half4_t*)(sT + e * 256 + ((fbase[ni] * 2) ^ ((e & 7) << 4))) = hv;
            }
        }
        __syncthreads();

        // ---- GEMM2 (swapped): accT2[f-frag][e-col] ----
        floatx4 acc2[2][2];
#pragma unroll
        for (int mi = 0; mi < 2; ++mi)
#pragma unroll
            for (int ni = 0; ni < 2; ++ni)
                acc2[mi][ni] = (floatx4){0.f, 0.f, 0.f, 0.f};
#pragma unroll
        for (int ks = 0; ks < 4; ++ks) {
            int k = ks * 32 + l4 * 8;
            half8_t a[2], b[2];
#pragma unroll
            for (int mi = 0; mi < 2; ++mi)
                a[mi] = lds_read8(sT, wm * 32 + mi * 16 + l15, 256, k);
#pragma unroll
            for (int ni = 0; ni < 2; ++ni)
                b[ni] = lds_read8(sB2, wn * 32 + ni * 16 + l15, 256, k);
#pragma unroll
            for (int mi = 0; mi < 2; ++mi)
#pragma unroll
                for (int ni = 0; ni < 2; ++ni)
                    acc2[mi][ni] = __builtin_amdgcn_mfma_f32_16x16x32_f16(
                        b[ni], a[mi], acc2[mi][ni], 0, 0, 0);
        }

        // ---- T14 late prefetch: acc/acc2 mostly dead, pressure minimal ----
        {
            int nt = tile + gridDim.x;
            pA0 = (float4){0.f, 0.f, 0.f, 0.f};
            pA1 = (float4){0.f, 0.f, 0.f, 0.f};
            if (nt < ntiles) {
                int e = nt * TE + pr;
                if (e < E) {
                    const float4* g = (const float4*)(edge_attr + (size_t)e * RD + pc);
                    pA0 = g[0]; pA1 = g[1];
                }
            }
        }

        // ---- epilogue: cutoff-scale, pack half4, store direct to Wp ----
#pragma unroll
        for (int mi = 0; mi < 2; ++mi) {
            int el = wm * 32 + mi * 16 + l15;
            int ge = e0 + el;
            int idx = (ge < E) ? ge : (E - 1);
            float d = edge_weight[idx];
            int pv = inv[idx];
            float C = (d < RC_CUT)
                        ? 0.5f * (__cosf(d * 0.6283185307179586f) + 1.0f)
                        : 0.0f;
            if (ge < E) {
#pragma unroll
                for (int ni = 0; ni < 2; ++ni) {
                    float4 bv = *(const float4*)(fb2 + fbase[ni]);
                    half4_t hv;
                    hv[0] = (_Float16)((acc2[mi][ni][0] + bv.x) * C);
                    hv[1] = (_Float16)((acc2[mi][ni][1] + bv.y) * C);
                    hv[2] = (_Float16)((acc2[mi][ni][2] + bv.z) * C);
                    hv[3] = (_Float16)((acc2[mi][ni][3] + bv.w) * C);
                    *(half4_t*)(Wp + (size_t)pv * FD + fbase[ni]) = hv;
                }
            }
        }
        __syncthreads();   // T consumed; next tile may overwrite sT
    }
}

// ==================== PHASE B: wave-per-dst streaming aggregation ============
// One 64-lane wave per dst row: all lanes share the SAME src each step, so the
// h read is one fully-coalesced 512B row; Wp read is 256B contiguous and
// globally sequential in p. meta[p] is a uniform broadcast load. 4-deep
// unroll keeps 4 edges in flight. Zero atomics, one float2 store per lane.
__global__ __launch_bounds__(256) void agg_kernel(
    const _Float16* __restrict__ Wp,
    const unsigned int* __restrict__ meta,
    const int* __restrict__ offs,
    const float* __restrict__ h,
    float* __restrict__ agg, int n)
{
    int g = blockIdx.x * 4 + (threadIdx.x >> 6);
    if (g >= n) return;
    int lane = threadIdx.x & 63;
    int p  = offs[g];
    int p1 = offs[g + 1];

    float a0 = 0.0f, a1 = 0.0f;
    const int le = lane * 2;

    for (; p + 4 <= p1; p += 4) {
        unsigned m0 = meta[p], m1 = meta[p + 1], m2 = meta[p + 2], m3 = meta[p + 3];
        half2_t w0 = *(const half2_t*)(Wp + (size_t)p * FD + le);
        half2_t w1 = *(const half2_t*)(Wp + (size_t)(p + 1) * FD + le);
        half2_t w2 = *(const half2_t*)(Wp + (size_t)(p + 2) * FD + le);
        half2_t w3 = *(const half2_t*)(Wp + (size_t)(p + 3) * FD + le);
        float2 h0 = *(const float2*)(h + (size_t)(m0 & 0xFFFFu) * FD + le);
        float2 h1 = *(const float2*)(h + (size_t)(m1 & 0xFFFFu) * FD + le);
        float2 h2 = *(const float2*)(h + (size_t)(m2 & 0xFFFFu) * FD + le);
        float2 h3 = *(const float2*)(h + (size_t)(m3 & 0xFFFFu) * FD + le);
        a0 += (float)w0[0] * h0.x + (float)w1[0] * h1.x
            + (float)w2[0] * h2.x + (float)w3[0] * h3.x;
        a1 += (float)w0[1] * h0.y + (float)w1[1] * h1.y
            + (float)w2[1] * h2.y + (float)w3[1] * h3.y;
    }
    for (; p < p1; ++p) {
        unsigned m = meta[p];
        half2_t w = *(const half2_t*)(Wp + (size_t)p * FD + le);
        float2 hv = *(const float2*)(h + (size_t)(m & 0xFFFFu) * FD + le);
        a0 += (float)w[0] * hv.x;
        a1 += (float)w[1] * hv.y;
    }
    *(float2*)(agg + (size_t)g * FD + le) = (float2){a0, a1};
}

// ==================== FALLBACK: fused kernel (global atomics) ================
__global__ __launch_bounds__(1024, 8) void edge_kernel_atomic(
    const float* __restrict__ edge_weight,
    const float* __restrict__ edge_attr,
    const float* __restrict__ fw1, const float* __restrict__ fb1,
    const float* __restrict__ fw2, const float* __restrict__ fb2,
    const int* __restrict__ eidx,
    const float* __restrict__ h,
    float* agg, int E, int ntiles)
{
    extern __shared__ char smem[];
    char* sT  = smem;
    char* sB1 = smem + 32768;
    char* sB2 = smem + 49152;

    for (int i = threadIdx.x * 8; i < FD * RD; i += blockDim.x * 8) {
        int r = i >> 6, c = i & 63;
        const float4* g = (const float4*)(fw1 + (size_t)r * RD + c);
        float4 v0 = g[0], v1 = g[1];
        half8_t hv;
        hv[0] = (_Float16)v0.x; hv[1] = (_Float16)v0.y;
        hv[2] = (_Float16)v0.z; hv[3] = (_Float16)v0.w;
        hv[4] = (_Float16)v1.x; hv[5] = (_Float16)v1.y;
        hv[6] = (_Float16)v1.z; hv[7] = (_Float16)v1.w;
        *(half8_t*)(sB1 + r * 128 + ((c * 2) ^ ((r & 7) << 4))) = hv;
    }
    for (int i = threadIdx.x * 8; i < FD * FD; i += blockDim.x * 8) {
        int r = i >> 7, c = i & 127;
        const float4* g = (const float4*)(fw2 + (size_t)r * FD + c);
        float4 v0 = g[0], v1 = g[1];
        half8_t hv;
        hv[0] = (_Float16)v0.x; hv[1] = (_Float16)v0.y;
        hv[2] = (_Float16)v0.z; hv[3] = (_Float16)v0.w;
        hv[4] = (_Float16)v1.x; hv[5] = (_Float16)v1.y;
        hv[6] = (_Float16)v1.z; hv[7] = (_Float16)v1.w;
        *(half8_t*)(sB2 + r * 256 + ((c * 2) ^ ((r & 7) << 4))) = hv;
    }
    __syncthreads();

    const int* srcp = eidx;
    const int* dstp = eidx + E;
    int lane = threadIdx.x & 63;
    int wid  = threadIdx.x >> 6;
    int wm = wid >> 2;
    int wn = wid & 3;
    int l15 = lane & 15;
    int l4  = lane >> 4;

    for (int tile = blockIdx.x; tile < ntiles; tile += gridDim.x) {
        int e0 = tile * TE;
        for (int i = threadIdx.x * 8; i < TE * RD; i += blockDim.x * 8) {
            int r = i >> 6, c = i & 63;
            half8_t hv;
            if (e0 + r < E) {
                const float4* g = (const float4*)(edge_attr + (size_t)(e0 + r) * RD + c);
                float4 v0 = g[0], v1 = g[1];
                hv[0] = (_Float16)v0.x; hv[1] = (_Float16)v0.y;
                hv[2] = (_Float16)v0.z; hv[3] = (_Float16)v0.w;
                hv[4] = (_Float16)v1.x; hv[5] = (_Float16)v1.y;
                hv[6] = (_Float16)v1.z; hv[7] = (_Float16)v1.w;
            } else {
                for (int q = 0; q < 8; ++q) hv[q] = (_Float16)0.0f;
            }
            *(half8_t*)(sT + r * 128 + ((c * 2) ^ ((r & 7) << 4))) = hv;
        }
        __syncthreads();

        floatx4 acc[2][2];
#pragma unroll
        for (int mi = 0; mi < 2; ++mi)
#pragma unroll
            for (int ni = 0; ni < 2; ++ni)
                acc[mi][ni] = (floatx4){0.f, 0.f, 0.f, 0.f};
#pragma unroll
        for (int ks = 0; ks < 2; ++ks) {
            int k = ks * 32 + l4 * 8;
            half8_t a[2], b[2];
#pragma unroll
            for (int mi = 0; mi < 2; ++mi)
                a[mi] = lds_read8(sT, wm * 32 + mi * 16 + l15, 128, k);
#pragma unroll
            for (int ni = 0; ni < 2; ++ni)
                b[ni] = lds_read8(sB1, wn * 32 + ni * 16 + l15, 128, k);
#pragma unroll
            for (int mi = 0; mi < 2; ++mi)
#pragma unroll
                for (int ni = 0; ni < 2; ++ni)
                    acc[mi][ni] = __builtin_amdgcn_mfma_f32_16x16x32_f16(
                        a[mi], b[ni], acc[mi][ni], 0, 0, 0);
        }
        __syncthreads();

#pragma unroll
        for (int ni = 0; ni < 2; ++ni) {
            int f = wn * 32 + ni * 16 + l15;
            float bias = fb1[f];
#pragma unroll
            for (int mi = 0; mi < 2; ++mi) {
#pragma unroll
                for (int j = 0; j < 4; ++j) {
                    int e = wm * 32 + mi * 16 + l4 * 4 + j;
                    float t = fast_tanh(acc[mi][ni][j] + bias);
                    *(_Float16*)(sT + e * 256 + ((f * 2) ^ ((e & 7) << 4))) =
                        (_Float16)t;
                }
            }
        }
        __syncthreads();

        floatx4 acc2[2][2];
#pragma unroll
        for (int mi = 0; mi < 2; ++mi)
#pragma unroll
            for (int ni = 0; ni < 2; ++ni)
                acc2[mi][ni] = (floatx4){0.f, 0.f, 0.f, 0.f};
#pragma unroll
        for (int ks = 0; ks < 4; ++ks) {
            int k = ks * 32 + l4 * 8;
            half8_t a[2], b[2];
#pragma unroll
            for (int mi = 0; mi < 2; ++mi)
                a[mi] = lds_read8(sT, wm * 32 + mi * 16 + l15, 256, k);
#pragma unroll
            for (int ni = 0; ni < 2; ++ni)
                b[ni] = lds_read8(sB2, wn * 32 + ni * 16 + l15, 256, k);
#pragma unroll
            for (int mi = 0; mi < 2; ++mi)
#pragma unroll
                for (int ni = 0; ni < 2; ++ni)
                    acc2[mi][ni] = __builtin_amdgcn_mfma_f32_16x16x32_f16(
                        a[mi], b[ni], acc2[mi][ni], 0, 0, 0);
        }
        __syncthreads();

        float bias2[2];
        int gcol[2];
#pragma unroll
        for (int ni = 0; ni < 2; ++ni) {
            gcol[ni] = wn * 32 + ni * 16 + l15;
            bias2[ni] = fb2[gcol[ni]];
        }
#pragma unroll
        for (int mi = 0; mi < 2; ++mi) {
            int ge[4], s4[4], dn4[4];
            float d4[4];
#pragma unroll
            for (int j = 0; j < 4; ++j) {
                int el = wm * 32 + mi * 16 + l4 * 4 + j;
                ge[j] = e0 + el;
                int idx = (ge[j] < E) ? ge[j] : (E - 1);
                s4[j]  = srcp[idx];
                dn4[j] = dstp[idx];
                d4[j]  = edge_weight[idx];
            }
#pragma unroll
            for (int j = 0; j < 4; ++j) {
                if (ge[j] >= E) continue;
                float C = (d4[j] < RC_CUT)
                            ? 0.5f * (__cosf(d4[j] * 0.6283185307179586f) + 1.0f)
                            : 0.0f;
                const float* hrow = h + (size_t)s4[j] * FD;
                float* ar = agg + (size_t)dn4[j] * FD;
#pragma unroll
                for (int ni = 0; ni < 2; ++ni) {
                    int g = gcol[ni];
                    float wv = (acc2[mi][ni][j] + bias2[ni]) * C;
                    atomicAdd(ar + g, wv * hrow[g]);
                }
            }
        }
    }
}

// ---------------- final: disc conv + lin2 + tanh + lin ----------------
__global__ __launch_bounds__(256) void final_kernel(
    const float* aggin, const float* __restrict__ h,
    const float* __restrict__ disc_w,
    const float* __restrict__ lin2_w, const float* __restrict__ lin2_b,
    const float* __restrict__ lin_w, const float* __restrict__ lin_b,
    float* out, int n)
{
    __shared__ float sg[16][FD];
    __shared__ float sm[16][FD];
    int base = blockIdx.x * 16;
    for (int i = threadIdx.x; i < 16 * FD; i += 256) {
        int r = i >> 7, c = i & 127;
        int row = base + r;
        float v = 0.0f;
        if (row < n) {
            v = aggin[(size_t)row * FD + c] + disc_w[c] * h[(size_t)row * FD + c];
            if (row + 1 < n) v += disc_w[FD + c] * h[(size_t)(row + 1) * FD + c];
            if (row >= 1)    v += disc_w[2 * FD + c] * h[(size_t)(row - 1) * FD + c];
        }
        sg[r][c] = v;
    }
    __syncthreads();
    int f = threadIdx.x & 127;
    int half = threadIdx.x >> 7;
    {
        float acc[8];
        float b = lin2_b[f];
#pragma unroll
        for (int r = 0; r < 8; ++r) acc[r] = b;
        const float* wrow = lin2_w + (size_t)f * FD;
        for (int k = 0; k < FD; k += 4) {
            float4 wv = *(const float4*)(wrow + k);
#pragma unroll
            for (int r = 0; r < 8; ++r) {
                acc[r] += sg[half * 8 + r][k]     * wv.x;
                acc[r] += sg[half * 8 + r][k + 1] * wv.y;
                acc[r] += sg[half * 8 + r][k + 2] * wv.z;
                acc[r] += sg[half * 8 + r][k + 3] * wv.w;
            }
        }
#pragma unroll
        for (int r = 0; r < 8; ++r) sm[half * 8 + r][f] = fast_tanh(acc[r]);
    }
    __syncthreads();
    {
        float acc[8];
        float b = lin_b[f];
#pragma unroll
        for (int r = 0; r < 8; ++r) acc[r] = b;
        const float* wrow = lin_w + (size_t)f * HD;
        for (int k = 0; k < FD; k += 4) {
            float4 wv = *(const float4*)(wrow + k);
#pragma unroll
            for (int r = 0; r < 8; ++r) {
                acc[r] += sm[half * 8 + r][k]     * wv.x;
                acc[r] += sm[half * 8 + r][k + 1] * wv.y;
                acc[r] += sm[half * 8 + r][k + 2] * wv.z;
                acc[r] += sm[half * 8 + r][k + 3] * wv.w;
            }
        }
#pragma unroll
        for (int r = 0; r < 8; ++r) {
            int row = base + half * 8 + r;
            if (row < n) out[(size_t)row * HD + f] = acc[r];
        }
    }
}

extern "C" void kernel_launch(void* const* d_in, const int* in_sizes, int n_in,
                              void* d_out, int out_size, void* d_ws, size_t ws_size,
                              hipStream_t stream)
{
    const float* x      = (const float*)d_in[0];
    const float* ew     = (const float*)d_in[1];
    const float* ea     = (const float*)d_in[2];
    const float* fw1    = (const float*)d_in[3];
    const float* fb1    = (const float*)d_in[4];
    const float* fw2    = (const float*)d_in[5];
    const float* fb2    = (const float*)d_in[6];
    const float* lin1_w = (const float*)d_in[7];
    const float* lin2_w = (const float*)d_in[8];
    const float* lin2_b = (const float*)d_in[9];
    const float* disc_w = (const float*)d_in[10];
    const float* lin_w  = (const float*)d_in[11];
    const float* lin_b  = (const float*)d_in[12];
    const int*   eidx   = (const int*)d_in[13];

    int n = in_sizes[0] / HD;
    int E = in_sizes[1];
    int ntiles = (E + TE - 1) / TE;
    int nb = (n + 255) / 256;
    float* out = (float*)d_out;

    const int* srcp = eidx;
    const int* dstp = eidx + E;

    // workspace layout (16B-aligned sections)
    char* base = (char*)d_ws;
    float*     h    = (float*)base;                       // n*128 f32
    size_t off_h    = (size_t)n * FD * 4;
    _Float16*  Wp   = (_Float16*)(base + off_h);          // E*128 f16
    size_t off_w    = off_h + (size_t)E * FD * 2;
    int*       inv  = (int*)(base + off_w);               // E ints
    size_t off_i    = off_w + (size_t)E * 4;
    unsigned int* meta = (unsigned int*)(base + off_i);   // E u32
    size_t off_m    = off_i + (size_t)E * 4;
    int*       cnt  = (int*)(base + off_m);               // n ints (per-dst)
    int*       offs = cnt + n;                            // n+1 ints
    int*       bsum = offs + n + 1;                       // nb ints
    size_t need     = off_m + (size_t)(2 * n + nb + 16) * 4;

    lin1_kernel<<<(n + 15) / 16, 256, 0, stream>>>(x, lin1_w, h, n);

    size_t smem = 81920;   // 80 KB -> 2 blocks/CU
    if (ws_size >= need && n <= 65535) {
        // ---------- two-phase path: sorted-by-dst, wave-per-dst agg ----------
        hipMemsetAsync(cnt, 0, (size_t)n * sizeof(int), stream);
        count_kernel<<<2048, 256, 0, stream>>>(dstp, cnt, E);
        scan1_kernel<<<nb, 256, 0, stream>>>(cnt, bsum, n);
        scan2_kernel<<<1, 64, 0, stream>>>(bsum, nb, offs + n);
        scan3_kernel<<<nb, 256, 0, stream>>>(cnt, bsum, offs, n);
        scatter_kernel<<<2048, 256, 0, stream>>>(srcp, dstp, cnt, inv, meta, E);

        hipFuncSetAttribute((const void*)edge_gemm_kernel,
                            hipFuncAttributeMaxDynamicSharedMemorySize, (int)smem);
        int nblocks = ntiles < 512 ? ntiles : 512;
        edge_gemm_kernel<<<nblocks, 1024, smem, stream>>>(ew, ea, fw1, fb1, fw2, fb2,
                                                          inv, Wp, E, ntiles);

        agg_kernel<<<(n + 3) / 4, 256, 0, stream>>>(Wp, meta, offs, h, out, n);
    } else {
        // ---------- fallback: proven fused atomic kernel ----------
        hipMemsetAsync(d_out, 0, (size_t)out_size * sizeof(float), stream);
        hipFuncSetAttribute((const void*)edge_kernel_atomic,
                            hipFuncAttributeMaxDynamicSharedMemorySize, (int)smem);
        int nblocks = ntiles < 512 ? ntiles : 512;
        edge_kernel_atomic<<<nblocks, 1024, smem, stream>>>(ew, ea, fw1, fb1, fw2, fb2,
                                                            eidx, h, out, E, ntiles);
    }

    final_kernel<<<(n + 15) / 16, 256, 0, stream>>>(out, h, disc_w, lin2_w, lin2_b,
                                                    lin_w, lin_b, out, n);
}